// Round 1
// baseline (435.722 us; speedup 1.0000x reference)
//
#include <hip/hip_runtime.h>
#include <hip/hip_bf16.h>
#include <math.h>

#define T_ 128
#define NE_ 64
#define NA_ 8
#define B_ 512
#define OBS_ 64
#define D_ 128
#define CH_ 128
#define VH_ 256
#define M_ (T_*B_)   // 65536

typedef __attribute__((ext_vector_type(8))) short bf16x8;
typedef __attribute__((ext_vector_type(8))) _Float16 f16x8;
typedef __attribute__((ext_vector_type(4))) float f32x4;

__device__ __forceinline__ float sigmoidf_(float x){ return 1.f/(1.f+__expf(-x)); }
__device__ __forceinline__ unsigned short f2bu(float v){
  __hip_bfloat16 b = __float2bfloat16(v);
  return __builtin_bit_cast(unsigned short, b);
}
__device__ __forceinline__ float bu2f(unsigned short u){
  return __builtin_bit_cast(float, (unsigned int)u << 16);
}
__device__ __forceinline__ unsigned short f2hu(float v){
  _Float16 h = (_Float16)v;
  return __builtin_bit_cast(unsigned short, h);
}
__device__ __forceinline__ float hu2f(unsigned short u){
  return (float)__builtin_bit_cast(_Float16, u);
}

// ---------------------------------------------------------------------------
// fp16 MFMA GEMM (single-term): C_fp16 = epi(A_fp16[M][K] @ B + bias)
// ---------------------------------------------------------------------------
template<int ACT>
__global__ __launch_bounds__(256)
void mgemmh_k(const ushort* __restrict__ A, const ushort* __restrict__ BT,
              const float* __restrict__ bias, ushort* __restrict__ C,
              int M, int N, int K)
{
  __shared__ ushort As[128*72];
  __shared__ ushort Bs[64*72];
  const int tid  = threadIdx.x;
  const int lane = tid & 63, wave = tid >> 6;
  const int wm = wave >> 1, wn = wave & 1;
  const int quad = lane >> 4, ln = lane & 15;
  const int n0 = blockIdx.x * 64;
  const int m0 = blockIdx.y * 128;

  f32x4 acc[4][2];
  #pragma unroll
  for (int i=0;i<4;i++)
    #pragma unroll
    for (int j=0;j<2;j++)
      #pragma unroll
      for (int r=0;r<4;r++) acc[i][j][r] = 0.f;

  for (int kc=0; kc<K; kc+=64){
    #pragma unroll
    for (int i=0;i<4;i++){
      int c8 = tid + i*256;
      int m = c8 >> 3, kq = (c8 & 7)*8;
      *(uint4*)&As[m*72+kq] = *(const uint4*)&A[(size_t)(m0+m)*K + kc + kq];
    }
    #pragma unroll
    for (int i=0;i<2;i++){
      int c8 = tid + i*256;
      int n = c8 >> 3, kq = (c8 & 7)*8;
      *(uint4*)&Bs[n*72+kq] = *(const uint4*)&BT[(size_t)(n0+n)*K + kc + kq];
    }
    __syncthreads();
    #pragma unroll
    for (int ks=0; ks<2; ks++){
      const int kq = ks*32 + quad*8;
      f16x8 af[4], bfv[2];
      #pragma unroll
      for (int mt=0;mt<4;mt++)
        af[mt] = *(const f16x8*)&As[(wm*64 + mt*16 + ln)*72 + kq];
      #pragma unroll
      for (int nt=0;nt<2;nt++)
        bfv[nt] = *(const f16x8*)&Bs[(wn*32 + nt*16 + ln)*72 + kq];
      #pragma unroll
      for (int mt=0;mt<4;mt++)
        #pragma unroll
        for (int nt=0;nt<2;nt++)
          acc[mt][nt] = __builtin_amdgcn_mfma_f32_16x16x32_f16(af[mt], bfv[nt], acc[mt][nt], 0,0,0);
    }
    __syncthreads();
  }

  float biasv[2];
  #pragma unroll
  for (int nt=0;nt<2;nt++) biasv[nt] = bias ? bias[n0 + wn*32 + nt*16 + ln] : 0.f;
  #pragma unroll
  for (int mt=0;mt<4;mt++){
    #pragma unroll
    for (int r=0;r<4;r++){
      int row = m0 + wm*64 + mt*16 + quad*4 + r;
      #pragma unroll
      for (int nt=0;nt<2;nt++){
        int col = n0 + wn*32 + nt*16 + ln;
        float v = acc[mt][nt][r] + biasv[nt];
        if (ACT==1) v = fmaxf(v, 0.f);
        C[(size_t)row*N + col] = f2hu(v);
      }
    }
  }
}

// ---------------------------------------------------------------------------
// bf16 MFMA GEMM (v1 head): BT = B^T [N,K] bf16; 128x128 tile, BK=128.
// ---------------------------------------------------------------------------
template<int ACT>
__global__ __launch_bounds__(256)
void mgemm_k(const __hip_bfloat16* __restrict__ A, const __hip_bfloat16* __restrict__ BT,
             const float* __restrict__ bias, __hip_bfloat16* __restrict__ Cb,
             int M, int N, int K)
{
  __shared__ ushort As[128*136];
  __shared__ ushort Bs[128*136];
  const int tid  = threadIdx.x;
  const int lane = tid & 63, wave = tid >> 6;
  const int wm = wave >> 1, wn = wave & 1;
  const int quad = lane >> 4, ln = lane & 15;
  const int n0 = blockIdx.x * 128;
  const int m0 = blockIdx.y * 128;

  f32x4 acc[4][4];
  #pragma unroll
  for (int i=0;i<4;i++)
    #pragma unroll
    for (int j=0;j<4;j++)
      #pragma unroll
      for (int r=0;r<4;r++) acc[i][j][r] = 0.f;

  for (int kc=0; kc<K; kc+=128){
    #pragma unroll
    for (int i=0;i<8;i++){
      int c8 = tid + i*256;
      int m = c8 >> 4, kq = (c8 & 15)*8;
      *(uint4*)&As[m*136 + kq] = *(const uint4*)&A[(size_t)(m0+m)*K + kc + kq];
    }
    #pragma unroll
    for (int i=0;i<8;i++){
      int c8 = tid + i*256;
      int n = c8 >> 4, kq = (c8 & 15)*8;
      *(uint4*)&Bs[n*136 + kq] = *(const uint4*)&BT[(size_t)(n0+n)*K + kc + kq];
    }
    __syncthreads();
    #pragma unroll
    for (int ks=0; ks<4; ks++){
      const int kq = ks*32 + quad*8;
      bf16x8 af[4], bfv[4];
      #pragma unroll
      for (int mt=0;mt<4;mt++)
        af[mt] = *(const bf16x8*)&As[(wm*64 + mt*16 + ln)*136 + kq];
      #pragma unroll
      for (int nt=0;nt<4;nt++)
        bfv[nt] = *(const bf16x8*)&Bs[(wn*64 + nt*16 + ln)*136 + kq];
      #pragma unroll
      for (int mt=0;mt<4;mt++)
        #pragma unroll
        for (int nt=0;nt<4;nt++)
          acc[mt][nt] = __builtin_amdgcn_mfma_f32_16x16x32_bf16(af[mt], bfv[nt], acc[mt][nt], 0,0,0);
    }
    __syncthreads();
  }

  float biasv[4];
  #pragma unroll
  for (int nt=0;nt<4;nt++) biasv[nt] = bias ? bias[n0 + wn*64 + nt*16 + ln] : 0.f;
  #pragma unroll
  for (int mt=0;mt<4;mt++){
    #pragma unroll
    for (int r=0;r<4;r++){
      int row = m0 + wm*64 + mt*16 + quad*4 + r;
      #pragma unroll
      for (int nt=0;nt<4;nt++){
        int col = n0 + wn*64 + nt*16 + ln;
        float v = acc[mt][nt][r] + biasv[nt];
        if (ACT==1) v = fmaxf(v, 0.f);
        Cb[(size_t)row*N + col] = __float2bfloat16(v);
      }
    }
  }
}

// ---------------------------------------------------------------------------
// Fused dpre+update: per 128-row block:
//   dpre = relu([Xe|Xc] @ uhwT + uhb)  (K=256, accumulated; tile kept in LDS)
//   Xe   = (Xe + relu(dpre @ uowT + uob)) * alive
// ---------------------------------------------------------------------------
__global__ __launch_bounds__(256)
void updf_k(const __hip_bfloat16* __restrict__ Xe, const __hip_bfloat16* __restrict__ Xc,
            const __hip_bfloat16* __restrict__ uhwT, const float* __restrict__ uhb,
            const __hip_bfloat16* __restrict__ uowT, const float* __restrict__ uob,
            const int* __restrict__ dones, __hip_bfloat16* __restrict__ XeOut)
{
  __shared__ ushort As[128*136];   // A-stage, then dpre tile
  __shared__ ushort Bs[128*136];
  const int tid  = threadIdx.x;
  const int lane = tid & 63, wave = tid >> 6;
  const int wm = wave >> 1, wn = wave & 1;
  const int quad = lane >> 4, ln = lane & 15;
  const int m0 = blockIdx.x * 128;

  f32x4 acc[4][4];
  #pragma unroll
  for (int i=0;i<4;i++)
    #pragma unroll
    for (int j=0;j<4;j++)
      #pragma unroll
      for (int r=0;r<4;r++) acc[i][j][r] = 0.f;

  // phase 1: dpre accumulate over K=256 (kc=0: Xe, kc=1: Xc)
  for (int kc=0; kc<2; kc++){
    const __hip_bfloat16* Ab = kc ? Xc : Xe;
    #pragma unroll
    for (int i=0;i<8;i++){
      int c8 = tid + i*256;
      int m = c8 >> 4, kq = (c8 & 15)*8;
      *(uint4*)&As[m*136 + kq] = *(const uint4*)&Ab[(size_t)(m0+m)*128 + kq];
    }
    #pragma unroll
    for (int i=0;i<8;i++){
      int c8 = tid + i*256;
      int n = c8 >> 4, kq = (c8 & 15)*8;
      *(uint4*)&Bs[n*136 + kq] = *(const uint4*)&uhwT[(size_t)n*256 + kc*128 + kq];
    }
    __syncthreads();
    #pragma unroll
    for (int ks=0; ks<4; ks++){
      const int kq = ks*32 + quad*8;
      bf16x8 af[4], bfv[4];
      #pragma unroll
      for (int mt=0;mt<4;mt++)
        af[mt] = *(const bf16x8*)&As[(wm*64 + mt*16 + ln)*136 + kq];
      #pragma unroll
      for (int nt=0;nt<4;nt++)
        bfv[nt] = *(const bf16x8*)&Bs[(wn*64 + nt*16 + ln)*136 + kq];
      #pragma unroll
      for (int mt=0;mt<4;mt++)
        #pragma unroll
        for (int nt=0;nt<4;nt++)
          acc[mt][nt] = __builtin_amdgcn_mfma_f32_16x16x32_bf16(af[mt], bfv[nt], acc[mt][nt], 0,0,0);
    }
    __syncthreads();
  }

  // stage uowT -> Bs, and dpre epilogue -> As (both free after last barrier)
  #pragma unroll
  for (int i=0;i<8;i++){
    int c8 = tid + i*256;
    int n = c8 >> 4, kq = (c8 & 15)*8;
    *(uint4*)&Bs[n*136 + kq] = *(const uint4*)&uowT[(size_t)n*128 + kq];
  }
  #pragma unroll
  for (int mt=0;mt<4;mt++){
    #pragma unroll
    for (int r=0;r<4;r++){
      int rl = wm*64 + mt*16 + quad*4 + r;
      #pragma unroll
      for (int nt=0;nt<4;nt++){
        int cl = wn*64 + nt*16 + ln;
        float v = fmaxf(acc[mt][nt][r] + uhb[cl], 0.f);
        As[rl*136 + cl] = f2bu(v);
      }
    }
  }
  __syncthreads();

  // phase 2: e = (e + relu(dpre @ uowT + uob)) * alive
  f32x4 acc2[4][4];
  #pragma unroll
  for (int i=0;i<4;i++)
    #pragma unroll
    for (int j=0;j<4;j++)
      #pragma unroll
      for (int r=0;r<4;r++) acc2[i][j][r] = 0.f;
  #pragma unroll
  for (int ks=0; ks<4; ks++){
    const int kq = ks*32 + quad*8;
    bf16x8 af[4], bfv[4];
    #pragma unroll
    for (int mt=0;mt<4;mt++)
      af[mt] = *(const bf16x8*)&As[(wm*64 + mt*16 + ln)*136 + kq];
    #pragma unroll
    for (int nt=0;nt<4;nt++)
      bfv[nt] = *(const bf16x8*)&Bs[(wn*64 + nt*16 + ln)*136 + kq];
    #pragma unroll
    for (int mt=0;mt<4;mt++)
      #pragma unroll
      for (int nt=0;nt<4;nt++)
        acc2[mt][nt] = __builtin_amdgcn_mfma_f32_16x16x32_bf16(af[mt], bfv[nt], acc2[mt][nt], 0,0,0);
  }
  #pragma unroll
  for (int mt=0;mt<4;mt++){
    #pragma unroll
    for (int r=0;r<4;r++){
      int row = m0 + wm*64 + mt*16 + quad*4 + r;
      float al = (dones[row]!=0) ? 0.f : 1.f;
      #pragma unroll
      for (int nt=0;nt<4;nt++){
        int cl = wn*64 + nt*16 + ln;
        float v = fmaxf(acc2[mt][nt][r] + uob[cl], 0.f);
        v += bu2f(((const ushort*)Xe)[(size_t)row*128 + cl]);
        v *= al;
        XeOut[(size_t)row*128 + cl] = __float2bfloat16(v);
      }
    }
  }
}

// ---------------------------------------------------------------------------
// Fused acat+coupling per (t,env).
// ---------------------------------------------------------------------------
__global__ __launch_bounds__(256)
void couple2_k(const __hip_bfloat16* __restrict__ Xe, const ushort* __restrict__ bcatT,
               const float* __restrict__ chb, const float* __restrict__ cow,
               const float* __restrict__ cob, __hip_bfloat16* __restrict__ ctxb)
{
  __shared__ ushort es16[8*136];
  __shared__ float ai[8][132], aj[8][132];
  __shared__ float cbw[CH_], cww[CH_], Cs[NA_][NA_];
  const int m0 = blockIdx.x * NA_;
  const int tid = threadIdx.x;
  const int lane = tid & 63, wave = tid >> 6;  // 4 waves
  const int quad = lane >> 4, ln = lane & 15;

  if (tid < 128){
    int j = tid >> 4, q = (tid & 15)*8;
    *(uint4*)&es16[j*136 + q] = *(const uint4*)((const ushort*)Xe + (size_t)(m0+j)*D_ + q);
    cbw[tid] = chb[tid]; cww[tid] = cow[tid];
  }
  __syncthreads();

  // acat MFMA: wave w covers cols w*64..w*64+63 (4 n-tiles)
  f32x4 acc[4];
  #pragma unroll
  for (int nt=0;nt<4;nt++)
    #pragma unroll
    for (int r=0;r<4;r++) acc[nt][r] = 0.f;
  #pragma unroll
  for (int ks=0; ks<4; ks++){
    bf16x8 af = *(const bf16x8*)&es16[(ln & 7)*136 + ks*32 + quad*8];
    #pragma unroll
    for (int nt=0;nt<4;nt++){
      int n = wave*64 + nt*16 + ln;
      bf16x8 bfv = *(const bf16x8*)&bcatT[(size_t)n*128 + ks*32 + quad*8];
      acc[nt] = __builtin_amdgcn_mfma_f32_16x16x32_bf16(af, bfv, acc[nt], 0,0,0);
    }
  }
  if (quad < 2){        // rows 0..7 live in quads 0,1
    #pragma unroll
    for (int nt=0;nt<4;nt++){
      int col = wave*64 + nt*16 + ln;
      #pragma unroll
      for (int r=0;r<4;r++){
        int row = quad*4 + r;
        float v = acc[nt][r];
        if (col < 128) ai[row][col] = v; else aj[row][col-128] = v;
      }
    }
  }
  __syncthreads();

  {
    int p = tid >> 2, q = tid & 3;
    int i = p >> 3, j = p & 7;
    float s = 0.f;
    #pragma unroll
    for (int h = 0; h < 32; h++){
      int hh = q*32 + h;
      s += fmaxf(ai[i][hh] + aj[j][hh] + cbw[hh], 0.f) * cww[hh];
    }
    s += __shfl_down(s, 2);
    s += __shfl_down(s, 1);
    if (q == 0) {
      float Cv = sigmoidf_(s + cob[0]);
      Cs[i][j] = (i==j) ? 0.f : Cv;
    }
  }
  __syncthreads();
  #pragma unroll
  for (int rep=0; rep<4; rep++){
    int idx = rep*256 + tid;
    int i = idx >> 7, d = idx & 127;
    float s = 0.f;
    #pragma unroll
    for (int j=0;j<NA_;j++) s = fmaf(Cs[i][j], bu2f(es16[j*136 + d]), s);
    ctxb[(size_t)(m0+i)*D_ + d] = __float2bfloat16(s);
  }
}

// ---------------------------------------------------------------------------
// Fused v2 + vout.
// ---------------------------------------------------------------------------
__global__ __launch_bounds__(256)
void vhead2_k(const __hip_bfloat16* __restrict__ v1, const __hip_bfloat16* __restrict__ v2wT,
              const float* __restrict__ v2b, const float* __restrict__ vow,
              const float* __restrict__ vob, float* __restrict__ values)
{
  __shared__ ushort As[128*136];
  __shared__ ushort Bs[128*136];
  const int tid  = threadIdx.x;
  const int lane = tid & 63, wave = tid >> 6;
  const int wm = wave >> 1, wn = wave & 1;
  const int quad = lane >> 4, ln = lane & 15;
  const int n0 = blockIdx.x * 128;
  const int m0 = blockIdx.y * 128;

  f32x4 acc[4][4];
  #pragma unroll
  for (int i=0;i<4;i++)
    #pragma unroll
    for (int j=0;j<4;j++)
      #pragma unroll
      for (int r=0;r<4;r++) acc[i][j][r] = 0.f;

  for (int kc=0; kc<2; kc++){
    #pragma unroll
    for (int i=0;i<8;i++){
      int c8 = tid + i*256;
      int m = c8 >> 4, kq = (c8 & 15)*8;
      *(uint4*)&As[m*136 + kq] = *(const uint4*)((const ushort*)v1 + (size_t)(m0+m)*256 + kc*128 + kq);
    }
    #pragma unroll
    for (int i=0;i<8;i++){
      int c8 = tid + i*256;
      int n = c8 >> 4, kq = (c8 & 15)*8;
      *(uint4*)&Bs[n*136 + kq] = *(const uint4*)((const ushort*)v2wT + (size_t)(n0+n)*256 + kc*128 + kq);
    }
    __syncthreads();
    #pragma unroll
    for (int ks=0; ks<4; ks++){
      const int kq = ks*32 + quad*8;
      bf16x8 af[4], bfv[4];
      #pragma unroll
      for (int mt=0;mt<4;mt++)
        af[mt] = *(const bf16x8*)&As[(wm*64 + mt*16 + ln)*136 + kq];
      #pragma unroll
      for (int nt=0;nt<4;nt++)
        bfv[nt] = *(const bf16x8*)&Bs[(wn*64 + nt*16 + ln)*136 + kq];
      #pragma unroll
      for (int mt=0;mt<4;mt++)
        #pragma unroll
        for (int nt=0;nt<4;nt++)
          acc[mt][nt] = __builtin_amdgcn_mfma_f32_16x16x32_bf16(af[mt], bfv[nt], acc[mt][nt], 0,0,0);
    }
    __syncthreads();
  }

  float v2bv[4], voww[4];
  #pragma unroll
  for (int nt=0;nt<4;nt++){
    int col = n0 + wn*64 + nt*16 + ln;
    v2bv[nt] = v2b[col];
    voww[nt] = vow[col];
  }
  float s[4][4];
  #pragma unroll
  for (int mt=0;mt<4;mt++)
    #pragma unroll
    for (int r=0;r<4;r++){
      float p = 0.f;
      #pragma unroll
      for (int nt=0;nt<4;nt++)
        p += fmaxf(acc[mt][nt][r] + v2bv[nt], 0.f) * voww[nt];
      s[mt][r] = p;
    }
  #pragma unroll
  for (int off=1; off<16; off<<=1)
    #pragma unroll
    for (int mt=0;mt<4;mt++)
      #pragma unroll
      for (int r=0;r<4;r++)
        s[mt][r] += __shfl_xor(s[mt][r], off);
  if (ln == 0){
    float add = (blockIdx.x == 0 && wn == 0) ? vob[0] : 0.f;
    #pragma unroll
    for (int mt=0;mt<4;mt++)
      #pragma unroll
      for (int r=0;r<4;r++)
        atomicAdd(&values[m0 + wm*64 + mt*16 + quad*4 + r], s[mt][r] + add);
  }
}

// ---------------------------------------------------------------------------
// MFMA GRU v9: v8 + (a) LDS-only barrier per step (raw s_waitcnt lgkmcnt(0)
// + s_barrier in ONE asm, memory-clobbered) so the per-step gi prefetch
// loads and eb_out stores are NOT drained at the barrier (__syncthreads
// emits vmcnt(0)/expcnt(0) which serialized ~L3-latency into every one of
// the 128 sequential steps); (b) 2-way parallel MFMA accumulator chains
// (K=128 was a 4-deep serial MFMA dependency; now 2 chains of 2 + 1 add).
// ---------------------------------------------------------------------------
__global__ __launch_bounds__(512, 1)
void grum8_k(const ushort* __restrict__ gih, const float* __restrict__ hidden0,
             const int* __restrict__ dones, const float* __restrict__ gWh,
             const float* __restrict__ bhn, __hip_bfloat16* __restrict__ eb_out,
             float* __restrict__ hout)
{
  __shared__ ushort wstg[32*392];
  __shared__ ushort hb[2][16*136];
  __shared__ float  dnS[T_*4];
  const int tid  = threadIdx.x;
  const int lane = tid & 63, wave = tid >> 6;
  const int quad = lane >> 4, ln = lane & 15;
  const int r0   = blockIdx.x * 4;
  const int col  = wave*16 + ln;
  const int lnb  = ln & 12;

  dnS[tid] = (dones[(size_t)(tid>>2)*B_ + r0 + (tid&3)] != 0) ? 1.f : 0.f;
  const float bhnr = bhn[col];

  for (int i=tid; i<16*136; i+=512){ hb[0][i]=0; hb[1][i]=0; }

  f16x8 bf[3][4];
  #pragma unroll
  for (int kc=0; kc<4; kc++){
    for (int i=tid; i<32*384; i+=512){
      int kk = i/384, c = i - kk*384;
      wstg[kk*392 + c] = f2hu(gWh[(size_t)(kc*32+kk)*384 + c]);
    }
    __syncthreads();
    #pragma unroll
    for (int g=0; g<3; g++){
      int c = g*128 + col;
      ushort tmp[8];
      #pragma unroll
      for (int j=0;j<8;j++) tmp[j] = wstg[(quad*8+j)*392 + c];
      bf[g][kc] = *(const f16x8*)tmp;
    }
    __syncthreads();
  }

  float hc = hidden0[(size_t)(r0+quad)*D_ + col];
  if (dnS[quad] > 0.5f) hc = 0.f;
  hb[0][(quad*4)*136 + col] = f2hu(hc);
  __syncthreads();

  float c_r, c_z, c_n;
  {
    const ushort* gp = gih + ((size_t)(r0+quad))*384;
    c_r = hu2f(gp[col]); c_z = hu2f(gp[col+128]); c_n = hu2f(gp[col+256]);
  }

  ushort pend_eu = 0;

  for (int t=0; t<T_; t++){
    if (t > 0)
      ((ushort*)eb_out)[((size_t)(t-1)*B_ + r0+quad)*D_ + col] = pend_eu;

    float n_r=0.f, n_z=0.f, n_n=0.f;
    if (t+1 < T_){
      const ushort* gp = gih + ((size_t)(t+1)*B_ + r0+quad)*384;
      n_r = hu2f(gp[col]); n_z = hu2f(gp[col+128]); n_n = hu2f(gp[col+256]);
    }

    const ushort* hbuf = hb[t&1];
    f32x4 accA[3], accB[3];
    #pragma unroll
    for (int g=0;g<3;g++)
      #pragma unroll
      for (int r=0;r<4;r++){ accA[g][r]=0.f; accB[g][r]=0.f; }
    #pragma unroll
    for (int ks=0; ks<2; ks++){
      f16x8 ahA = *(const f16x8*)&hbuf[lnb*136 + (2*ks  )*32 + quad*8];
      f16x8 ahB = *(const f16x8*)&hbuf[lnb*136 + (2*ks+1)*32 + quad*8];
      #pragma unroll
      for (int g=0;g<3;g++){
        accA[g] = __builtin_amdgcn_mfma_f32_16x16x32_f16(ahA, bf[g][2*ks  ], accA[g], 0,0,0);
        accB[g] = __builtin_amdgcn_mfma_f32_16x16x32_f16(ahB, bf[g][2*ks+1], accB[g], 0,0,0);
      }
    }

    const float dnow  = dnS[t*4 + quad];
    const float dnext = (t+1 < T_) ? dnS[(t+1)*4 + quad] : 0.f;
    float rg = sigmoidf_(c_r + accA[0][0] + accB[0][0]);
    float zg = sigmoidf_(c_z + accA[1][0] + accB[1][0]);
    float x  = c_n + rg*(accA[2][0] + accB[2][0] + bhnr);
    float ng = 2.f/(1.f+__expf(-2.f*x)) - 1.f;
    float hnew = (1.f - zg)*ng + zg*hc;
    pend_eu = f2bu(hnew*(1.f-dnow));
    float hv = (dnext > 0.5f) ? 0.f : hnew;
    hc = hv;
    hb[(t+1)&1][(quad*4)*136 + col] = f2hu(hv);
    // LDS-only barrier: order the hb double-buffer hand-off (lgkmcnt) but
    // do NOT drain vmcnt/expcnt — the gi prefetch loads and eb_out stores
    // stay in flight across steps. Single asm + memory clobber so no
    // memory op can be moved across it by the scheduler.
    asm volatile("s_waitcnt lgkmcnt(0)\n\ts_barrier" ::: "memory");
    c_r = n_r; c_z = n_z; c_n = n_n;
  }
  ((ushort*)eb_out)[((size_t)(T_-1)*B_ + r0+quad)*D_ + col] = pend_eu;
  hout[(size_t)(r0+quad)*D_ + col] = hc;
}

// ---------------------------------------------------------------------------
// Fused preamble (one dispatch).
// ---------------------------------------------------------------------------
__global__ __launch_bounds__(256)
void packall_k(const float* __restrict__ obs, ushort* __restrict__ obsH,
               const float* __restrict__ e1w, ushort* __restrict__ e1T,
               const float* __restrict__ e2w, ushort* __restrict__ e2T,
               const float* __restrict__ gWi, ushort* __restrict__ giT,
               const float* __restrict__ chw, __hip_bfloat16* __restrict__ bcatT,
               const float* __restrict__ uhw, __hip_bfloat16* __restrict__ uhwT,
               const float* __restrict__ uow, __hip_bfloat16* __restrict__ uowT,
               const float* __restrict__ v1w, __hip_bfloat16* __restrict__ v1wT,
               const float* __restrict__ v2w, __hip_bfloat16* __restrict__ v2wT)
{
  const int b = blockIdx.x, tid = threadIdx.x;
  if (b < 16384){
    int idx = b*256 + tid;
    obsH[idx] = f2hu(obs[idx]);
  } else if (b < 16416){
    int idx = (b-16384)*256 + tid;
    int n = idx >> 6, k = idx & 63;
    e1T[idx] = f2hu(e1w[k*128 + n]);
  } else if (b < 16480){
    int idx = (b-16416)*256 + tid;
    int n = idx >> 7, k = idx & 127;
    e2T[idx] = f2hu(e2w[k*128 + n]);
  } else if (b < 16672){
    int idx = (b-16480)*256 + tid;
    int n = idx >> 7, k = idx & 127;
    giT[idx] = f2hu(gWi[k*384 + n]);
  } else if (b < 16800){
    int idx = (b-16672)*256 + tid;
    int n = idx >> 7, k = idx & 127;
    float v = (n < 128) ? chw[k*128 + n] : chw[(128+k)*128 + (n-128)];
    bcatT[idx] = __float2bfloat16(v);
  } else if (b < 16928){
    int idx = (b-16800)*256 + tid;
    int r = idx >> 7, c = idx & 127;
    uhwT[c*256 + r] = __float2bfloat16(uhw[idx]);
  } else if (b < 16992){
    int idx = (b-16928)*256 + tid;
    int r = idx >> 7, c = idx & 127;
    uowT[c*128 + r] = __float2bfloat16(uow[idx]);
  } else if (b < 17120){
    int idx = (b-16992)*256 + tid;
    int r = idx >> 8, c = idx & 255;
    v1wT[c*128 + r] = __float2bfloat16(v1w[idx]);
  } else {
    int idx = (b-17120)*256 + tid;
    int r = idx >> 8, c = idx & 255;
    v2wT[c*256 + r] = __float2bfloat16(v2w[idx]);
  }
}

extern "C" void kernel_launch(void* const* d_in, const int* in_sizes, int n_in,
                              void* d_out, int out_size, void* d_ws, size_t ws_size,
                              hipStream_t stream) {
  const float* hidden = (const float*)d_in[0];
  const float* obs    = (const float*)d_in[1];
  const int*   dones  = (const int*)  d_in[2];
  const float* e1w = (const float*)d_in[3];
  const float* e1b = (const float*)d_in[4];
  const float* e2w = (const float*)d_in[5];
  const float* e2b = (const float*)d_in[6];
  const float* gWi = (const float*)d_in[7];
  const float* gbi = (const float*)d_in[8];
  const float* gWh = (const float*)d_in[9];
  const float* gbhn= (const float*)d_in[10];
  const float* chw = (const float*)d_in[11];
  const float* chb = (const float*)d_in[12];
  const float* cow = (const float*)d_in[13];
  const float* cob = (const float*)d_in[14];
  const float* uhw = (const float*)d_in[15];
  const float* uhb = (const float*)d_in[16];
  const float* uow = (const float*)d_in[17];
  const float* uob = (const float*)d_in[18];
  const float* v1w = (const float*)d_in[19];
  const float* v1b = (const float*)d_in[20];
  const float* v2w = (const float*)d_in[21];
  const float* v2b = (const float*)d_in[22];
  const float* vow = (const float*)d_in[23];
  const float* vob = (const float*)d_in[24];
  (void)in_sizes; (void)n_in; (void)out_size;

  float* out_hidden = (float*)d_out;
  float* out_values = (float*)d_out + (size_t)B_*D_;

  // Arena (float-slot offsets). Peak ~27.4M slots = 110 MB.
  float* ws = (float*)d_ws;
  ushort* obsH  = (ushort*)(ws);                      // [0, 2.10M)
  ushort* emb1H = (ushort*)(ws + 2097152);            // [2.10M, 6.29M)
  ushort* emb2H = (ushort*)(ws + 6291456);            // [6.29M, 10.49M)
  ushort* giH   = (ushort*)(ws + 10485760);           // [10.49M, 23.07M)
  __hip_bfloat16* Xe = (__hip_bfloat16*)(ws + 23068672); // [23.07M, 27.26M)
  ushort* wb    = (ushort*)(ws + 27262976);           // weights
  // post-GRU overlays (obs/emb/gi regions dead after grum):
  __hip_bfloat16* Xc    = (__hip_bfloat16*)(ws);              // [0, 4.19M)
  __hip_bfloat16* v1b16 = (__hip_bfloat16*)(ws + 4194304);    // [4.19M, 12.58M)
  if (ws_size < (size_t)27500000 * sizeof(float)) return;

  __hip_bfloat16* bcatT = (__hip_bfloat16*)wb;           // [256][128]
  __hip_bfloat16* uhwT  = (__hip_bfloat16*)wb + 32768;   // [128][256]
  __hip_bfloat16* uowT  = (__hip_bfloat16*)wb + 65536;   // [128][128]
  __hip_bfloat16* v1wT  = (__hip_bfloat16*)wb + 81920;   // [256][128]
  __hip_bfloat16* v2wT  = (__hip_bfloat16*)wb + 114688;  // [256][256]
  ushort* e1wT = wb + 180224;   // [128][64]  fp16
  ushort* e2wT = wb + 188416;   // [128][128] fp16
  ushort* gWiT = wb + 204800;   // [384][128] fp16

  dim3 blk(256);
  hipMemsetAsync(out_values, 0, (size_t)M_*sizeof(float), stream);
  packall_k<<<dim3(17376), blk, 0, stream>>>(
    obs, obsH, e1w, e1wT, e2w, e2wT, gWi, gWiT,
    chw, bcatT, uhw, uhwT, uow, uowT, v1w, v1wT, v2w, v2wT);

  // embeds + gi: single-term fp16 MFMA
  mgemmh_k<1><<<dim3(2,512), blk, 0, stream>>>(obsH,  e1wT, e1b, emb1H, M_, 128, 64);
  mgemmh_k<1><<<dim3(2,512), blk, 0, stream>>>(emb1H, e2wT, e2b, emb2H, M_, 128, 128);
  mgemmh_k<0><<<dim3(6,512), blk, 0, stream>>>(emb2H, gWiT, gbi, giH,   M_, 384, 128);

  // MFMA GRU
  grum8_k<<<dim3(128), dim3(512), 0, stream>>>(giH, hidden, dones, gWh, gbhn, Xe, out_hidden);

  for (int it=0; it<2; it++){
    couple2_k<<<dim3(T_*NE_), blk, 0, stream>>>(Xe, (const ushort*)bcatT, chb, cow, cob, Xc);
    updf_k<<<dim3(512), blk, 0, stream>>>(Xe, Xc, uhwT, uhb, uowT, uob, dones, Xe);
  }
  // value head: v1 GEMM, then fused v2+dot
  mgemm_k<1><<<dim3(2,512), blk, 0, stream>>>(Xe, v1wT, v1b, v1b16, M_, 256, 128);
  vhead2_k<<<dim3(2,512), blk, 0, stream>>>(v1b16, v2wT, v2b, vow, vob, out_values);
}

// Round 3
// 429.076 us; speedup vs baseline: 1.0155x; 1.0155x over previous
//
#include <hip/hip_runtime.h>
#include <hip/hip_bf16.h>
#include <math.h>

#define T_ 128
#define NE_ 64
#define NA_ 8
#define B_ 512
#define OBS_ 64
#define D_ 128
#define CH_ 128
#define VH_ 256
#define M_ (T_*B_)   // 65536

typedef __attribute__((ext_vector_type(8))) short bf16x8;
typedef __attribute__((ext_vector_type(8))) _Float16 f16x8;
typedef __attribute__((ext_vector_type(4))) float f32x4;

__device__ __forceinline__ float sigmoidf_(float x){ return 1.f/(1.f+__expf(-x)); }
__device__ __forceinline__ unsigned short f2bu(float v){
  __hip_bfloat16 b = __float2bfloat16(v);
  return __builtin_bit_cast(unsigned short, b);
}
__device__ __forceinline__ float bu2f(unsigned short u){
  return __builtin_bit_cast(float, (unsigned int)u << 16);
}
__device__ __forceinline__ unsigned short f2hu(float v){
  _Float16 h = (_Float16)v;
  return __builtin_bit_cast(unsigned short, h);
}
__device__ __forceinline__ float hu2f(unsigned short u){
  return (float)__builtin_bit_cast(_Float16, u);
}

// ---------------------------------------------------------------------------
// fp16 MFMA GEMM (single-term): C_fp16 = epi(A_fp16[M][K] @ B + bias)
// ---------------------------------------------------------------------------
template<int ACT>
__global__ __launch_bounds__(256)
void mgemmh_k(const ushort* __restrict__ A, const ushort* __restrict__ BT,
              const float* __restrict__ bias, ushort* __restrict__ C,
              int M, int N, int K)
{
  __shared__ ushort As[128*72];
  __shared__ ushort Bs[64*72];
  const int tid  = threadIdx.x;
  const int lane = tid & 63, wave = tid >> 6;
  const int wm = wave >> 1, wn = wave & 1;
  const int quad = lane >> 4, ln = lane & 15;
  const int n0 = blockIdx.x * 64;
  const int m0 = blockIdx.y * 128;

  f32x4 acc[4][2];
  #pragma unroll
  for (int i=0;i<4;i++)
    #pragma unroll
    for (int j=0;j<2;j++)
      #pragma unroll
      for (int r=0;r<4;r++) acc[i][j][r] = 0.f;

  for (int kc=0; kc<K; kc+=64){
    #pragma unroll
    for (int i=0;i<4;i++){
      int c8 = tid + i*256;
      int m = c8 >> 3, kq = (c8 & 7)*8;
      *(uint4*)&As[m*72+kq] = *(const uint4*)&A[(size_t)(m0+m)*K + kc + kq];
    }
    #pragma unroll
    for (int i=0;i<2;i++){
      int c8 = tid + i*256;
      int n = c8 >> 3, kq = (c8 & 7)*8;
      *(uint4*)&Bs[n*72+kq] = *(const uint4*)&BT[(size_t)(n0+n)*K + kc + kq];
    }
    __syncthreads();
    #pragma unroll
    for (int ks=0; ks<2; ks++){
      const int kq = ks*32 + quad*8;
      f16x8 af[4], bfv[2];
      #pragma unroll
      for (int mt=0;mt<4;mt++)
        af[mt] = *(const f16x8*)&As[(wm*64 + mt*16 + ln)*72 + kq];
      #pragma unroll
      for (int nt=0;nt<2;nt++)
        bfv[nt] = *(const f16x8*)&Bs[(wn*32 + nt*16 + ln)*72 + kq];
      #pragma unroll
      for (int mt=0;mt<4;mt++)
        #pragma unroll
        for (int nt=0;nt<2;nt++)
          acc[mt][nt] = __builtin_amdgcn_mfma_f32_16x16x32_f16(af[mt], bfv[nt], acc[mt][nt], 0,0,0);
    }
    __syncthreads();
  }

  float biasv[2];
  #pragma unroll
  for (int nt=0;nt<2;nt++) biasv[nt] = bias ? bias[n0 + wn*32 + nt*16 + ln] : 0.f;
  #pragma unroll
  for (int mt=0;mt<4;mt++){
    #pragma unroll
    for (int r=0;r<4;r++){
      int row = m0 + wm*64 + mt*16 + quad*4 + r;
      #pragma unroll
      for (int nt=0;nt<2;nt++){
        int col = n0 + wn*32 + nt*16 + ln;
        float v = acc[mt][nt][r] + biasv[nt];
        if (ACT==1) v = fmaxf(v, 0.f);
        C[(size_t)row*N + col] = f2hu(v);
      }
    }
  }
}

// ---------------------------------------------------------------------------
// bf16 MFMA GEMM (v1 head): BT = B^T [N,K] bf16; 128x128 tile, BK=128.
// ---------------------------------------------------------------------------
template<int ACT>
__global__ __launch_bounds__(256)
void mgemm_k(const __hip_bfloat16* __restrict__ A, const __hip_bfloat16* __restrict__ BT,
             const float* __restrict__ bias, __hip_bfloat16* __restrict__ Cb,
             int M, int N, int K)
{
  __shared__ ushort As[128*136];
  __shared__ ushort Bs[128*136];
  const int tid  = threadIdx.x;
  const int lane = tid & 63, wave = tid >> 6;
  const int wm = wave >> 1, wn = wave & 1;
  const int quad = lane >> 4, ln = lane & 15;
  const int n0 = blockIdx.x * 128;
  const int m0 = blockIdx.y * 128;

  f32x4 acc[4][4];
  #pragma unroll
  for (int i=0;i<4;i++)
    #pragma unroll
    for (int j=0;j<4;j++)
      #pragma unroll
      for (int r=0;r<4;r++) acc[i][j][r] = 0.f;

  for (int kc=0; kc<K; kc+=128){
    #pragma unroll
    for (int i=0;i<8;i++){
      int c8 = tid + i*256;
      int m = c8 >> 4, kq = (c8 & 15)*8;
      *(uint4*)&As[m*136 + kq] = *(const uint4*)&A[(size_t)(m0+m)*K + kc + kq];
    }
    #pragma unroll
    for (int i=0;i<8;i++){
      int c8 = tid + i*256;
      int n = c8 >> 4, kq = (c8 & 15)*8;
      *(uint4*)&Bs[n*136 + kq] = *(const uint4*)&BT[(size_t)(n0+n)*K + kc + kq];
    }
    __syncthreads();
    #pragma unroll
    for (int ks=0; ks<4; ks++){
      const int kq = ks*32 + quad*8;
      bf16x8 af[4], bfv[4];
      #pragma unroll
      for (int mt=0;mt<4;mt++)
        af[mt] = *(const bf16x8*)&As[(wm*64 + mt*16 + ln)*136 + kq];
      #pragma unroll
      for (int nt=0;nt<4;nt++)
        bfv[nt] = *(const bf16x8*)&Bs[(wn*64 + nt*16 + ln)*136 + kq];
      #pragma unroll
      for (int mt=0;mt<4;mt++)
        #pragma unroll
        for (int nt=0;nt<4;nt++)
          acc[mt][nt] = __builtin_amdgcn_mfma_f32_16x16x32_bf16(af[mt], bfv[nt], acc[mt][nt], 0,0,0);
    }
    __syncthreads();
  }

  float biasv[4];
  #pragma unroll
  for (int nt=0;nt<4;nt++) biasv[nt] = bias ? bias[n0 + wn*64 + nt*16 + ln] : 0.f;
  #pragma unroll
  for (int mt=0;mt<4;mt++){
    #pragma unroll
    for (int r=0;r<4;r++){
      int row = m0 + wm*64 + mt*16 + quad*4 + r;
      #pragma unroll
      for (int nt=0;nt<4;nt++){
        int col = n0 + wn*64 + nt*16 + ln;
        float v = acc[mt][nt][r] + biasv[nt];
        if (ACT==1) v = fmaxf(v, 0.f);
        Cb[(size_t)row*N + col] = __float2bfloat16(v);
      }
    }
  }
}

// ---------------------------------------------------------------------------
// Fused dpre+update.
// ---------------------------------------------------------------------------
__global__ __launch_bounds__(256)
void updf_k(const __hip_bfloat16* __restrict__ Xe, const __hip_bfloat16* __restrict__ Xc,
            const __hip_bfloat16* __restrict__ uhwT, const float* __restrict__ uhb,
            const __hip_bfloat16* __restrict__ uowT, const float* __restrict__ uob,
            const int* __restrict__ dones, __hip_bfloat16* __restrict__ XeOut)
{
  __shared__ ushort As[128*136];   // A-stage, then dpre tile
  __shared__ ushort Bs[128*136];
  const int tid  = threadIdx.x;
  const int lane = tid & 63, wave = tid >> 6;
  const int wm = wave >> 1, wn = wave & 1;
  const int quad = lane >> 4, ln = lane & 15;
  const int m0 = blockIdx.x * 128;

  f32x4 acc[4][4];
  #pragma unroll
  for (int i=0;i<4;i++)
    #pragma unroll
    for (int j=0;j<4;j++)
      #pragma unroll
      for (int r=0;r<4;r++) acc[i][j][r] = 0.f;

  // phase 1: dpre accumulate over K=256 (kc=0: Xe, kc=1: Xc)
  for (int kc=0; kc<2; kc++){
    const __hip_bfloat16* Ab = kc ? Xc : Xe;
    #pragma unroll
    for (int i=0;i<8;i++){
      int c8 = tid + i*256;
      int m = c8 >> 4, kq = (c8 & 15)*8;
      *(uint4*)&As[m*136 + kq] = *(const uint4*)&Ab[(size_t)(m0+m)*128 + kq];
    }
    #pragma unroll
    for (int i=0;i<8;i++){
      int c8 = tid + i*256;
      int n = c8 >> 4, kq = (c8 & 15)*8;
      *(uint4*)&Bs[n*136 + kq] = *(const uint4*)&uhwT[(size_t)n*256 + kc*128 + kq];
    }
    __syncthreads();
    #pragma unroll
    for (int ks=0; ks<4; ks++){
      const int kq = ks*32 + quad*8;
      bf16x8 af[4], bfv[4];
      #pragma unroll
      for (int mt=0;mt<4;mt++)
        af[mt] = *(const bf16x8*)&As[(wm*64 + mt*16 + ln)*136 + kq];
      #pragma unroll
      for (int nt=0;nt<4;nt++)
        bfv[nt] = *(const bf16x8*)&Bs[(wn*64 + nt*16 + ln)*136 + kq];
      #pragma unroll
      for (int mt=0;mt<4;mt++)
        #pragma unroll
        for (int nt=0;nt<4;nt++)
          acc[mt][nt] = __builtin_amdgcn_mfma_f32_16x16x32_bf16(af[mt], bfv[nt], acc[mt][nt], 0,0,0);
    }
    __syncthreads();
  }

  // stage uowT -> Bs, and dpre epilogue -> As (both free after last barrier)
  #pragma unroll
  for (int i=0;i<8;i++){
    int c8 = tid + i*256;
    int n = c8 >> 4, kq = (c8 & 15)*8;
    *(uint4*)&Bs[n*136 + kq] = *(const uint4*)&uowT[(size_t)n*128 + kq];
  }
  #pragma unroll
  for (int mt=0;mt<4;mt++){
    #pragma unroll
    for (int r=0;r<4;r++){
      int rl = wm*64 + mt*16 + quad*4 + r;
      #pragma unroll
      for (int nt=0;nt<4;nt++){
        int cl = wn*64 + nt*16 + ln;
        float v = fmaxf(acc[mt][nt][r] + uhb[cl], 0.f);
        As[rl*136 + cl] = f2bu(v);
      }
    }
  }
  __syncthreads();

  // phase 2: e = (e + relu(dpre @ uowT + uob)) * alive
  f32x4 acc2[4][4];
  #pragma unroll
  for (int i=0;i<4;i++)
    #pragma unroll
    for (int j=0;j<4;j++)
      #pragma unroll
      for (int r=0;r<4;r++) acc2[i][j][r] = 0.f;
  #pragma unroll
  for (int ks=0; ks<4; ks++){
    const int kq = ks*32 + quad*8;
    bf16x8 af[4], bfv[4];
    #pragma unroll
    for (int mt=0;mt<4;mt++)
      af[mt] = *(const bf16x8*)&As[(wm*64 + mt*16 + ln)*136 + kq];
    #pragma unroll
    for (int nt=0;nt<4;nt++)
      bfv[nt] = *(const bf16x8*)&Bs[(wn*64 + nt*16 + ln)*136 + kq];
    #pragma unroll
    for (int mt=0;mt<4;mt++)
      #pragma unroll
      for (int nt=0;nt<4;nt++)
        acc2[mt][nt] = __builtin_amdgcn_mfma_f32_16x16x32_bf16(af[mt], bfv[nt], acc2[mt][nt], 0,0,0);
  }
  #pragma unroll
  for (int mt=0;mt<4;mt++){
    #pragma unroll
    for (int r=0;r<4;r++){
      int row = m0 + wm*64 + mt*16 + quad*4 + r;
      float al = (dones[row]!=0) ? 0.f : 1.f;
      #pragma unroll
      for (int nt=0;nt<4;nt++){
        int cl = wn*64 + nt*16 + ln;
        float v = fmaxf(acc2[mt][nt][r] + uob[cl], 0.f);
        v += bu2f(((const ushort*)Xe)[(size_t)row*128 + cl]);
        v *= al;
        XeOut[(size_t)row*128 + cl] = __float2bfloat16(v);
      }
    }
  }
}

// ---------------------------------------------------------------------------
// Fused acat+coupling per (t,env).
// ---------------------------------------------------------------------------
__global__ __launch_bounds__(256)
void couple2_k(const __hip_bfloat16* __restrict__ Xe, const ushort* __restrict__ bcatT,
               const float* __restrict__ chb, const float* __restrict__ cow,
               const float* __restrict__ cob, __hip_bfloat16* __restrict__ ctxb)
{
  __shared__ ushort es16[8*136];
  __shared__ float ai[8][132], aj[8][132];
  __shared__ float cbw[CH_], cww[CH_], Cs[NA_][NA_];
  const int m0 = blockIdx.x * NA_;
  const int tid = threadIdx.x;
  const int lane = tid & 63, wave = tid >> 6;  // 4 waves
  const int quad = lane >> 4, ln = lane & 15;

  if (tid < 128){
    int j = tid >> 4, q = (tid & 15)*8;
    *(uint4*)&es16[j*136 + q] = *(const uint4*)((const ushort*)Xe + (size_t)(m0+j)*D_ + q);
    cbw[tid] = chb[tid]; cww[tid] = cow[tid];
  }
  __syncthreads();

  // acat MFMA: wave w covers cols w*64..w*64+63 (4 n-tiles)
  f32x4 acc[4];
  #pragma unroll
  for (int nt=0;nt<4;nt++)
    #pragma unroll
    for (int r=0;r<4;r++) acc[nt][r] = 0.f;
  #pragma unroll
  for (int ks=0; ks<4; ks++){
    bf16x8 af = *(const bf16x8*)&es16[(ln & 7)*136 + ks*32 + quad*8];
    #pragma unroll
    for (int nt=0;nt<4;nt++){
      int n = wave*64 + nt*16 + ln;
      bf16x8 bfv = *(const bf16x8*)&bcatT[(size_t)n*128 + ks*32 + quad*8];
      acc[nt] = __builtin_amdgcn_mfma_f32_16x16x32_bf16(af, bfv, acc[nt], 0,0,0);
    }
  }
  if (quad < 2){        // rows 0..7 live in quads 0,1
    #pragma unroll
    for (int nt=0;nt<4;nt++){
      int col = wave*64 + nt*16 + ln;
      #pragma unroll
      for (int r=0;r<4;r++){
        int row = quad*4 + r;
        float v = acc[nt][r];
        if (col < 128) ai[row][col] = v; else aj[row][col-128] = v;
      }
    }
  }
  __syncthreads();

  {
    int p = tid >> 2, q = tid & 3;
    int i = p >> 3, j = p & 7;
    float s = 0.f;
    #pragma unroll
    for (int h = 0; h < 32; h++){
      int hh = q*32 + h;
      s += fmaxf(ai[i][hh] + aj[j][hh] + cbw[hh], 0.f) * cww[hh];
    }
    s += __shfl_down(s, 2);
    s += __shfl_down(s, 1);
    if (q == 0) {
      float Cv = sigmoidf_(s + cob[0]);
      Cs[i][j] = (i==j) ? 0.f : Cv;
    }
  }
  __syncthreads();
  #pragma unroll
  for (int rep=0; rep<4; rep++){
    int idx = rep*256 + tid;
    int i = idx >> 7, d = idx & 127;
    float s = 0.f;
    #pragma unroll
    for (int j=0;j<NA_;j++) s = fmaf(Cs[i][j], bu2f(es16[j*136 + d]), s);
    ctxb[(size_t)(m0+i)*D_ + d] = __float2bfloat16(s);
  }
}

// ---------------------------------------------------------------------------
// Fused v2 + vout.
// ---------------------------------------------------------------------------
__global__ __launch_bounds__(256)
void vhead2_k(const __hip_bfloat16* __restrict__ v1, const __hip_bfloat16* __restrict__ v2wT,
              const float* __restrict__ v2b, const float* __restrict__ vow,
              const float* __restrict__ vob, float* __restrict__ values)
{
  __shared__ ushort As[128*136];
  __shared__ ushort Bs[128*136];
  const int tid  = threadIdx.x;
  const int lane = tid & 63, wave = tid >> 6;
  const int wm = wave >> 1, wn = wave & 1;
  const int quad = lane >> 4, ln = lane & 15;
  const int n0 = blockIdx.x * 128;
  const int m0 = blockIdx.y * 128;

  f32x4 acc[4][4];
  #pragma unroll
  for (int i=0;i<4;i++)
    #pragma unroll
    for (int j=0;j<4;j++)
      #pragma unroll
      for (int r=0;r<4;r++) acc[i][j][r] = 0.f;

  for (int kc=0; kc<2; kc++){
    #pragma unroll
    for (int i=0;i<8;i++){
      int c8 = tid + i*256;
      int m = c8 >> 4, kq = (c8 & 15)*8;
      *(uint4*)&As[m*136 + kq] = *(const uint4*)((const ushort*)v1 + (size_t)(m0+m)*256 + kc*128 + kq);
    }
    #pragma unroll
    for (int i=0;i<8;i++){
      int c8 = tid + i*256;
      int n = c8 >> 4, kq = (c8 & 15)*8;
      *(uint4*)&Bs[n*136 + kq] = *(const uint4*)((const ushort*)v2wT + (size_t)(n0+n)*256 + kc*128 + kq);
    }
    __syncthreads();
    #pragma unroll
    for (int ks=0; ks<4; ks++){
      const int kq = ks*32 + quad*8;
      bf16x8 af[4], bfv[4];
      #pragma unroll
      for (int mt=0;mt<4;mt++)
        af[mt] = *(const bf16x8*)&As[(wm*64 + mt*16 + ln)*136 + kq];
      #pragma unroll
      for (int nt=0;nt<4;nt++)
        bfv[nt] = *(const bf16x8*)&Bs[(wn*64 + nt*16 + ln)*136 + kq];
      #pragma unroll
      for (int mt=0;mt<4;mt++)
        #pragma unroll
        for (int nt=0;nt<4;nt++)
          acc[mt][nt] = __builtin_amdgcn_mfma_f32_16x16x32_bf16(af[mt], bfv[nt], acc[mt][nt], 0,0,0);
    }
    __syncthreads();
  }

  float v2bv[4], voww[4];
  #pragma unroll
  for (int nt=0;nt<4;nt++){
    int col = n0 + wn*64 + nt*16 + ln;
    v2bv[nt] = v2b[col];
    voww[nt] = vow[col];
  }
  float s[4][4];
  #pragma unroll
  for (int mt=0;mt<4;mt++)
    #pragma unroll
    for (int r=0;r<4;r++){
      float p = 0.f;
      #pragma unroll
      for (int nt=0;nt<4;nt++)
        p += fmaxf(acc[mt][nt][r] + v2bv[nt], 0.f) * voww[nt];
      s[mt][r] = p;
    }
  #pragma unroll
  for (int off=1; off<16; off<<=1)
    #pragma unroll
    for (int mt=0;mt<4;mt++)
      #pragma unroll
      for (int r=0;r<4;r++)
        s[mt][r] += __shfl_xor(s[mt][r], off);
  if (ln == 0){
    float add = (blockIdx.x == 0 && wn == 0) ? vob[0] : 0.f;
    #pragma unroll
    for (int mt=0;mt<4;mt++)
      #pragma unroll
      for (int r=0;r<4;r++)
        atomicAdd(&values[m0 + wm*64 + mt*16 + quad*4 + r], s[mt][r] + add);
  }
}

// ---------------------------------------------------------------------------
// MFMA GRU v10: depth-4 gi prefetch pipeline. gi[t+1..t+3] held as RAW fp16
// ushorts in statically-named registers (no convert -> no vmcnt wait at
// issue); each step issues gi[t+4] and converts only the t+1 buffer at step
// end: ~3 step-times of slack vs ~900cy HBM latency. LDS-only barrier keeps
// the loads in flight across steps. Unroll x4, static buffer rotation.
// ---------------------------------------------------------------------------
__global__ __launch_bounds__(512, 1)
void grum8_k(const ushort* __restrict__ gih, const float* __restrict__ hidden0,
             const int* __restrict__ dones, const float* __restrict__ gWh,
             const float* __restrict__ bhn, __hip_bfloat16* __restrict__ eb_out,
             float* __restrict__ hout)
{
  __shared__ ushort wstg[32*392];
  __shared__ ushort hb[2][16*136];
  __shared__ float  dnS[T_*4];
  const int tid  = threadIdx.x;
  const int lane = tid & 63, wave = tid >> 6;
  const int quad = lane >> 4, ln = lane & 15;
  const int r0   = blockIdx.x * 4;
  const int col  = wave*16 + ln;
  const int lnb  = ln & 12;

  dnS[tid] = (dones[(size_t)(tid>>2)*B_ + r0 + (tid&3)] != 0) ? 1.f : 0.f;
  const float bhnr = bhn[col];

  for (int i=tid; i<16*136; i+=512){ hb[0][i]=0; hb[1][i]=0; }

  f16x8 bf[3][4];
  #pragma unroll
  for (int kc=0; kc<4; kc++){
    for (int i=tid; i<32*384; i+=512){
      int kk = i/384, c = i - kk*384;
      wstg[kk*392 + c] = f2hu(gWh[(size_t)(kc*32+kk)*384 + c]);
    }
    __syncthreads();
    #pragma unroll
    for (int g=0; g<3; g++){
      int c = g*128 + col;
      ushort tmp[8];
      #pragma unroll
      for (int j=0;j<8;j++) tmp[j] = wstg[(quad*8+j)*392 + c];
      bf[g][kc] = *(const f16x8*)tmp;
    }
    __syncthreads();
  }

  float hc = hidden0[(size_t)(r0+quad)*D_ + col];
  if (dnS[quad] > 0.5f) hc = 0.f;
  hb[0][(quad*4)*136 + col] = f2hu(hc);
  __syncthreads();

  const ushort* gbase = gih + ((size_t)(r0+quad))*384;
  const size_t  gstep = (size_t)B_*384;

  // current-step gates (float) + depth-3 raw fp16 prefetch buffers
  float c_r, c_z, c_n;
  c_r = hu2f(gbase[col]); c_z = hu2f(gbase[col+128]); c_n = hu2f(gbase[col+256]);
  ushort aR,aZ,aN, bR,bZ,bN, cR,cZ,cN, dR,dZ,dN;
  { const ushort* gp = gbase + 1*gstep; aR = gp[col]; aZ = gp[col+128]; aN = gp[col+256]; }
  { const ushort* gp = gbase + 2*gstep; bR = gp[col]; bZ = gp[col+128]; bN = gp[col+256]; }
  { const ushort* gp = gbase + 3*gstep; cR = gp[col]; cZ = gp[col+128]; cN = gp[col+256]; }
  dR=0; dZ=0; dN=0;

  ushort pend_eu = 0;

#define GSTEP(t, IR,IZ,IN, OR,OZ,ON)                                          \
  {                                                                           \
    if ((t) > 0)                                                              \
      ((ushort*)eb_out)[((size_t)((t)-1)*B_ + r0+quad)*D_ + col] = pend_eu;   \
    { int tl = (t)+4; if (tl > T_-1) tl = T_-1;                               \
      const ushort* gp = gbase + (size_t)tl*gstep;                            \
      OR = gp[col]; OZ = gp[col+128]; ON = gp[col+256]; }                     \
    const ushort* hbuf = hb[(t)&1];                                           \
    f32x4 accA[3], accB[3];                                                   \
    _Pragma("unroll")                                                         \
    for (int g=0;g<3;g++){                                                    \
      _Pragma("unroll")                                                       \
      for (int r=0;r<4;r++){ accA[g][r]=0.f; accB[g][r]=0.f; }                \
    }                                                                         \
    _Pragma("unroll")                                                         \
    for (int ks=0; ks<2; ks++){                                               \
      f16x8 ahA = *(const f16x8*)&hbuf[lnb*136 + (2*ks  )*32 + quad*8];       \
      f16x8 ahB = *(const f16x8*)&hbuf[lnb*136 + (2*ks+1)*32 + quad*8];       \
      _Pragma("unroll")                                                       \
      for (int g=0;g<3;g++){                                                  \
        accA[g] = __builtin_amdgcn_mfma_f32_16x16x32_f16(ahA, bf[g][2*ks  ], accA[g], 0,0,0); \
        accB[g] = __builtin_amdgcn_mfma_f32_16x16x32_f16(ahB, bf[g][2*ks+1], accB[g], 0,0,0); \
      }                                                                       \
    }                                                                         \
    const float dnow  = dnS[(t)*4 + quad];                                    \
    const float dnext = ((t)+1 < T_) ? dnS[((t)+1)*4 + quad] : 0.f;           \
    float rg = sigmoidf_(c_r + accA[0][0] + accB[0][0]);                      \
    float zg = sigmoidf_(c_z + accA[1][0] + accB[1][0]);                      \
    float x  = c_n + rg*(accA[2][0] + accB[2][0] + bhnr);                     \
    float ng = 2.f/(1.f+__expf(-2.f*x)) - 1.f;                                \
    float hnew = (1.f - zg)*ng + zg*hc;                                       \
    pend_eu = f2bu(hnew*(1.f-dnow));                                          \
    float hv = (dnext > 0.5f) ? 0.f : hnew;                                   \
    hc = hv;                                                                  \
    hb[((t)+1)&1][(quad*4)*136 + col] = f2hu(hv);                             \
    asm volatile("s_waitcnt lgkmcnt(0)\n\ts_barrier" ::: "memory");           \
    c_r = hu2f(IR); c_z = hu2f(IZ); c_n = hu2f(IN);                           \
  }

  for (int t=0; t<T_; t+=4){
    GSTEP(t+0, aR,aZ,aN, dR,dZ,dN);
    GSTEP(t+1, bR,bZ,bN, aR,aZ,aN);
    GSTEP(t+2, cR,cZ,cN, bR,bZ,bN);
    GSTEP(t+3, dR,dZ,dN, cR,cZ,cN);
  }
#undef GSTEP

  ((ushort*)eb_out)[((size_t)(T_-1)*B_ + r0+quad)*D_ + col] = pend_eu;
  hout[(size_t)(r0+quad)*D_ + col] = hc;
}

// ---------------------------------------------------------------------------
// Fused preamble (one dispatch).
// ---------------------------------------------------------------------------
__global__ __launch_bounds__(256)
void packall_k(const float* __restrict__ obs, ushort* __restrict__ obsH,
               const float* __restrict__ e1w, ushort* __restrict__ e1T,
               const float* __restrict__ e2w, ushort* __restrict__ e2T,
               const float* __restrict__ gWi, ushort* __restrict__ giT,
               const float* __restrict__ chw, __hip_bfloat16* __restrict__ bcatT,
               const float* __restrict__ uhw, __hip_bfloat16* __restrict__ uhwT,
               const float* __restrict__ uow, __hip_bfloat16* __restrict__ uowT,
               const float* __restrict__ v1w, __hip_bfloat16* __restrict__ v1wT,
               const float* __restrict__ v2w, __hip_bfloat16* __restrict__ v2wT)
{
  const int b = blockIdx.x, tid = threadIdx.x;
  if (b < 16384){
    int idx = b*256 + tid;
    obsH[idx] = f2hu(obs[idx]);
  } else if (b < 16416){
    int idx = (b-16384)*256 + tid;
    int n = idx >> 6, k = idx & 63;
    e1T[idx] = f2hu(e1w[k*128 + n]);
  } else if (b < 16480){
    int idx = (b-16416)*256 + tid;
    int n = idx >> 7, k = idx & 127;
    e2T[idx] = f2hu(e2w[k*128 + n]);
  } else if (b < 16672){
    int idx = (b-16480)*256 + tid;
    int n = idx >> 7, k = idx & 127;
    giT[idx] = f2hu(gWi[k*384 + n]);
  } else if (b < 16800){
    int idx = (b-16672)*256 + tid;
    int n = idx >> 7, k = idx & 127;
    float v = (n < 128) ? chw[k*128 + n] : chw[(128+k)*128 + (n-128)];
    bcatT[idx] = __float2bfloat16(v);
  } else if (b < 16928){
    int idx = (b-16800)*256 + tid;
    int r = idx >> 7, c = idx & 127;
    uhwT[c*256 + r] = __float2bfloat16(uhw[idx]);
  } else if (b < 16992){
    int idx = (b-16928)*256 + tid;
    int r = idx >> 7, c = idx & 127;
    uowT[c*128 + r] = __float2bfloat16(uow[idx]);
  } else if (b < 17120){
    int idx = (b-16992)*256 + tid;
    int r = idx >> 8, c = idx & 255;
    v1wT[c*128 + r] = __float2bfloat16(v1w[idx]);
  } else {
    int idx = (b-17120)*256 + tid;
    int r = idx >> 8, c = idx & 255;
    v2wT[c*256 + r] = __float2bfloat16(v2w[idx]);
  }
}

extern "C" void kernel_launch(void* const* d_in, const int* in_sizes, int n_in,
                              void* d_out, int out_size, void* d_ws, size_t ws_size,
                              hipStream_t stream) {
  const float* hidden = (const float*)d_in[0];
  const float* obs    = (const float*)d_in[1];
  const int*   dones  = (const int*)  d_in[2];
  const float* e1w = (const float*)d_in[3];
  const float* e1b = (const float*)d_in[4];
  const float* e2w = (const float*)d_in[5];
  const float* e2b = (const float*)d_in[6];
  const float* gWi = (const float*)d_in[7];
  const float* gbi = (const float*)d_in[8];
  const float* gWh = (const float*)d_in[9];
  const float* gbhn= (const float*)d_in[10];
  const float* chw = (const float*)d_in[11];
  const float* chb = (const float*)d_in[12];
  const float* cow = (const float*)d_in[13];
  const float* cob = (const float*)d_in[14];
  const float* uhw = (const float*)d_in[15];
  const float* uhb = (const float*)d_in[16];
  const float* uow = (const float*)d_in[17];
  const float* uob = (const float*)d_in[18];
  const float* v1w = (const float*)d_in[19];
  const float* v1b = (const float*)d_in[20];
  const float* v2w = (const float*)d_in[21];
  const float* v2b = (const float*)d_in[22];
  const float* vow = (const float*)d_in[23];
  const float* vob = (const float*)d_in[24];
  (void)in_sizes; (void)n_in; (void)out_size;

  float* out_hidden = (float*)d_out;
  float* out_values = (float*)d_out + (size_t)B_*D_;

  // Arena (float-slot offsets). Peak ~27.4M slots = 110 MB.
  float* ws = (float*)d_ws;
  ushort* obsH  = (ushort*)(ws);                      // [0, 2.10M)
  ushort* emb1H = (ushort*)(ws + 2097152);            // [2.10M, 6.29M)
  ushort* emb2H = (ushort*)(ws + 6291456);            // [6.29M, 10.49M)
  ushort* giH   = (ushort*)(ws + 10485760);           // [10.49M, 23.07M)
  __hip_bfloat16* Xe = (__hip_bfloat16*)(ws + 23068672); // [23.07M, 27.26M)
  ushort* wb    = (ushort*)(ws + 27262976);           // weights
  // post-GRU overlays (obs/emb/gi regions dead after grum):
  __hip_bfloat16* Xc    = (__hip_bfloat16*)(ws);              // [0, 4.19M)
  __hip_bfloat16* v1b16 = (__hip_bfloat16*)(ws + 4194304);    // [4.19M, 12.58M)
  if (ws_size < (size_t)27500000 * sizeof(float)) return;

  __hip_bfloat16* bcatT = (__hip_bfloat16*)wb;           // [256][128]
  __hip_bfloat16* uhwT  = (__hip_bfloat16*)wb + 32768;   // [128][256]
  __hip_bfloat16* uowT  = (__hip_bfloat16*)wb + 65536;   // [128][128]
  __hip_bfloat16* v1wT  = (__hip_bfloat16*)wb + 81920;   // [256][128]
  __hip_bfloat16* v2wT  = (__hip_bfloat16*)wb + 114688;  // [256][256]
  ushort* e1wT = wb + 180224;   // [128][64]  fp16
  ushort* e2wT = wb + 188416;   // [128][128] fp16
  ushort* gWiT = wb + 204800;   // [384][128] fp16

  dim3 blk(256);
  hipMemsetAsync(out_values, 0, (size_t)M_*sizeof(float), stream);
  packall_k<<<dim3(17376), blk, 0, stream>>>(
    obs, obsH, e1w, e1wT, e2w, e2wT, gWi, gWiT,
    chw, bcatT, uhw, uhwT, uow, uowT, v1w, v1wT, v2w, v2wT);

  // embeds + gi: single-term fp16 MFMA
  mgemmh_k<1><<<dim3(2,512), blk, 0, stream>>>(obsH,  e1wT, e1b, emb1H, M_, 128, 64);
  mgemmh_k<1><<<dim3(2,512), blk, 0, stream>>>(emb1H, e2wT, e2b, emb2H, M_, 128, 128);
  mgemmh_k<0><<<dim3(6,512), blk, 0, stream>>>(emb2H, gWiT, gbi, giH,   M_, 384, 128);

  // MFMA GRU
  grum8_k<<<dim3(128), dim3(512), 0, stream>>>(giH, hidden, dones, gWh, gbhn, Xe, out_hidden);

  for (int it=0; it<2; it++){
    couple2_k<<<dim3(T_*NE_), blk, 0, stream>>>(Xe, (const ushort*)bcatT, chb, cow, cob, Xc);
    updf_k<<<dim3(512), blk, 0, stream>>>(Xe, Xc, uhwT, uhb, uowT, uob, dones, Xe);
  }
  // value head: v1 GEMM, then fused v2+dot
  mgemm_k<1><<<dim3(2,512), blk, 0, stream>>>(Xe, v1wT, v1b, v1b16, M_, 256, 128);
  vhead2_k<<<dim3(2,512), blk, 0, stream>>>(v1b16, v2wT, v2b, vow, vob, out_values);
}

// Round 4
// 427.663 us; speedup vs baseline: 1.0188x; 1.0033x over previous
//
#include <hip/hip_runtime.h>
#include <hip/hip_bf16.h>
#include <math.h>

#define T_ 128
#define NE_ 64
#define NA_ 8
#define B_ 512
#define OBS_ 64
#define D_ 128
#define CH_ 128
#define VH_ 256
#define M_ (T_*B_)   // 65536

typedef __attribute__((ext_vector_type(8))) short bf16x8;
typedef __attribute__((ext_vector_type(8))) _Float16 f16x8;
typedef __attribute__((ext_vector_type(4))) float f32x4;

__device__ __forceinline__ float sigmoidf_(float x){ return 1.f/(1.f+__expf(-x)); }
__device__ __forceinline__ unsigned short f2bu(float v){
  __hip_bfloat16 b = __float2bfloat16(v);
  return __builtin_bit_cast(unsigned short, b);
}
__device__ __forceinline__ float bu2f(unsigned short u){
  return __builtin_bit_cast(float, (unsigned int)u << 16);
}
__device__ __forceinline__ unsigned short f2hu(float v){
  _Float16 h = (_Float16)v;
  return __builtin_bit_cast(unsigned short, h);
}
__device__ __forceinline__ float hu2f(unsigned short u){
  return (float)__builtin_bit_cast(_Float16, u);
}

// ---------------------------------------------------------------------------
// fp16 MFMA GEMM (single-term): C_fp16 = epi(A_fp16[M][K] @ B + bias)
// ---------------------------------------------------------------------------
template<int ACT>
__global__ __launch_bounds__(256)
void mgemmh_k(const ushort* __restrict__ A, const ushort* __restrict__ BT,
              const float* __restrict__ bias, ushort* __restrict__ C,
              int M, int N, int K)
{
  __shared__ ushort As[128*72];
  __shared__ ushort Bs[64*72];
  const int tid  = threadIdx.x;
  const int lane = tid & 63, wave = tid >> 6;
  const int wm = wave >> 1, wn = wave & 1;
  const int quad = lane >> 4, ln = lane & 15;
  const int n0 = blockIdx.x * 64;
  const int m0 = blockIdx.y * 128;

  f32x4 acc[4][2];
  #pragma unroll
  for (int i=0;i<4;i++)
    #pragma unroll
    for (int j=0;j<2;j++)
      #pragma unroll
      for (int r=0;r<4;r++) acc[i][j][r] = 0.f;

  for (int kc=0; kc<K; kc+=64){
    #pragma unroll
    for (int i=0;i<4;i++){
      int c8 = tid + i*256;
      int m = c8 >> 3, kq = (c8 & 7)*8;
      *(uint4*)&As[m*72+kq] = *(const uint4*)&A[(size_t)(m0+m)*K + kc + kq];
    }
    #pragma unroll
    for (int i=0;i<2;i++){
      int c8 = tid + i*256;
      int n = c8 >> 3, kq = (c8 & 7)*8;
      *(uint4*)&Bs[n*72+kq] = *(const uint4*)&BT[(size_t)(n0+n)*K + kc + kq];
    }
    __syncthreads();
    #pragma unroll
    for (int ks=0; ks<2; ks++){
      const int kq = ks*32 + quad*8;
      f16x8 af[4], bfv[2];
      #pragma unroll
      for (int mt=0;mt<4;mt++)
        af[mt] = *(const f16x8*)&As[(wm*64 + mt*16 + ln)*72 + kq];
      #pragma unroll
      for (int nt=0;nt<2;nt++)
        bfv[nt] = *(const f16x8*)&Bs[(wn*32 + nt*16 + ln)*72 + kq];
      #pragma unroll
      for (int mt=0;mt<4;mt++)
        #pragma unroll
        for (int nt=0;nt<2;nt++)
          acc[mt][nt] = __builtin_amdgcn_mfma_f32_16x16x32_f16(af[mt], bfv[nt], acc[mt][nt], 0,0,0);
    }
    __syncthreads();
  }

  float biasv[2];
  #pragma unroll
  for (int nt=0;nt<2;nt++) biasv[nt] = bias ? bias[n0 + wn*32 + nt*16 + ln] : 0.f;
  #pragma unroll
  for (int mt=0;mt<4;mt++){
    #pragma unroll
    for (int r=0;r<4;r++){
      int row = m0 + wm*64 + mt*16 + quad*4 + r;
      #pragma unroll
      for (int nt=0;nt<2;nt++){
        int col = n0 + wn*32 + nt*16 + ln;
        float v = acc[mt][nt][r] + biasv[nt];
        if (ACT==1) v = fmaxf(v, 0.f);
        C[(size_t)row*N + col] = f2hu(v);
      }
    }
  }
}

// ---------------------------------------------------------------------------
// bf16 MFMA GEMM (v1 head): BT = B^T [N,K] bf16; 128x128 tile, BK=128.
// ---------------------------------------------------------------------------
template<int ACT>
__global__ __launch_bounds__(256)
void mgemm_k(const __hip_bfloat16* __restrict__ A, const __hip_bfloat16* __restrict__ BT,
             const float* __restrict__ bias, __hip_bfloat16* __restrict__ Cb,
             int M, int N, int K)
{
  __shared__ ushort As[128*136];
  __shared__ ushort Bs[128*136];
  const int tid  = threadIdx.x;
  const int lane = tid & 63, wave = tid >> 6;
  const int wm = wave >> 1, wn = wave & 1;
  const int quad = lane >> 4, ln = lane & 15;
  const int n0 = blockIdx.x * 128;
  const int m0 = blockIdx.y * 128;

  f32x4 acc[4][4];
  #pragma unroll
  for (int i=0;i<4;i++)
    #pragma unroll
    for (int j=0;j<4;j++)
      #pragma unroll
      for (int r=0;r<4;r++) acc[i][j][r] = 0.f;

  for (int kc=0; kc<K; kc+=128){
    #pragma unroll
    for (int i=0;i<8;i++){
      int c8 = tid + i*256;
      int m = c8 >> 4, kq = (c8 & 15)*8;
      *(uint4*)&As[m*136 + kq] = *(const uint4*)&A[(size_t)(m0+m)*K + kc + kq];
    }
    #pragma unroll
    for (int i=0;i<8;i++){
      int c8 = tid + i*256;
      int n = c8 >> 4, kq = (c8 & 15)*8;
      *(uint4*)&Bs[n*136 + kq] = *(const uint4*)&BT[(size_t)(n0+n)*K + kc + kq];
    }
    __syncthreads();
    #pragma unroll
    for (int ks=0; ks<4; ks++){
      const int kq = ks*32 + quad*8;
      bf16x8 af[4], bfv[4];
      #pragma unroll
      for (int mt=0;mt<4;mt++)
        af[mt] = *(const bf16x8*)&As[(wm*64 + mt*16 + ln)*136 + kq];
      #pragma unroll
      for (int nt=0;nt<4;nt++)
        bfv[nt] = *(const bf16x8*)&Bs[(wn*64 + nt*16 + ln)*136 + kq];
      #pragma unroll
      for (int mt=0;mt<4;mt++)
        #pragma unroll
        for (int nt=0;nt<4;nt++)
          acc[mt][nt] = __builtin_amdgcn_mfma_f32_16x16x32_bf16(af[mt], bfv[nt], acc[mt][nt], 0,0,0);
    }
    __syncthreads();
  }

  float biasv[4];
  #pragma unroll
  for (int nt=0;nt<4;nt++) biasv[nt] = bias ? bias[n0 + wn*64 + nt*16 + ln] : 0.f;
  #pragma unroll
  for (int mt=0;mt<4;mt++){
    #pragma unroll
    for (int r=0;r<4;r++){
      int row = m0 + wm*64 + mt*16 + quad*4 + r;
      #pragma unroll
      for (int nt=0;nt<4;nt++){
        int col = n0 + wn*64 + nt*16 + ln;
        float v = acc[mt][nt][r] + biasv[nt];
        if (ACT==1) v = fmaxf(v, 0.f);
        Cb[(size_t)row*N + col] = __float2bfloat16(v);
      }
    }
  }
}

// ---------------------------------------------------------------------------
// Fused dpre+update.
// ---------------------------------------------------------------------------
__global__ __launch_bounds__(256)
void updf_k(const __hip_bfloat16* __restrict__ Xe, const __hip_bfloat16* __restrict__ Xc,
            const __hip_bfloat16* __restrict__ uhwT, const float* __restrict__ uhb,
            const __hip_bfloat16* __restrict__ uowT, const float* __restrict__ uob,
            const int* __restrict__ dones, __hip_bfloat16* __restrict__ XeOut)
{
  __shared__ ushort As[128*136];   // A-stage, then dpre tile
  __shared__ ushort Bs[128*136];
  const int tid  = threadIdx.x;
  const int lane = tid & 63, wave = tid >> 6;
  const int wm = wave >> 1, wn = wave & 1;
  const int quad = lane >> 4, ln = lane & 15;
  const int m0 = blockIdx.x * 128;

  f32x4 acc[4][4];
  #pragma unroll
  for (int i=0;i<4;i++)
    #pragma unroll
    for (int j=0;j<4;j++)
      #pragma unroll
      for (int r=0;r<4;r++) acc[i][j][r] = 0.f;

  // phase 1: dpre accumulate over K=256 (kc=0: Xe, kc=1: Xc)
  for (int kc=0; kc<2; kc++){
    const __hip_bfloat16* Ab = kc ? Xc : Xe;
    #pragma unroll
    for (int i=0;i<8;i++){
      int c8 = tid + i*256;
      int m = c8 >> 4, kq = (c8 & 15)*8;
      *(uint4*)&As[m*136 + kq] = *(const uint4*)&Ab[(size_t)(m0+m)*128 + kq];
    }
    #pragma unroll
    for (int i=0;i<8;i++){
      int c8 = tid + i*256;
      int n = c8 >> 4, kq = (c8 & 15)*8;
      *(uint4*)&Bs[n*136 + kq] = *(const uint4*)&uhwT[(size_t)n*256 + kc*128 + kq];
    }
    __syncthreads();
    #pragma unroll
    for (int ks=0; ks<4; ks++){
      const int kq = ks*32 + quad*8;
      bf16x8 af[4], bfv[4];
      #pragma unroll
      for (int mt=0;mt<4;mt++)
        af[mt] = *(const bf16x8*)&As[(wm*64 + mt*16 + ln)*136 + kq];
      #pragma unroll
      for (int nt=0;nt<4;nt++)
        bfv[nt] = *(const bf16x8*)&Bs[(wn*64 + nt*16 + ln)*136 + kq];
      #pragma unroll
      for (int mt=0;mt<4;mt++)
        #pragma unroll
        for (int nt=0;nt<4;nt++)
          acc[mt][nt] = __builtin_amdgcn_mfma_f32_16x16x32_bf16(af[mt], bfv[nt], acc[mt][nt], 0,0,0);
    }
    __syncthreads();
  }

  // stage uowT -> Bs, and dpre epilogue -> As (both free after last barrier)
  #pragma unroll
  for (int i=0;i<8;i++){
    int c8 = tid + i*256;
    int n = c8 >> 4, kq = (c8 & 15)*8;
    *(uint4*)&Bs[n*136 + kq] = *(const uint4*)&uowT[(size_t)n*128 + kq];
  }
  #pragma unroll
  for (int mt=0;mt<4;mt++){
    #pragma unroll
    for (int r=0;r<4;r++){
      int rl = wm*64 + mt*16 + quad*4 + r;
      #pragma unroll
      for (int nt=0;nt<4;nt++){
        int cl = wn*64 + nt*16 + ln;
        float v = fmaxf(acc[mt][nt][r] + uhb[cl], 0.f);
        As[rl*136 + cl] = f2bu(v);
      }
    }
  }
  __syncthreads();

  // phase 2: e = (e + relu(dpre @ uowT + uob)) * alive
  f32x4 acc2[4][4];
  #pragma unroll
  for (int i=0;i<4;i++)
    #pragma unroll
    for (int j=0;j<4;j++)
      #pragma unroll
      for (int r=0;r<4;r++) acc2[i][j][r] = 0.f;
  #pragma unroll
  for (int ks=0; ks<4; ks++){
    const int kq = ks*32 + quad*8;
    bf16x8 af[4], bfv[4];
    #pragma unroll
    for (int mt=0;mt<4;mt++)
      af[mt] = *(const bf16x8*)&As[(wm*64 + mt*16 + ln)*136 + kq];
    #pragma unroll
    for (int nt=0;nt<4;nt++)
      bfv[nt] = *(const bf16x8*)&Bs[(wn*64 + nt*16 + ln)*136 + kq];
    #pragma unroll
    for (int mt=0;mt<4;mt++)
      #pragma unroll
      for (int nt=0;nt<4;nt++)
        acc2[mt][nt] = __builtin_amdgcn_mfma_f32_16x16x32_bf16(af[mt], bfv[nt], acc2[mt][nt], 0,0,0);
  }
  #pragma unroll
  for (int mt=0;mt<4;mt++){
    #pragma unroll
    for (int r=0;r<4;r++){
      int row = m0 + wm*64 + mt*16 + quad*4 + r;
      float al = (dones[row]!=0) ? 0.f : 1.f;
      #pragma unroll
      for (int nt=0;nt<4;nt++){
        int cl = wn*64 + nt*16 + ln;
        float v = fmaxf(acc2[mt][nt][r] + uob[cl], 0.f);
        v += bu2f(((const ushort*)Xe)[(size_t)row*128 + cl]);
        v *= al;
        XeOut[(size_t)row*128 + cl] = __float2bfloat16(v);
      }
    }
  }
}

// ---------------------------------------------------------------------------
// Fused acat+coupling per (t,env).
// ---------------------------------------------------------------------------
__global__ __launch_bounds__(256)
void couple2_k(const __hip_bfloat16* __restrict__ Xe, const ushort* __restrict__ bcatT,
               const float* __restrict__ chb, const float* __restrict__ cow,
               const float* __restrict__ cob, __hip_bfloat16* __restrict__ ctxb)
{
  __shared__ ushort es16[8*136];
  __shared__ float ai[8][132], aj[8][132];
  __shared__ float cbw[CH_], cww[CH_], Cs[NA_][NA_];
  const int m0 = blockIdx.x * NA_;
  const int tid = threadIdx.x;
  const int lane = tid & 63, wave = tid >> 6;  // 4 waves
  const int quad = lane >> 4, ln = lane & 15;

  if (tid < 128){
    int j = tid >> 4, q = (tid & 15)*8;
    *(uint4*)&es16[j*136 + q] = *(const uint4*)((const ushort*)Xe + (size_t)(m0+j)*D_ + q);
    cbw[tid] = chb[tid]; cww[tid] = cow[tid];
  }
  __syncthreads();

  // acat MFMA: wave w covers cols w*64..w*64+63 (4 n-tiles)
  f32x4 acc[4];
  #pragma unroll
  for (int nt=0;nt<4;nt++)
    #pragma unroll
    for (int r=0;r<4;r++) acc[nt][r] = 0.f;
  #pragma unroll
  for (int ks=0; ks<4; ks++){
    bf16x8 af = *(const bf16x8*)&es16[(ln & 7)*136 + ks*32 + quad*8];
    #pragma unroll
    for (int nt=0;nt<4;nt++){
      int n = wave*64 + nt*16 + ln;
      bf16x8 bfv = *(const bf16x8*)&bcatT[(size_t)n*128 + ks*32 + quad*8];
      acc[nt] = __builtin_amdgcn_mfma_f32_16x16x32_bf16(af, bfv, acc[nt], 0,0,0);
    }
  }
  if (quad < 2){        // rows 0..7 live in quads 0,1
    #pragma unroll
    for (int nt=0;nt<4;nt++){
      int col = wave*64 + nt*16 + ln;
      #pragma unroll
      for (int r=0;r<4;r++){
        int row = quad*4 + r;
        float v = acc[nt][r];
        if (col < 128) ai[row][col] = v; else aj[row][col-128] = v;
      }
    }
  }
  __syncthreads();

  {
    int p = tid >> 2, q = tid & 3;
    int i = p >> 3, j = p & 7;
    float s = 0.f;
    #pragma unroll
    for (int h = 0; h < 32; h++){
      int hh = q*32 + h;
      s += fmaxf(ai[i][hh] + aj[j][hh] + cbw[hh], 0.f) * cww[hh];
    }
    s += __shfl_down(s, 2);
    s += __shfl_down(s, 1);
    if (q == 0) {
      float Cv = sigmoidf_(s + cob[0]);
      Cs[i][j] = (i==j) ? 0.f : Cv;
    }
  }
  __syncthreads();
  #pragma unroll
  for (int rep=0; rep<4; rep++){
    int idx = rep*256 + tid;
    int i = idx >> 7, d = idx & 127;
    float s = 0.f;
    #pragma unroll
    for (int j=0;j<NA_;j++) s = fmaf(Cs[i][j], bu2f(es16[j*136 + d]), s);
    ctxb[(size_t)(m0+i)*D_ + d] = __float2bfloat16(s);
  }
}

// ---------------------------------------------------------------------------
// Fused v2 + vout.
// ---------------------------------------------------------------------------
__global__ __launch_bounds__(256)
void vhead2_k(const __hip_bfloat16* __restrict__ v1, const __hip_bfloat16* __restrict__ v2wT,
              const float* __restrict__ v2b, const float* __restrict__ vow,
              const float* __restrict__ vob, float* __restrict__ values)
{
  __shared__ ushort As[128*136];
  __shared__ ushort Bs[128*136];
  const int tid  = threadIdx.x;
  const int lane = tid & 63, wave = tid >> 6;
  const int wm = wave >> 1, wn = wave & 1;
  const int quad = lane >> 4, ln = lane & 15;
  const int n0 = blockIdx.x * 128;
  const int m0 = blockIdx.y * 128;

  f32x4 acc[4][4];
  #pragma unroll
  for (int i=0;i<4;i++)
    #pragma unroll
    for (int j=0;j<4;j++)
      #pragma unroll
      for (int r=0;r<4;r++) acc[i][j][r] = 0.f;

  for (int kc=0; kc<2; kc++){
    #pragma unroll
    for (int i=0;i<8;i++){
      int c8 = tid + i*256;
      int m = c8 >> 4, kq = (c8 & 15)*8;
      *(uint4*)&As[m*136 + kq] = *(const uint4*)((const ushort*)v1 + (size_t)(m0+m)*256 + kc*128 + kq);
    }
    #pragma unroll
    for (int i=0;i<8;i++){
      int c8 = tid + i*256;
      int n = c8 >> 4, kq = (c8 & 15)*8;
      *(uint4*)&Bs[n*136 + kq] = *(const uint4*)((const ushort*)v2wT + (size_t)(n0+n)*256 + kc*128 + kq);
    }
    __syncthreads();
    #pragma unroll
    for (int ks=0; ks<4; ks++){
      const int kq = ks*32 + quad*8;
      bf16x8 af[4], bfv[4];
      #pragma unroll
      for (int mt=0;mt<4;mt++)
        af[mt] = *(const bf16x8*)&As[(wm*64 + mt*16 + ln)*136 + kq];
      #pragma unroll
      for (int nt=0;nt<4;nt++)
        bfv[nt] = *(const bf16x8*)&Bs[(wn*64 + nt*16 + ln)*136 + kq];
      #pragma unroll
      for (int mt=0;mt<4;mt++)
        #pragma unroll
        for (int nt=0;nt<4;nt++)
          acc[mt][nt] = __builtin_amdgcn_mfma_f32_16x16x32_bf16(af[mt], bfv[nt], acc[mt][nt], 0,0,0);
    }
    __syncthreads();
  }

  float v2bv[4], voww[4];
  #pragma unroll
  for (int nt=0;nt<4;nt++){
    int col = n0 + wn*64 + nt*16 + ln;
    v2bv[nt] = v2b[col];
    voww[nt] = vow[col];
  }
  float s[4][4];
  #pragma unroll
  for (int mt=0;mt<4;mt++)
    #pragma unroll
    for (int r=0;r<4;r++){
      float p = 0.f;
      #pragma unroll
      for (int nt=0;nt<4;nt++)
        p += fmaxf(acc[mt][nt][r] + v2bv[nt], 0.f) * voww[nt];
      s[mt][r] = p;
    }
  #pragma unroll
  for (int off=1; off<16; off<<=1)
    #pragma unroll
    for (int mt=0;mt<4;mt++)
      #pragma unroll
      for (int r=0;r<4;r++)
        s[mt][r] += __shfl_xor(s[mt][r], off);
  if (ln == 0){
    float add = (blockIdx.x == 0 && wn == 0) ? vob[0] : 0.f;
    #pragma unroll
    for (int mt=0;mt<4;mt++)
      #pragma unroll
      for (int r=0;r<4;r++)
        atomicAdd(&values[m0 + wm*64 + mt*16 + quad*4 + r], s[mt][r] + add);
  }
}

// ---------------------------------------------------------------------------
// MFMA GRU v11 (grum9_k): 256 blocks x 2 rows x 4 waves (256 thr) -> ALL 256
// CUs active, per-CU per-step contention halved (16 ds_read_b128 vs 32,
// 1 wave/SIMD VALU issue vs 2, half global traffic, 4-wave barrier vs 8).
// Round-3 evidence: grum8 was contention-bound on a half-idle GPU (only 128
// CUs; per-active-CU VALUBusy ~46%), not load-latency-bound (depth-4
// prefetch gave only -3%). Mapping: thread -> (row=quad>>1, col=wave*32+
// (quad&1)*16+ln); A-frag = h rows replicated 8x (hb rows 0/8, stride 140);
// per-wave B-frags bf[3][4][2] (two 16-col tiles). Depth-4 raw-fp16 gi
// prefetch + LDS-only barrier retained; running gi/eb pointers (no per-step
// 64-bit mults); gi prefetch overrun (<=4 steps) lands in workspace - safe.
// ---------------------------------------------------------------------------
__global__ __launch_bounds__(256, 1)
void grum9_k(const ushort* __restrict__ gih, const float* __restrict__ hidden0,
             const int* __restrict__ dones, const float* __restrict__ gWh,
             const float* __restrict__ bhn, __hip_bfloat16* __restrict__ eb_out,
             float* __restrict__ hout)
{
  __shared__ ushort wstg[32*392];
  __shared__ ushort hb[2][16*140];
  __shared__ float  dnS[T_*2];
  const int tid  = threadIdx.x;
  const int lane = tid & 63, wave = tid >> 6;   // 4 waves
  const int quad = lane >> 4, ln = lane & 15;
  const int r0   = blockIdx.x * 2;
  const int row  = quad >> 1;                   // 0..1
  const int tsel = quad & 1;                    // which 16-col tile
  const int col  = wave*32 + tsel*16 + ln;      // 0..127
  const int arow = (ln & 8) * 140;              // A-read row offset (h-row = ln>>3)

  for (int i=tid; i<T_*2; i+=256)
    dnS[i] = (dones[(size_t)(i>>1)*B_ + r0 + (i&1)] != 0) ? 1.f : 0.f;
  const float bhnr = bhn[col];

  // stage Wh -> fp16 B-frags: bf[g][kc][t2], 24 frags (96 VGPR)
  f16x8 bf[3][4][2];
  #pragma unroll
  for (int kc=0; kc<4; kc++){
    for (int i=tid; i<32*192; i+=256){
      int kk = i/192, c2 = (i - kk*192)*2;
      float2 w2 = *(const float2*)&gWh[(size_t)(kc*32+kk)*384 + c2];
      unsigned int pk = (unsigned int)f2hu(w2.x) | ((unsigned int)f2hu(w2.y) << 16);
      *(unsigned int*)&wstg[kk*392 + c2] = pk;
    }
    __syncthreads();
    #pragma unroll
    for (int g=0; g<3; g++){
      #pragma unroll
      for (int t2=0; t2<2; t2++){
        int c = g*128 + wave*32 + t2*16 + ln;
        ushort tmp[8];
        #pragma unroll
        for (int j=0;j<8;j++) tmp[j] = wstg[(quad*8+j)*392 + c];
        bf[g][kc][t2] = *(const f16x8*)tmp;
      }
    }
    __syncthreads();
  }

  float hc = hidden0[(size_t)(r0+row)*D_ + col];
  if (dnS[row] > 0.5f) hc = 0.f;
  hb[0][row*8*140 + col] = f2hu(hc);
  __syncthreads();

  // gi stream: current gates (float) + depth-3 raw fp16 prefetch, running ptrs
  const ushort* gcur = gih + (size_t)(r0+row)*384;
  const size_t  gstep = (size_t)B_*384;
  float c_r = hu2f(gcur[col]), c_z = hu2f(gcur[col+128]), c_n = hu2f(gcur[col+256]);
  const ushort* gpre = gcur + gstep;
  ushort aR,aZ,aN, bR,bZ,bN, cR,cZ,cN, dR,dZ,dN;
  aR=gpre[col]; aZ=gpre[col+128]; aN=gpre[col+256]; gpre += gstep;
  bR=gpre[col]; bZ=gpre[col+128]; bN=gpre[col+256]; gpre += gstep;
  cR=gpre[col]; cZ=gpre[col+128]; cN=gpre[col+256]; gpre += gstep;  // gpre at t=4
  dR=0; dZ=0; dN=0;

  ushort* ebp = (ushort*)eb_out + (size_t)(r0+row)*D_ + col;  // slot for t-1 store
  ushort pend_eu = 0;

#define GSTEP(t, IR,IZ,IN, OR,OZ,ON)                                          \
  {                                                                           \
    if ((t) > 0){ *ebp = pend_eu; ebp += (size_t)B_*D_; }                     \
    OR = gpre[col]; OZ = gpre[col+128]; ON = gpre[col+256]; gpre += gstep;    \
    const ushort* hbuf = hb[(t)&1];                                           \
    f16x8 ah0 = *(const f16x8*)&hbuf[arow + 0*32 + quad*8];                   \
    f16x8 ah1 = *(const f16x8*)&hbuf[arow + 1*32 + quad*8];                   \
    f16x8 ah2 = *(const f16x8*)&hbuf[arow + 2*32 + quad*8];                   \
    f16x8 ah3 = *(const f16x8*)&hbuf[arow + 3*32 + quad*8];                   \
    f32x4 aA[3][2], aB[3][2];                                                 \
    _Pragma("unroll")                                                         \
    for (int g=0;g<3;g++){                                                    \
      _Pragma("unroll")                                                       \
      for (int t2=0;t2<2;t2++){                                               \
        f32x4 z0; z0[0]=0.f; z0[1]=0.f; z0[2]=0.f; z0[3]=0.f;                 \
        f32x4 z1; z1[0]=0.f; z1[1]=0.f; z1[2]=0.f; z1[3]=0.f;                 \
        aA[g][t2] = __builtin_amdgcn_mfma_f32_16x16x32_f16(ah0, bf[g][0][t2], z0, 0,0,0); \
        aA[g][t2] = __builtin_amdgcn_mfma_f32_16x16x32_f16(ah1, bf[g][1][t2], aA[g][t2], 0,0,0); \
        aB[g][t2] = __builtin_amdgcn_mfma_f32_16x16x32_f16(ah2, bf[g][2][t2], z1, 0,0,0); \
        aB[g][t2] = __builtin_amdgcn_mfma_f32_16x16x32_f16(ah3, bf[g][3][t2], aB[g][t2], 0,0,0); \
      }                                                                       \
    }                                                                         \
    float g_r = tsel ? (aA[0][1][0]+aB[0][1][0]) : (aA[0][0][0]+aB[0][0][0]); \
    float g_z = tsel ? (aA[1][1][0]+aB[1][1][0]) : (aA[1][0][0]+aB[1][0][0]); \
    float g_n = tsel ? (aA[2][1][0]+aB[2][1][0]) : (aA[2][0][0]+aB[2][0][0]); \
    const float dnow  = dnS[(t)*2 + row];                                     \
    const float dnext = ((t)+1 < T_) ? dnS[((t)+1)*2 + row] : 0.f;            \
    float rg = sigmoidf_(c_r + g_r);                                          \
    float zg = sigmoidf_(c_z + g_z);                                          \
    float x  = c_n + rg*(g_n + bhnr);                                         \
    float ng = 2.f/(1.f+__expf(-2.f*x)) - 1.f;                                \
    float hnew = (1.f - zg)*ng + zg*hc;                                       \
    pend_eu = f2bu(hnew*(1.f-dnow));                                          \
    float hv = (dnext > 0.5f) ? 0.f : hnew;                                   \
    hc = hv;                                                                  \
    hb[((t)+1)&1][row*8*140 + col] = f2hu(hv);                                \
    asm volatile("s_waitcnt lgkmcnt(0)\n\ts_barrier" ::: "memory");           \
    c_r = hu2f(IR); c_z = hu2f(IZ); c_n = hu2f(IN);                           \
  }

  for (int t=0; t<T_; t+=4){
    GSTEP(t+0, aR,aZ,aN, dR,dZ,dN);
    GSTEP(t+1, bR,bZ,bN, aR,aZ,aN);
    GSTEP(t+2, cR,cZ,cN, bR,bZ,bN);
    GSTEP(t+3, dR,dZ,dN, cR,cZ,cN);
  }
#undef GSTEP

  *ebp = pend_eu;   // slot T_-1
  hout[(size_t)(r0+row)*D_ + col] = hc;
}

// ---------------------------------------------------------------------------
// Fused preamble (one dispatch).
// ---------------------------------------------------------------------------
__global__ __launch_bounds__(256)
void packall_k(const float* __restrict__ obs, ushort* __restrict__ obsH,
               const float* __restrict__ e1w, ushort* __restrict__ e1T,
               const float* __restrict__ e2w, ushort* __restrict__ e2T,
               const float* __restrict__ gWi, ushort* __restrict__ giT,
               const float* __restrict__ chw, __hip_bfloat16* __restrict__ bcatT,
               const float* __restrict__ uhw, __hip_bfloat16* __restrict__ uhwT,
               const float* __restrict__ uow, __hip_bfloat16* __restrict__ uowT,
               const float* __restrict__ v1w, __hip_bfloat16* __restrict__ v1wT,
               const float* __restrict__ v2w, __hip_bfloat16* __restrict__ v2wT)
{
  const int b = blockIdx.x, tid = threadIdx.x;
  if (b < 16384){
    int idx = b*256 + tid;
    obsH[idx] = f2hu(obs[idx]);
  } else if (b < 16416){
    int idx = (b-16384)*256 + tid;
    int n = idx >> 6, k = idx & 63;
    e1T[idx] = f2hu(e1w[k*128 + n]);
  } else if (b < 16480){
    int idx = (b-16416)*256 + tid;
    int n = idx >> 7, k = idx & 127;
    e2T[idx] = f2hu(e2w[k*128 + n]);
  } else if (b < 16672){
    int idx = (b-16480)*256 + tid;
    int n = idx >> 7, k = idx & 127;
    giT[idx] = f2hu(gWi[k*384 + n]);
  } else if (b < 16800){
    int idx = (b-16672)*256 + tid;
    int n = idx >> 7, k = idx & 127;
    float v = (n < 128) ? chw[k*128 + n] : chw[(128+k)*128 + (n-128)];
    bcatT[idx] = __float2bfloat16(v);
  } else if (b < 16928){
    int idx = (b-16800)*256 + tid;
    int r = idx >> 7, c = idx & 127;
    uhwT[c*256 + r] = __float2bfloat16(uhw[idx]);
  } else if (b < 16992){
    int idx = (b-16928)*256 + tid;
    int r = idx >> 7, c = idx & 127;
    uowT[c*128 + r] = __float2bfloat16(uow[idx]);
  } else if (b < 17120){
    int idx = (b-16992)*256 + tid;
    int r = idx >> 8, c = idx & 255;
    v1wT[c*128 + r] = __float2bfloat16(v1w[idx]);
  } else {
    int idx = (b-17120)*256 + tid;
    int r = idx >> 8, c = idx & 255;
    v2wT[c*256 + r] = __float2bfloat16(v2w[idx]);
  }
}

extern "C" void kernel_launch(void* const* d_in, const int* in_sizes, int n_in,
                              void* d_out, int out_size, void* d_ws, size_t ws_size,
                              hipStream_t stream) {
  const float* hidden = (const float*)d_in[0];
  const float* obs    = (const float*)d_in[1];
  const int*   dones  = (const int*)  d_in[2];
  const float* e1w = (const float*)d_in[3];
  const float* e1b = (const float*)d_in[4];
  const float* e2w = (const float*)d_in[5];
  const float* e2b = (const float*)d_in[6];
  const float* gWi = (const float*)d_in[7];
  const float* gbi = (const float*)d_in[8];
  const float* gWh = (const float*)d_in[9];
  const float* gbhn= (const float*)d_in[10];
  const float* chw = (const float*)d_in[11];
  const float* chb = (const float*)d_in[12];
  const float* cow = (const float*)d_in[13];
  const float* cob = (const float*)d_in[14];
  const float* uhw = (const float*)d_in[15];
  const float* uhb = (const float*)d_in[16];
  const float* uow = (const float*)d_in[17];
  const float* uob = (const float*)d_in[18];
  const float* v1w = (const float*)d_in[19];
  const float* v1b = (const float*)d_in[20];
  const float* v2w = (const float*)d_in[21];
  const float* v2b = (const float*)d_in[22];
  const float* vow = (const float*)d_in[23];
  const float* vob = (const float*)d_in[24];
  (void)in_sizes; (void)n_in; (void)out_size;

  float* out_hidden = (float*)d_out;
  float* out_values = (float*)d_out + (size_t)B_*D_;

  // Arena (float-slot offsets). Peak ~27.4M slots = 110 MB.
  float* ws = (float*)d_ws;
  ushort* obsH  = (ushort*)(ws);                      // [0, 2.10M)
  ushort* emb1H = (ushort*)(ws + 2097152);            // [2.10M, 6.29M)
  ushort* emb2H = (ushort*)(ws + 6291456);            // [6.29M, 10.49M)
  ushort* giH   = (ushort*)(ws + 10485760);           // [10.49M, 23.07M)
  __hip_bfloat16* Xe = (__hip_bfloat16*)(ws + 23068672); // [23.07M, 27.26M)
  ushort* wb    = (ushort*)(ws + 27262976);           // weights
  // post-GRU overlays (obs/emb/gi regions dead after grum):
  __hip_bfloat16* Xc    = (__hip_bfloat16*)(ws);              // [0, 4.19M)
  __hip_bfloat16* v1b16 = (__hip_bfloat16*)(ws + 4194304);    // [4.19M, 12.58M)
  if (ws_size < (size_t)27500000 * sizeof(float)) return;

  __hip_bfloat16* bcatT = (__hip_bfloat16*)wb;           // [256][128]
  __hip_bfloat16* uhwT  = (__hip_bfloat16*)wb + 32768;   // [128][256]
  __hip_bfloat16* uowT  = (__hip_bfloat16*)wb + 65536;   // [128][128]
  __hip_bfloat16* v1wT  = (__hip_bfloat16*)wb + 81920;   // [256][128]
  __hip_bfloat16* v2wT  = (__hip_bfloat16*)wb + 114688;  // [256][256]
  ushort* e1wT = wb + 180224;   // [128][64]  fp16
  ushort* e2wT = wb + 188416;   // [128][128] fp16
  ushort* gWiT = wb + 204800;   // [384][128] fp16

  dim3 blk(256);
  hipMemsetAsync(out_values, 0, (size_t)M_*sizeof(float), stream);
  packall_k<<<dim3(17376), blk, 0, stream>>>(
    obs, obsH, e1w, e1wT, e2w, e2wT, gWi, gWiT,
    chw, bcatT, uhw, uhwT, uow, uowT, v1w, v1wT, v2w, v2wT);

  // embeds + gi: single-term fp16 MFMA
  mgemmh_k<1><<<dim3(2,512), blk, 0, stream>>>(obsH,  e1wT, e1b, emb1H, M_, 128, 64);
  mgemmh_k<1><<<dim3(2,512), blk, 0, stream>>>(emb1H, e2wT, e2b, emb2H, M_, 128, 128);
  mgemmh_k<0><<<dim3(6,512), blk, 0, stream>>>(emb2H, gWiT, gbi, giH,   M_, 384, 128);

  // MFMA GRU: 256 blocks x 2 rows, all CUs
  grum9_k<<<dim3(256), dim3(256), 0, stream>>>(giH, hidden, dones, gWh, gbhn, Xe, out_hidden);

  for (int it=0; it<2; it++){
    couple2_k<<<dim3(T_*NE_), blk, 0, stream>>>(Xe, (const ushort*)bcatT, chb, cow, cob, Xc);
    updf_k<<<dim3(512), blk, 0, stream>>>(Xe, Xc, uhwT, uhb, uowT, uob, dones, Xe);
  }
  // value head: v1 GEMM, then fused v2+dot
  mgemm_k<1><<<dim3(2,512), blk, 0, stream>>>(Xe, v1wT, v1b, v1b16, M_, 256, 128);
  vhead2_k<<<dim3(2,512), blk, 0, stream>>>(v1b16, v2wT, v2b, vow, vob, out_values);
}

// Round 5
// 397.604 us; speedup vs baseline: 1.0959x; 1.0756x over previous
//
#include <hip/hip_runtime.h>
#include <hip/hip_bf16.h>
#include <math.h>

#define T_ 128
#define NE_ 64
#define NA_ 8
#define B_ 512
#define OBS_ 64
#define D_ 128
#define CH_ 128
#define VH_ 256
#define M_ (T_*B_)   // 65536

typedef __attribute__((ext_vector_type(8))) short bf16x8;
typedef __attribute__((ext_vector_type(8))) _Float16 f16x8;
typedef __attribute__((ext_vector_type(4))) float f32x4;

__device__ __forceinline__ float sigmoidf_(float x){ return 1.f/(1.f+__expf(-x)); }
__device__ __forceinline__ unsigned short f2bu(float v){
  __hip_bfloat16 b = __float2bfloat16(v);
  return __builtin_bit_cast(unsigned short, b);
}
__device__ __forceinline__ float bu2f(unsigned short u){
  return __builtin_bit_cast(float, (unsigned int)u << 16);
}
__device__ __forceinline__ unsigned short f2hu(float v){
  _Float16 h = (_Float16)v;
  return __builtin_bit_cast(unsigned short, h);
}
__device__ __forceinline__ float hu2f(unsigned short u){
  return (float)__builtin_bit_cast(_Float16, u);
}

// ---------------------------------------------------------------------------
// Fused preamble GEMM chain: obs(f32) -> emb1 -> emb2 -> gi, one kernel.
// Per 128-row block: stage obs f32->f16 in LDS, GEMM1(K=64), emb1 in LDS,
// GEMM2(K=128), emb2 in LDS, then gi in 3 x 128-col chunks (K=128) straight
// to global. Kills obsH conversion pass (67MB), emb1/emb2 HBM round trips
// (67MB) and 3 dispatch tails. 2 x 34KB LDS ping-pong -> 2 blocks/CU.
// ---------------------------------------------------------------------------
__global__ __launch_bounds__(256)
void embgi_k(const float* __restrict__ obs,
             const ushort* __restrict__ e1wT, const float* __restrict__ e1b,
             const ushort* __restrict__ e2wT, const float* __restrict__ e2b,
             const ushort* __restrict__ gWiT, const float* __restrict__ gbi,
             ushort* __restrict__ giH)
{
  __shared__ ushort S1[128*136];
  __shared__ ushort S2[128*136];
  const int tid  = threadIdx.x;
  const int lane = tid & 63, wave = tid >> 6;
  const int wm = wave >> 1, wn = wave & 1;
  const int quad = lane >> 4, ln = lane & 15;
  const int m0 = blockIdx.x * 128;

  f32x4 acc[4][4];

  // stage obs (f32 -> f16) into S1, e1wT into S2
  #pragma unroll
  for (int i=0;i<8;i++){
    int c4 = tid + i*256;                 // 2048 float4 groups
    int m = c4 >> 4, kf = (c4 & 15) * 4;
    float4 v = *(const float4*)&obs[(size_t)(m0+m)*OBS_ + kf];
    ushort4 h; h.x=f2hu(v.x); h.y=f2hu(v.y); h.z=f2hu(v.z); h.w=f2hu(v.w);
    *(ushort4*)&S1[m*136 + kf] = h;
  }
  #pragma unroll
  for (int i=0;i<4;i++){
    int c8 = tid + i*256;                 // 1024 ushort8
    int n = c8 >> 3, kq = (c8 & 7)*8;
    *(uint4*)&S2[n*136 + kq] = *(const uint4*)&e1wT[(size_t)n*64 + kq];
  }
  __syncthreads();

  // GEMM1: emb1 = relu(obs @ e1w + e1b), K=64
  #pragma unroll
  for (int i=0;i<4;i++)
    #pragma unroll
    for (int j=0;j<4;j++)
      #pragma unroll
      for (int r=0;r<4;r++) acc[i][j][r] = 0.f;
  #pragma unroll
  for (int ks=0; ks<2; ks++){
    const int kq = ks*32 + quad*8;
    f16x8 af[4], bfv[4];
    #pragma unroll
    for (int mt=0;mt<4;mt++)
      af[mt] = *(const f16x8*)&S1[(wm*64 + mt*16 + ln)*136 + kq];
    #pragma unroll
    for (int nt=0;nt<4;nt++)
      bfv[nt] = *(const f16x8*)&S2[(wn*64 + nt*16 + ln)*136 + kq];
    #pragma unroll
    for (int mt=0;mt<4;mt++)
      #pragma unroll
      for (int nt=0;nt<4;nt++)
        acc[mt][nt] = __builtin_amdgcn_mfma_f32_16x16x32_f16(af[mt], bfv[nt], acc[mt][nt], 0,0,0);
  }
  __syncthreads();   // everyone done reading S1/S2

  // emb1 -> S1; stage e2wT -> S2
  #pragma unroll
  for (int mt=0;mt<4;mt++)
    #pragma unroll
    for (int r=0;r<4;r++){
      int rl = wm*64 + mt*16 + quad*4 + r;
      #pragma unroll
      for (int nt=0;nt<4;nt++){
        int cl = wn*64 + nt*16 + ln;
        S1[rl*136 + cl] = f2hu(fmaxf(acc[mt][nt][r] + e1b[cl], 0.f));
      }
    }
  #pragma unroll
  for (int i=0;i<8;i++){
    int c8 = tid + i*256;
    int n = c8 >> 4, kq = (c8 & 15)*8;
    *(uint4*)&S2[n*136 + kq] = *(const uint4*)&e2wT[(size_t)n*128 + kq];
  }
  __syncthreads();

  // GEMM2: emb2 = relu(emb1 @ e2w + e2b), K=128
  #pragma unroll
  for (int i=0;i<4;i++)
    #pragma unroll
    for (int j=0;j<4;j++)
      #pragma unroll
      for (int r=0;r<4;r++) acc[i][j][r] = 0.f;
  #pragma unroll
  for (int ks=0; ks<4; ks++){
    const int kq = ks*32 + quad*8;
    f16x8 af[4], bfv[4];
    #pragma unroll
    for (int mt=0;mt<4;mt++)
      af[mt] = *(const f16x8*)&S1[(wm*64 + mt*16 + ln)*136 + kq];
    #pragma unroll
    for (int nt=0;nt<4;nt++)
      bfv[nt] = *(const f16x8*)&S2[(wn*64 + nt*16 + ln)*136 + kq];
    #pragma unroll
    for (int mt=0;mt<4;mt++)
      #pragma unroll
      for (int nt=0;nt<4;nt++)
        acc[mt][nt] = __builtin_amdgcn_mfma_f32_16x16x32_f16(af[mt], bfv[nt], acc[mt][nt], 0,0,0);
  }
  __syncthreads();   // done reading emb1(S1) / e2w(S2)

  // emb2 -> S1
  #pragma unroll
  for (int mt=0;mt<4;mt++)
    #pragma unroll
    for (int r=0;r<4;r++){
      int rl = wm*64 + mt*16 + quad*4 + r;
      #pragma unroll
      for (int nt=0;nt<4;nt++){
        int cl = wn*64 + nt*16 + ln;
        S1[rl*136 + cl] = f2hu(fmaxf(acc[mt][nt][r] + e2b[cl], 0.f));
      }
    }

  // gi chunks: gi[:, c*128 .. c*128+127] = emb2 @ gWi_chunk + gbi  (no act)
  for (int c=0; c<3; c++){
    #pragma unroll
    for (int i=0;i<8;i++){
      int c8 = tid + i*256;
      int n = c8 >> 4, kq = (c8 & 15)*8;
      *(uint4*)&S2[n*136 + kq] = *(const uint4*)&gWiT[(size_t)(c*128+n)*128 + kq];
    }
    __syncthreads();
    #pragma unroll
    for (int i=0;i<4;i++)
      #pragma unroll
      for (int j=0;j<4;j++)
        #pragma unroll
        for (int r=0;r<4;r++) acc[i][j][r] = 0.f;
    #pragma unroll
    for (int ks=0; ks<4; ks++){
      const int kq = ks*32 + quad*8;
      f16x8 af[4], bfv[4];
      #pragma unroll
      for (int mt=0;mt<4;mt++)
        af[mt] = *(const f16x8*)&S1[(wm*64 + mt*16 + ln)*136 + kq];
      #pragma unroll
      for (int nt=0;nt<4;nt++)
        bfv[nt] = *(const f16x8*)&S2[(wn*64 + nt*16 + ln)*136 + kq];
      #pragma unroll
      for (int mt=0;mt<4;mt++)
        #pragma unroll
        for (int nt=0;nt<4;nt++)
          acc[mt][nt] = __builtin_amdgcn_mfma_f32_16x16x32_f16(af[mt], bfv[nt], acc[mt][nt], 0,0,0);
    }
    __syncthreads();   // done reading S2 before next chunk restage
    #pragma unroll
    for (int mt=0;mt<4;mt++)
      #pragma unroll
      for (int r=0;r<4;r++){
        int row = m0 + wm*64 + mt*16 + quad*4 + r;
        #pragma unroll
        for (int nt=0;nt<4;nt++){
          int cl = wn*64 + nt*16 + ln;
          giH[(size_t)row*384 + c*128 + cl] = f2hu(acc[mt][nt][r] + gbi[c*128 + cl]);
        }
      }
  }
}

// ---------------------------------------------------------------------------
// bf16 MFMA GEMM (v1 head): BT = B^T [N,K] bf16; 128x128 tile, BK=128.
// ---------------------------------------------------------------------------
template<int ACT>
__global__ __launch_bounds__(256)
void mgemm_k(const __hip_bfloat16* __restrict__ A, const __hip_bfloat16* __restrict__ BT,
             const float* __restrict__ bias, __hip_bfloat16* __restrict__ Cb,
             int M, int N, int K)
{
  __shared__ ushort As[128*136];
  __shared__ ushort Bs[128*136];
  const int tid  = threadIdx.x;
  const int lane = tid & 63, wave = tid >> 6;
  const int wm = wave >> 1, wn = wave & 1;
  const int quad = lane >> 4, ln = lane & 15;
  const int n0 = blockIdx.x * 128;
  const int m0 = blockIdx.y * 128;

  f32x4 acc[4][4];
  #pragma unroll
  for (int i=0;i<4;i++)
    #pragma unroll
    for (int j=0;j<4;j++)
      #pragma unroll
      for (int r=0;r<4;r++) acc[i][j][r] = 0.f;

  for (int kc=0; kc<K; kc+=128){
    #pragma unroll
    for (int i=0;i<8;i++){
      int c8 = tid + i*256;
      int m = c8 >> 4, kq = (c8 & 15)*8;
      *(uint4*)&As[m*136 + kq] = *(const uint4*)&A[(size_t)(m0+m)*K + kc + kq];
    }
    #pragma unroll
    for (int i=0;i<8;i++){
      int c8 = tid + i*256;
      int n = c8 >> 4, kq = (c8 & 15)*8;
      *(uint4*)&Bs[n*136 + kq] = *(const uint4*)&BT[(size_t)(n0+n)*K + kc + kq];
    }
    __syncthreads();
    #pragma unroll
    for (int ks=0; ks<4; ks++){
      const int kq = ks*32 + quad*8;
      bf16x8 af[4], bfv[4];
      #pragma unroll
      for (int mt=0;mt<4;mt++)
        af[mt] = *(const bf16x8*)&As[(wm*64 + mt*16 + ln)*136 + kq];
      #pragma unroll
      for (int nt=0;nt<4;nt++)
        bfv[nt] = *(const bf16x8*)&Bs[(wn*64 + nt*16 + ln)*136 + kq];
      #pragma unroll
      for (int mt=0;mt<4;mt++)
        #pragma unroll
        for (int nt=0;nt<4;nt++)
          acc[mt][nt] = __builtin_amdgcn_mfma_f32_16x16x32_bf16(af[mt], bfv[nt], acc[mt][nt], 0,0,0);
    }
    __syncthreads();
  }

  float biasv[4];
  #pragma unroll
  for (int nt=0;nt<4;nt++) biasv[nt] = bias ? bias[n0 + wn*64 + nt*16 + ln] : 0.f;
  #pragma unroll
  for (int mt=0;mt<4;mt++){
    #pragma unroll
    for (int r=0;r<4;r++){
      int row = m0 + wm*64 + mt*16 + quad*4 + r;
      #pragma unroll
      for (int nt=0;nt<4;nt++){
        int col = n0 + wn*64 + nt*16 + ln;
        float v = acc[mt][nt][r] + biasv[nt];
        if (ACT==1) v = fmaxf(v, 0.f);
        Cb[(size_t)row*N + col] = __float2bfloat16(v);
      }
    }
  }
}

// ---------------------------------------------------------------------------
// Fused dpre+update.
// ---------------------------------------------------------------------------
__global__ __launch_bounds__(256)
void updf_k(const __hip_bfloat16* __restrict__ Xe, const __hip_bfloat16* __restrict__ Xc,
            const __hip_bfloat16* __restrict__ uhwT, const float* __restrict__ uhb,
            const __hip_bfloat16* __restrict__ uowT, const float* __restrict__ uob,
            const int* __restrict__ dones, __hip_bfloat16* __restrict__ XeOut)
{
  __shared__ ushort As[128*136];   // A-stage, then dpre tile
  __shared__ ushort Bs[128*136];
  const int tid  = threadIdx.x;
  const int lane = tid & 63, wave = tid >> 6;
  const int wm = wave >> 1, wn = wave & 1;
  const int quad = lane >> 4, ln = lane & 15;
  const int m0 = blockIdx.x * 128;

  f32x4 acc[4][4];
  #pragma unroll
  for (int i=0;i<4;i++)
    #pragma unroll
    for (int j=0;j<4;j++)
      #pragma unroll
      for (int r=0;r<4;r++) acc[i][j][r] = 0.f;

  // phase 1: dpre accumulate over K=256 (kc=0: Xe, kc=1: Xc)
  for (int kc=0; kc<2; kc++){
    const __hip_bfloat16* Ab = kc ? Xc : Xe;
    #pragma unroll
    for (int i=0;i<8;i++){
      int c8 = tid + i*256;
      int m = c8 >> 4, kq = (c8 & 15)*8;
      *(uint4*)&As[m*136 + kq] = *(const uint4*)&Ab[(size_t)(m0+m)*128 + kq];
    }
    #pragma unroll
    for (int i=0;i<8;i++){
      int c8 = tid + i*256;
      int n = c8 >> 4, kq = (c8 & 15)*8;
      *(uint4*)&Bs[n*136 + kq] = *(const uint4*)&uhwT[(size_t)n*256 + kc*128 + kq];
    }
    __syncthreads();
    #pragma unroll
    for (int ks=0; ks<4; ks++){
      const int kq = ks*32 + quad*8;
      bf16x8 af[4], bfv[4];
      #pragma unroll
      for (int mt=0;mt<4;mt++)
        af[mt] = *(const bf16x8*)&As[(wm*64 + mt*16 + ln)*136 + kq];
      #pragma unroll
      for (int nt=0;nt<4;nt++)
        bfv[nt] = *(const bf16x8*)&Bs[(wn*64 + nt*16 + ln)*136 + kq];
      #pragma unroll
      for (int mt=0;mt<4;mt++)
        #pragma unroll
        for (int nt=0;nt<4;nt++)
          acc[mt][nt] = __builtin_amdgcn_mfma_f32_16x16x32_bf16(af[mt], bfv[nt], acc[mt][nt], 0,0,0);
    }
    __syncthreads();
  }

  // stage uowT -> Bs, and dpre epilogue -> As (both free after last barrier)
  #pragma unroll
  for (int i=0;i<8;i++){
    int c8 = tid + i*256;
    int n = c8 >> 4, kq = (c8 & 15)*8;
    *(uint4*)&Bs[n*136 + kq] = *(const uint4*)&uowT[(size_t)n*128 + kq];
  }
  #pragma unroll
  for (int mt=0;mt<4;mt++){
    #pragma unroll
    for (int r=0;r<4;r++){
      int rl = wm*64 + mt*16 + quad*4 + r;
      #pragma unroll
      for (int nt=0;nt<4;nt++){
        int cl = wn*64 + nt*16 + ln;
        float v = fmaxf(acc[mt][nt][r] + uhb[cl], 0.f);
        As[rl*136 + cl] = f2bu(v);
      }
    }
  }
  __syncthreads();

  // phase 2: e = (e + relu(dpre @ uowT + uob)) * alive
  f32x4 acc2[4][4];
  #pragma unroll
  for (int i=0;i<4;i++)
    #pragma unroll
    for (int j=0;j<4;j++)
      #pragma unroll
      for (int r=0;r<4;r++) acc2[i][j][r] = 0.f;
  #pragma unroll
  for (int ks=0; ks<4; ks++){
    const int kq = ks*32 + quad*8;
    bf16x8 af[4], bfv[4];
    #pragma unroll
    for (int mt=0;mt<4;mt++)
      af[mt] = *(const bf16x8*)&As[(wm*64 + mt*16 + ln)*136 + kq];
    #pragma unroll
    for (int nt=0;nt<4;nt++)
      bfv[nt] = *(const bf16x8*)&Bs[(wn*64 + nt*16 + ln)*136 + kq];
    #pragma unroll
    for (int mt=0;mt<4;mt++)
      #pragma unroll
      for (int nt=0;nt<4;nt++)
        acc2[mt][nt] = __builtin_amdgcn_mfma_f32_16x16x32_bf16(af[mt], bfv[nt], acc2[mt][nt], 0,0,0);
  }
  #pragma unroll
  for (int mt=0;mt<4;mt++){
    #pragma unroll
    for (int r=0;r<4;r++){
      int row = m0 + wm*64 + mt*16 + quad*4 + r;
      float al = (dones[row]!=0) ? 0.f : 1.f;
      #pragma unroll
      for (int nt=0;nt<4;nt++){
        int cl = wn*64 + nt*16 + ln;
        float v = fmaxf(acc2[mt][nt][r] + uob[cl], 0.f);
        v += bu2f(((const ushort*)Xe)[(size_t)row*128 + cl]);
        v *= al;
        XeOut[(size_t)row*128 + cl] = __float2bfloat16(v);
      }
    }
  }
}

// ---------------------------------------------------------------------------
// Fused acat+coupling per (t,env).
// ---------------------------------------------------------------------------
__global__ __launch_bounds__(256)
void couple2_k(const __hip_bfloat16* __restrict__ Xe, const ushort* __restrict__ bcatT,
               const float* __restrict__ chb, const float* __restrict__ cow,
               const float* __restrict__ cob, __hip_bfloat16* __restrict__ ctxb)
{
  __shared__ ushort es16[8*136];
  __shared__ float ai[8][132], aj[8][132];
  __shared__ float cbw[CH_], cww[CH_], Cs[NA_][NA_];
  const int m0 = blockIdx.x * NA_;
  const int tid = threadIdx.x;
  const int lane = tid & 63, wave = tid >> 6;  // 4 waves
  const int quad = lane >> 4, ln = lane & 15;

  if (tid < 128){
    int j = tid >> 4, q = (tid & 15)*8;
    *(uint4*)&es16[j*136 + q] = *(const uint4*)((const ushort*)Xe + (size_t)(m0+j)*D_ + q);
    cbw[tid] = chb[tid]; cww[tid] = cow[tid];
  }
  __syncthreads();

  // acat MFMA: wave w covers cols w*64..w*64+63 (4 n-tiles)
  f32x4 acc[4];
  #pragma unroll
  for (int nt=0;nt<4;nt++)
    #pragma unroll
    for (int r=0;r<4;r++) acc[nt][r] = 0.f;
  #pragma unroll
  for (int ks=0; ks<4; ks++){
    bf16x8 af = *(const bf16x8*)&es16[(ln & 7)*136 + ks*32 + quad*8];
    #pragma unroll
    for (int nt=0;nt<4;nt++){
      int n = wave*64 + nt*16 + ln;
      bf16x8 bfv = *(const bf16x8*)&bcatT[(size_t)n*128 + ks*32 + quad*8];
      acc[nt] = __builtin_amdgcn_mfma_f32_16x16x32_bf16(af, bfv, acc[nt], 0,0,0);
    }
  }
  if (quad < 2){        // rows 0..7 live in quads 0,1
    #pragma unroll
    for (int nt=0;nt<4;nt++){
      int col = wave*64 + nt*16 + ln;
      #pragma unroll
      for (int r=0;r<4;r++){
        int row = quad*4 + r;
        float v = acc[nt][r];
        if (col < 128) ai[row][col] = v; else aj[row][col-128] = v;
      }
    }
  }
  __syncthreads();

  {
    int p = tid >> 2, q = tid & 3;
    int i = p >> 3, j = p & 7;
    float s = 0.f;
    #pragma unroll
    for (int h = 0; h < 32; h++){
      int hh = q*32 + h;
      s += fmaxf(ai[i][hh] + aj[j][hh] + cbw[hh], 0.f) * cww[hh];
    }
    s += __shfl_down(s, 2);
    s += __shfl_down(s, 1);
    if (q == 0) {
      float Cv = sigmoidf_(s + cob[0]);
      Cs[i][j] = (i==j) ? 0.f : Cv;
    }
  }
  __syncthreads();
  #pragma unroll
  for (int rep=0; rep<4; rep++){
    int idx = rep*256 + tid;
    int i = idx >> 7, d = idx & 127;
    float s = 0.f;
    #pragma unroll
    for (int j=0;j<NA_;j++) s = fmaf(Cs[i][j], bu2f(es16[j*136 + d]), s);
    ctxb[(size_t)(m0+i)*D_ + d] = __float2bfloat16(s);
  }
}

// ---------------------------------------------------------------------------
// Fused v2 + vout.
// ---------------------------------------------------------------------------
__global__ __launch_bounds__(256)
void vhead2_k(const __hip_bfloat16* __restrict__ v1, const __hip_bfloat16* __restrict__ v2wT,
              const float* __restrict__ v2b, const float* __restrict__ vow,
              const float* __restrict__ vob, float* __restrict__ values)
{
  __shared__ ushort As[128*136];
  __shared__ ushort Bs[128*136];
  const int tid  = threadIdx.x;
  const int lane = tid & 63, wave = tid >> 6;
  const int wm = wave >> 1, wn = wave & 1;
  const int quad = lane >> 4, ln = lane & 15;
  const int n0 = blockIdx.x * 128;
  const int m0 = blockIdx.y * 128;

  f32x4 acc[4][4];
  #pragma unroll
  for (int i=0;i<4;i++)
    #pragma unroll
    for (int j=0;j<4;j++)
      #pragma unroll
      for (int r=0;r<4;r++) acc[i][j][r] = 0.f;

  for (int kc=0; kc<2; kc++){
    #pragma unroll
    for (int i=0;i<8;i++){
      int c8 = tid + i*256;
      int m = c8 >> 4, kq = (c8 & 15)*8;
      *(uint4*)&As[m*136 + kq] = *(const uint4*)((const ushort*)v1 + (size_t)(m0+m)*256 + kc*128 + kq);
    }
    #pragma unroll
    for (int i=0;i<8;i++){
      int c8 = tid + i*256;
      int n = c8 >> 4, kq = (c8 & 15)*8;
      *(uint4*)&Bs[n*136 + kq] = *(const uint4*)((const ushort*)v2wT + (size_t)(n0+n)*256 + kc*128 + kq);
    }
    __syncthreads();
    #pragma unroll
    for (int ks=0; ks<4; ks++){
      const int kq = ks*32 + quad*8;
      bf16x8 af[4], bfv[4];
      #pragma unroll
      for (int mt=0;mt<4;mt++)
        af[mt] = *(const bf16x8*)&As[(wm*64 + mt*16 + ln)*136 + kq];
      #pragma unroll
      for (int nt=0;nt<4;nt++)
        bfv[nt] = *(const bf16x8*)&Bs[(wn*64 + nt*16 + ln)*136 + kq];
      #pragma unroll
      for (int mt=0;mt<4;mt++)
        #pragma unroll
        for (int nt=0;nt<4;nt++)
          acc[mt][nt] = __builtin_amdgcn_mfma_f32_16x16x32_bf16(af[mt], bfv[nt], acc[mt][nt], 0,0,0);
    }
    __syncthreads();
  }

  float v2bv[4], voww[4];
  #pragma unroll
  for (int nt=0;nt<4;nt++){
    int col = n0 + wn*64 + nt*16 + ln;
    v2bv[nt] = v2b[col];
    voww[nt] = vow[col];
  }
  float s[4][4];
  #pragma unroll
  for (int mt=0;mt<4;mt++)
    #pragma unroll
    for (int r=0;r<4;r++){
      float p = 0.f;
      #pragma unroll
      for (int nt=0;nt<4;nt++)
        p += fmaxf(acc[mt][nt][r] + v2bv[nt], 0.f) * voww[nt];
      s[mt][r] = p;
    }
  #pragma unroll
  for (int off=1; off<16; off<<=1)
    #pragma unroll
    for (int mt=0;mt<4;mt++)
      #pragma unroll
      for (int r=0;r<4;r++)
        s[mt][r] += __shfl_xor(s[mt][r], off);
  if (ln == 0){
    float add = (blockIdx.x == 0 && wn == 0) ? vob[0] : 0.f;
    #pragma unroll
    for (int mt=0;mt<4;mt++)
      #pragma unroll
      for (int r=0;r<4;r++)
        atomicAdd(&values[m0 + wm*64 + mt*16 + quad*4 + r], s[mt][r] + add);
  }
}

// ---------------------------------------------------------------------------
// MFMA GRU v10 (best measured: 84.9us, round 3). Depth-4 gi prefetch, raw
// fp16 registers, LDS-only barrier, x4 unroll static rotation. Parked: per-
// step serial chain (barrier+ds_read+MFMA dep+transcendental) is the floor;
// R1/R3/R4 falsified barrier-drain / load-latency / CU-contention theories.
// ---------------------------------------------------------------------------
__global__ __launch_bounds__(512, 1)
void grum8_k(const ushort* __restrict__ gih, const float* __restrict__ hidden0,
             const int* __restrict__ dones, const float* __restrict__ gWh,
             const float* __restrict__ bhn, __hip_bfloat16* __restrict__ eb_out,
             float* __restrict__ hout)
{
  __shared__ ushort wstg[32*392];
  __shared__ ushort hb[2][16*136];
  __shared__ float  dnS[T_*4];
  const int tid  = threadIdx.x;
  const int lane = tid & 63, wave = tid >> 6;
  const int quad = lane >> 4, ln = lane & 15;
  const int r0   = blockIdx.x * 4;
  const int col  = wave*16 + ln;
  const int lnb  = ln & 12;

  dnS[tid] = (dones[(size_t)(tid>>2)*B_ + r0 + (tid&3)] != 0) ? 1.f : 0.f;
  const float bhnr = bhn[col];

  for (int i=tid; i<16*136; i+=512){ hb[0][i]=0; hb[1][i]=0; }

  f16x8 bf[3][4];
  #pragma unroll
  for (int kc=0; kc<4; kc++){
    for (int i=tid; i<32*384; i+=512){
      int kk = i/384, c = i - kk*384;
      wstg[kk*392 + c] = f2hu(gWh[(size_t)(kc*32+kk)*384 + c]);
    }
    __syncthreads();
    #pragma unroll
    for (int g=0; g<3; g++){
      int c = g*128 + col;
      ushort tmp[8];
      #pragma unroll
      for (int j=0;j<8;j++) tmp[j] = wstg[(quad*8+j)*392 + c];
      bf[g][kc] = *(const f16x8*)tmp;
    }
    __syncthreads();
  }

  float hc = hidden0[(size_t)(r0+quad)*D_ + col];
  if (dnS[quad] > 0.5f) hc = 0.f;
  hb[0][(quad*4)*136 + col] = f2hu(hc);
  __syncthreads();

  const ushort* gbase = gih + ((size_t)(r0+quad))*384;
  const size_t  gstep = (size_t)B_*384;

  // current-step gates (float) + depth-3 raw fp16 prefetch buffers
  float c_r, c_z, c_n;
  c_r = hu2f(gbase[col]); c_z = hu2f(gbase[col+128]); c_n = hu2f(gbase[col+256]);
  ushort aR,aZ,aN, bR,bZ,bN, cR,cZ,cN, dR,dZ,dN;
  { const ushort* gp = gbase + 1*gstep; aR = gp[col]; aZ = gp[col+128]; aN = gp[col+256]; }
  { const ushort* gp = gbase + 2*gstep; bR = gp[col]; bZ = gp[col+128]; bN = gp[col+256]; }
  { const ushort* gp = gbase + 3*gstep; cR = gp[col]; cZ = gp[col+128]; cN = gp[col+256]; }
  dR=0; dZ=0; dN=0;

  ushort pend_eu = 0;

#define GSTEP(t, IR,IZ,IN, OR,OZ,ON)                                          \
  {                                                                           \
    if ((t) > 0)                                                              \
      ((ushort*)eb_out)[((size_t)((t)-1)*B_ + r0+quad)*D_ + col] = pend_eu;   \
    { int tl = (t)+4; if (tl > T_-1) tl = T_-1;                               \
      const ushort* gp = gbase + (size_t)tl*gstep;                            \
      OR = gp[col]; OZ = gp[col+128]; ON = gp[col+256]; }                     \
    const ushort* hbuf = hb[(t)&1];                                           \
    f32x4 accA[3], accB[3];                                                   \
    _Pragma("unroll")                                                         \
    for (int g=0;g<3;g++){                                                    \
      _Pragma("unroll")                                                       \
      for (int r=0;r<4;r++){ accA[g][r]=0.f; accB[g][r]=0.f; }                \
    }                                                                         \
    _Pragma("unroll")                                                         \
    for (int ks=0; ks<2; ks++){                                               \
      f16x8 ahA = *(const f16x8*)&hbuf[lnb*136 + (2*ks  )*32 + quad*8];       \
      f16x8 ahB = *(const f16x8*)&hbuf[lnb*136 + (2*ks+1)*32 + quad*8];       \
      _Pragma("unroll")                                                       \
      for (int g=0;g<3;g++){                                                  \
        accA[g] = __builtin_amdgcn_mfma_f32_16x16x32_f16(ahA, bf[g][2*ks  ], accA[g], 0,0,0); \
        accB[g] = __builtin_amdgcn_mfma_f32_16x16x32_f16(ahB, bf[g][2*ks+1], accB[g], 0,0,0); \
      }                                                                       \
    }                                                                         \
    const float dnow  = dnS[(t)*4 + quad];                                    \
    const float dnext = ((t)+1 < T_) ? dnS[((t)+1)*4 + quad] : 0.f;           \
    float rg = sigmoidf_(c_r + accA[0][0] + accB[0][0]);                      \
    float zg = sigmoidf_(c_z + accA[1][0] + accB[1][0]);                      \
    float x  = c_n + rg*(accA[2][0] + accB[2][0] + bhnr);                     \
    float ng = 2.f/(1.f+__expf(-2.f*x)) - 1.f;                                \
    float hnew = (1.f - zg)*ng + zg*hc;                                       \
    pend_eu = f2bu(hnew*(1.f-dnow));                                          \
    float hv = (dnext > 0.5f) ? 0.f : hnew;                                   \
    hc = hv;                                                                  \
    hb[((t)+1)&1][(quad*4)*136 + col] = f2hu(hv);                             \
    asm volatile("s_waitcnt lgkmcnt(0)\n\ts_barrier" ::: "memory");           \
    c_r = hu2f(IR); c_z = hu2f(IZ); c_n = hu2f(IN);                           \
  }

  for (int t=0; t<T_; t+=4){
    GSTEP(t+0, aR,aZ,aN, dR,dZ,dN);
    GSTEP(t+1, bR,bZ,bN, aR,aZ,aN);
    GSTEP(t+2, cR,cZ,cN, bR,bZ,bN);
    GSTEP(t+3, dR,dZ,dN, cR,cZ,cN);
  }
#undef GSTEP

  ((ushort*)eb_out)[((size_t)(T_-1)*B_ + r0+quad)*D_ + col] = pend_eu;
  hout[(size_t)(r0+quad)*D_ + col] = hc;
}

// ---------------------------------------------------------------------------
// Weight-prep preamble (obs conversion removed; handled in embgi_k).
// ---------------------------------------------------------------------------
__global__ __launch_bounds__(256)
void packall_k(const float* __restrict__ e1w, ushort* __restrict__ e1T,
               const float* __restrict__ e2w, ushort* __restrict__ e2T,
               const float* __restrict__ gWi, ushort* __restrict__ giT,
               const float* __restrict__ chw, __hip_bfloat16* __restrict__ bcatT,
               const float* __restrict__ uhw, __hip_bfloat16* __restrict__ uhwT,
               const float* __restrict__ uow, __hip_bfloat16* __restrict__ uowT,
               const float* __restrict__ v1w, __hip_bfloat16* __restrict__ v1wT,
               const float* __restrict__ v2w, __hip_bfloat16* __restrict__ v2wT)
{
  const int b = blockIdx.x, tid = threadIdx.x;
  if (b < 32){
    int idx = b*256 + tid;
    int n = idx >> 6, k = idx & 63;
    e1T[idx] = f2hu(e1w[k*128 + n]);
  } else if (b < 96){
    int idx = (b-32)*256 + tid;
    int n = idx >> 7, k = idx & 127;
    e2T[idx] = f2hu(e2w[k*128 + n]);
  } else if (b < 288){
    int idx = (b-96)*256 + tid;
    int n = idx >> 7, k = idx & 127;
    giT[idx] = f2hu(gWi[k*384 + n]);
  } else if (b < 416){
    int idx = (b-288)*256 + tid;
    int n = idx >> 7, k = idx & 127;
    float v = (n < 128) ? chw[k*128 + n] : chw[(128+k)*128 + (n-128)];
    bcatT[idx] = __float2bfloat16(v);
  } else if (b < 544){
    int idx = (b-416)*256 + tid;
    int r = idx >> 7, c = idx & 127;
    uhwT[c*256 + r] = __float2bfloat16(uhw[idx]);
  } else if (b < 608){
    int idx = (b-544)*256 + tid;
    int r = idx >> 7, c = idx & 127;
    uowT[c*128 + r] = __float2bfloat16(uow[idx]);
  } else if (b < 736){
    int idx = (b-608)*256 + tid;
    int r = idx >> 8, c = idx & 255;
    v1wT[c*128 + r] = __float2bfloat16(v1w[idx]);
  } else {
    int idx = (b-736)*256 + tid;
    int r = idx >> 8, c = idx & 255;
    v2wT[c*256 + r] = __float2bfloat16(v2w[idx]);
  }
}

extern "C" void kernel_launch(void* const* d_in, const int* in_sizes, int n_in,
                              void* d_out, int out_size, void* d_ws, size_t ws_size,
                              hipStream_t stream) {
  const float* hidden = (const float*)d_in[0];
  const float* obs    = (const float*)d_in[1];
  const int*   dones  = (const int*)  d_in[2];
  const float* e1w = (const float*)d_in[3];
  const float* e1b = (const float*)d_in[4];
  const float* e2w = (const float*)d_in[5];
  const float* e2b = (const float*)d_in[6];
  const float* gWi = (const float*)d_in[7];
  const float* gbi = (const float*)d_in[8];
  const float* gWh = (const float*)d_in[9];
  const float* gbhn= (const float*)d_in[10];
  const float* chw = (const float*)d_in[11];
  const float* chb = (const float*)d_in[12];
  const float* cow = (const float*)d_in[13];
  const float* cob = (const float*)d_in[14];
  const float* uhw = (const float*)d_in[15];
  const float* uhb = (const float*)d_in[16];
  const float* uow = (const float*)d_in[17];
  const float* uob = (const float*)d_in[18];
  const float* v1w = (const float*)d_in[19];
  const float* v1b = (const float*)d_in[20];
  const float* v2w = (const float*)d_in[21];
  const float* v2b = (const float*)d_in[22];
  const float* vow = (const float*)d_in[23];
  const float* vob = (const float*)d_in[24];
  (void)in_sizes; (void)n_in; (void)out_size;

  float* out_hidden = (float*)d_out;
  float* out_values = (float*)d_out + (size_t)B_*D_;

  // Arena (float-slot offsets). Peak ~27.4M slots = 110 MB.
  float* ws = (float*)d_ws;
  ushort* giH   = (ushort*)(ws + 10485760);           // [10.49M, 23.07M)
  __hip_bfloat16* Xe = (__hip_bfloat16*)(ws + 23068672); // [23.07M, 27.26M)
  ushort* wb    = (ushort*)(ws + 27262976);           // weights
  // post-GRU overlays (pre-GRU regions dead after grum):
  __hip_bfloat16* Xc    = (__hip_bfloat16*)(ws);              // [0, 4.19M)
  __hip_bfloat16* v1b16 = (__hip_bfloat16*)(ws + 4194304);    // [4.19M, 12.58M)
  if (ws_size < (size_t)27500000 * sizeof(float)) return;

  __hip_bfloat16* bcatT = (__hip_bfloat16*)wb;           // [256][128]
  __hip_bfloat16* uhwT  = (__hip_bfloat16*)wb + 32768;   // [128][256]
  __hip_bfloat16* uowT  = (__hip_bfloat16*)wb + 65536;   // [128][128]
  __hip_bfloat16* v1wT  = (__hip_bfloat16*)wb + 81920;   // [256][128]
  __hip_bfloat16* v2wT  = (__hip_bfloat16*)wb + 114688;  // [256][256]
  ushort* e1wT = wb + 180224;   // [128][64]  fp16
  ushort* e2wT = wb + 188416;   // [128][128] fp16
  ushort* gWiT = wb + 204800;   // [384][128] fp16

  dim3 blk(256);
  hipMemsetAsync(out_values, 0, (size_t)M_*sizeof(float), stream);
  packall_k<<<dim3(992), blk, 0, stream>>>(
    e1w, e1wT, e2w, e2wT, gWi, gWiT,
    chw, bcatT, uhw, uhwT, uow, uowT, v1w, v1wT, v2w, v2wT);

  // fused obs -> emb1 -> emb2 -> gi
  embgi_k<<<dim3(512), blk, 0, stream>>>(obs, e1wT, e1b, e2wT, e2b, gWiT, gbi, giH);

  // MFMA GRU (best measured config)
  grum8_k<<<dim3(128), dim3(512), 0, stream>>>(giH, hidden, dones, gWh, gbhn, Xe, out_hidden);

  for (int it=0; it<2; it++){
    couple2_k<<<dim3(T_*NE_), blk, 0, stream>>>(Xe, (const ushort*)bcatT, chb, cow, cob, Xc);
    updf_k<<<dim3(512), blk, 0, stream>>>(Xe, Xc, uhwT, uhb, uowT, uob, dones, Xe);
  }
  // value head: v1 GEMM, then fused v2+dot
  mgemm_k<1><<<dim3(2,512), blk, 0, stream>>>(Xe, v1wT, v1b, v1b16, M_, 256, 128);
  vhead2_k<<<dim3(2,512), blk, 0, stream>>>(v1b16, v2wT, v2b, vow, vob, out_values);
}

// Round 7
// 388.722 us; speedup vs baseline: 1.1209x; 1.0228x over previous
//
#include <hip/hip_runtime.h>
#include <hip/hip_bf16.h>
#include <math.h>

#define T_ 128
#define NE_ 64
#define NA_ 8
#define B_ 512
#define OBS_ 64
#define D_ 128
#define CH_ 128
#define VH_ 256
#define M_ (T_*B_)   // 65536

typedef __attribute__((ext_vector_type(8))) short bf16x8;
typedef __attribute__((ext_vector_type(8))) _Float16 f16x8;
typedef __attribute__((ext_vector_type(4))) float f32x4;

__device__ __forceinline__ float sigmoidf_(float x){ return 1.f/(1.f+__expf(-x)); }
__device__ __forceinline__ unsigned short f2bu(float v){
  __hip_bfloat16 b = __float2bfloat16(v);
  return __builtin_bit_cast(unsigned short, b);
}
__device__ __forceinline__ float bu2f(unsigned short u){
  return __builtin_bit_cast(float, (unsigned int)u << 16);
}
__device__ __forceinline__ unsigned short f2hu(float v){
  _Float16 h = (_Float16)v;
  return __builtin_bit_cast(unsigned short, h);
}
__device__ __forceinline__ float hu2f(unsigned short u){
  return (float)__builtin_bit_cast(_Float16, u);
}

// ---------------------------------------------------------------------------
// Fused preamble GEMM chain: obs(f32) -> emb1 -> emb2 -> gi, one kernel.
// ---------------------------------------------------------------------------
__global__ __launch_bounds__(256)
void embgi_k(const float* __restrict__ obs,
             const ushort* __restrict__ e1wT, const float* __restrict__ e1b,
             const ushort* __restrict__ e2wT, const float* __restrict__ e2b,
             const ushort* __restrict__ gWiT, const float* __restrict__ gbi,
             ushort* __restrict__ giH)
{
  __shared__ ushort S1[128*136];
  __shared__ ushort S2[128*136];
  const int tid  = threadIdx.x;
  const int lane = tid & 63, wave = tid >> 6;
  const int wm = wave >> 1, wn = wave & 1;
  const int quad = lane >> 4, ln = lane & 15;
  const int m0 = blockIdx.x * 128;

  f32x4 acc[4][4];

  // stage obs (f32 -> f16) into S1, e1wT into S2
  #pragma unroll
  for (int i=0;i<8;i++){
    int c4 = tid + i*256;                 // 2048 float4 groups
    int m = c4 >> 4, kf = (c4 & 15) * 4;
    float4 v = *(const float4*)&obs[(size_t)(m0+m)*OBS_ + kf];
    ushort4 h; h.x=f2hu(v.x); h.y=f2hu(v.y); h.z=f2hu(v.z); h.w=f2hu(v.w);
    *(ushort4*)&S1[m*136 + kf] = h;
  }
  #pragma unroll
  for (int i=0;i<4;i++){
    int c8 = tid + i*256;                 // 1024 ushort8
    int n = c8 >> 3, kq = (c8 & 7)*8;
    *(uint4*)&S2[n*136 + kq] = *(const uint4*)&e1wT[(size_t)n*64 + kq];
  }
  __syncthreads();

  // GEMM1: emb1 = relu(obs @ e1w + e1b), K=64
  #pragma unroll
  for (int i=0;i<4;i++)
    #pragma unroll
    for (int j=0;j<4;j++)
      #pragma unroll
      for (int r=0;r<4;r++) acc[i][j][r] = 0.f;
  #pragma unroll
  for (int ks=0; ks<2; ks++){
    const int kq = ks*32 + quad*8;
    f16x8 af[4], bfv[4];
    #pragma unroll
    for (int mt=0;mt<4;mt++)
      af[mt] = *(const f16x8*)&S1[(wm*64 + mt*16 + ln)*136 + kq];
    #pragma unroll
    for (int nt=0;nt<4;nt++)
      bfv[nt] = *(const f16x8*)&S2[(wn*64 + nt*16 + ln)*136 + kq];
    #pragma unroll
    for (int mt=0;mt<4;mt++)
      #pragma unroll
      for (int nt=0;nt<4;nt++)
        acc[mt][nt] = __builtin_amdgcn_mfma_f32_16x16x32_f16(af[mt], bfv[nt], acc[mt][nt], 0,0,0);
  }
  __syncthreads();   // everyone done reading S1/S2

  // emb1 -> S1; stage e2wT -> S2
  #pragma unroll
  for (int mt=0;mt<4;mt++)
    #pragma unroll
    for (int r=0;r<4;r++){
      int rl = wm*64 + mt*16 + quad*4 + r;
      #pragma unroll
      for (int nt=0;nt<4;nt++){
        int cl = wn*64 + nt*16 + ln;
        S1[rl*136 + cl] = f2hu(fmaxf(acc[mt][nt][r] + e1b[cl], 0.f));
      }
    }
  #pragma unroll
  for (int i=0;i<8;i++){
    int c8 = tid + i*256;
    int n = c8 >> 4, kq = (c8 & 15)*8;
    *(uint4*)&S2[n*136 + kq] = *(const uint4*)&e2wT[(size_t)n*128 + kq];
  }
  __syncthreads();

  // GEMM2: emb2 = relu(emb1 @ e2w + e2b), K=128
  #pragma unroll
  for (int i=0;i<4;i++)
    #pragma unroll
    for (int j=0;j<4;j++)
      #pragma unroll
      for (int r=0;r<4;r++) acc[i][j][r] = 0.f;
  #pragma unroll
  for (int ks=0; ks<4; ks++){
    const int kq = ks*32 + quad*8;
    f16x8 af[4], bfv[4];
    #pragma unroll
    for (int mt=0;mt<4;mt++)
      af[mt] = *(const f16x8*)&S1[(wm*64 + mt*16 + ln)*136 + kq];
    #pragma unroll
    for (int nt=0;nt<4;nt++)
      bfv[nt] = *(const f16x8*)&S2[(wn*64 + nt*16 + ln)*136 + kq];
    #pragma unroll
    for (int mt=0;mt<4;mt++)
      #pragma unroll
      for (int nt=0;nt<4;nt++)
        acc[mt][nt] = __builtin_amdgcn_mfma_f32_16x16x32_f16(af[mt], bfv[nt], acc[mt][nt], 0,0,0);
  }
  __syncthreads();   // done reading emb1(S1) / e2w(S2)

  // emb2 -> S1
  #pragma unroll
  for (int mt=0;mt<4;mt++)
    #pragma unroll
    for (int r=0;r<4;r++){
      int rl = wm*64 + mt*16 + quad*4 + r;
      #pragma unroll
      for (int nt=0;nt<4;nt++){
        int cl = wn*64 + nt*16 + ln;
        S1[rl*136 + cl] = f2hu(fmaxf(acc[mt][nt][r] + e2b[cl], 0.f));
      }
    }

  // gi chunks: gi[:, c*128 .. c*128+127] = emb2 @ gWi_chunk + gbi  (no act)
  for (int c=0; c<3; c++){
    #pragma unroll
    for (int i=0;i<8;i++){
      int c8 = tid + i*256;
      int n = c8 >> 4, kq = (c8 & 15)*8;
      *(uint4*)&S2[n*136 + kq] = *(const uint4*)&gWiT[(size_t)(c*128+n)*128 + kq];
    }
    __syncthreads();
    #pragma unroll
    for (int i=0;i<4;i++)
      #pragma unroll
      for (int j=0;j<4;j++)
        #pragma unroll
        for (int r=0;r<4;r++) acc[i][j][r] = 0.f;
    #pragma unroll
    for (int ks=0; ks<4; ks++){
      const int kq = ks*32 + quad*8;
      f16x8 af[4], bfv[4];
      #pragma unroll
      for (int mt=0;mt<4;mt++)
        af[mt] = *(const f16x8*)&S1[(wm*64 + mt*16 + ln)*136 + kq];
      #pragma unroll
      for (int nt=0;nt<4;nt++)
        bfv[nt] = *(const f16x8*)&S2[(wn*64 + nt*16 + ln)*136 + kq];
      #pragma unroll
      for (int mt=0;mt<4;mt++)
        #pragma unroll
        for (int nt=0;nt<4;nt++)
          acc[mt][nt] = __builtin_amdgcn_mfma_f32_16x16x32_f16(af[mt], bfv[nt], acc[mt][nt], 0,0,0);
    }
    __syncthreads();   // done reading S2 before next chunk restage
    #pragma unroll
    for (int mt=0;mt<4;mt++)
      #pragma unroll
      for (int r=0;r<4;r++){
        int row = m0 + wm*64 + mt*16 + quad*4 + r;
        #pragma unroll
        for (int nt=0;nt<4;nt++){
          int cl = wn*64 + nt*16 + ln;
          giH[(size_t)row*384 + c*128 + cl] = f2hu(acc[mt][nt][r] + gbi[c*128 + cl]);
        }
      }
  }
}

// ---------------------------------------------------------------------------
// Fused dpre+update.
// ---------------------------------------------------------------------------
__global__ __launch_bounds__(256)
void updf_k(const __hip_bfloat16* __restrict__ Xe, const __hip_bfloat16* __restrict__ Xc,
            const __hip_bfloat16* __restrict__ uhwT, const float* __restrict__ uhb,
            const __hip_bfloat16* __restrict__ uowT, const float* __restrict__ uob,
            const int* __restrict__ dones, __hip_bfloat16* __restrict__ XeOut)
{
  __shared__ ushort As[128*136];   // A-stage, then dpre tile
  __shared__ ushort Bs[128*136];
  const int tid  = threadIdx.x;
  const int lane = tid & 63, wave = tid >> 6;
  const int wm = wave >> 1, wn = wave & 1;
  const int quad = lane >> 4, ln = lane & 15;
  const int m0 = blockIdx.x * 128;

  f32x4 acc[4][4];
  #pragma unroll
  for (int i=0;i<4;i++)
    #pragma unroll
    for (int j=0;j<4;j++)
      #pragma unroll
      for (int r=0;r<4;r++) acc[i][j][r] = 0.f;

  // phase 1: dpre accumulate over K=256 (kc=0: Xe, kc=1: Xc)
  for (int kc=0; kc<2; kc++){
    const __hip_bfloat16* Ab = kc ? Xc : Xe;
    #pragma unroll
    for (int i=0;i<8;i++){
      int c8 = tid + i*256;
      int m = c8 >> 4, kq = (c8 & 15)*8;
      *(uint4*)&As[m*136 + kq] = *(const uint4*)&Ab[(size_t)(m0+m)*128 + kq];
    }
    #pragma unroll
    for (int i=0;i<8;i++){
      int c8 = tid + i*256;
      int n = c8 >> 4, kq = (c8 & 15)*8;
      *(uint4*)&Bs[n*136 + kq] = *(const uint4*)&uhwT[(size_t)n*256 + kc*128 + kq];
    }
    __syncthreads();
    #pragma unroll
    for (int ks=0; ks<4; ks++){
      const int kq = ks*32 + quad*8;
      bf16x8 af[4], bfv[4];
      #pragma unroll
      for (int mt=0;mt<4;mt++)
        af[mt] = *(const bf16x8*)&As[(wm*64 + mt*16 + ln)*136 + kq];
      #pragma unroll
      for (int nt=0;nt<4;nt++)
        bfv[nt] = *(const bf16x8*)&Bs[(wn*64 + nt*16 + ln)*136 + kq];
      #pragma unroll
      for (int mt=0;mt<4;mt++)
        #pragma unroll
        for (int nt=0;nt<4;nt++)
          acc[mt][nt] = __builtin_amdgcn_mfma_f32_16x16x32_bf16(af[mt], bfv[nt], acc[mt][nt], 0,0,0);
    }
    __syncthreads();
  }

  // stage uowT -> Bs, and dpre epilogue -> As (both free after last barrier)
  #pragma unroll
  for (int i=0;i<8;i++){
    int c8 = tid + i*256;
    int n = c8 >> 4, kq = (c8 & 15)*8;
    *(uint4*)&Bs[n*136 + kq] = *(const uint4*)&uowT[(size_t)n*128 + kq];
  }
  #pragma unroll
  for (int mt=0;mt<4;mt++){
    #pragma unroll
    for (int r=0;r<4;r++){
      int rl = wm*64 + mt*16 + quad*4 + r;
      #pragma unroll
      for (int nt=0;nt<4;nt++){
        int cl = wn*64 + nt*16 + ln;
        float v = fmaxf(acc[mt][nt][r] + uhb[cl], 0.f);
        As[rl*136 + cl] = f2bu(v);
      }
    }
  }
  __syncthreads();

  // phase 2: e = (e + relu(dpre @ uowT + uob)) * alive
  f32x4 acc2[4][4];
  #pragma unroll
  for (int i=0;i<4;i++)
    #pragma unroll
    for (int j=0;j<4;j++)
      #pragma unroll
      for (int r=0;r<4;r++) acc2[i][j][r] = 0.f;
  #pragma unroll
  for (int ks=0; ks<4; ks++){
    const int kq = ks*32 + quad*8;
    bf16x8 af[4], bfv[4];
    #pragma unroll
    for (int mt=0;mt<4;mt++)
      af[mt] = *(const bf16x8*)&As[(wm*64 + mt*16 + ln)*136 + kq];
    #pragma unroll
    for (int nt=0;nt<4;nt++)
      bfv[nt] = *(const bf16x8*)&Bs[(wn*64 + nt*16 + ln)*136 + kq];
    #pragma unroll
    for (int mt=0;mt<4;mt++)
      #pragma unroll
      for (int nt=0;nt<4;nt++)
        acc2[mt][nt] = __builtin_amdgcn_mfma_f32_16x16x32_bf16(af[mt], bfv[nt], acc2[mt][nt], 0,0,0);
  }
  #pragma unroll
  for (int mt=0;mt<4;mt++){
    #pragma unroll
    for (int r=0;r<4;r++){
      int row = m0 + wm*64 + mt*16 + quad*4 + r;
      float al = (dones[row]!=0) ? 0.f : 1.f;
      #pragma unroll
      for (int nt=0;nt<4;nt++){
        int cl = wn*64 + nt*16 + ln;
        float v = fmaxf(acc2[mt][nt][r] + uob[cl], 0.f);
        v += bu2f(((const ushort*)Xe)[(size_t)row*128 + cl]);
        v *= al;
        XeOut[(size_t)row*128 + cl] = __float2bfloat16(v);
      }
    }
  }
}

// ---------------------------------------------------------------------------
// Fused acat+coupling per (t,env). R6: 4x fewer LDS instructions in the Ch
// phase (float4 reads of ai/aj/cbw/cww) and ctx phase (ushort4 es16 reads,
// 8B coalesced ctx stores).
// ---------------------------------------------------------------------------
__global__ __launch_bounds__(256)
void couple2_k(const __hip_bfloat16* __restrict__ Xe, const ushort* __restrict__ bcatT,
               const float* __restrict__ chb, const float* __restrict__ cow,
               const float* __restrict__ cob, __hip_bfloat16* __restrict__ ctxb)
{
  __shared__ alignas(16) ushort es16[8*136];
  __shared__ alignas(16) float ai[8][132], aj[8][132];
  __shared__ alignas(16) float cbw[CH_], cww[CH_];
  __shared__ float Cs[NA_][NA_];
  const int m0 = blockIdx.x * NA_;
  const int tid = threadIdx.x;
  const int lane = tid & 63, wave = tid >> 6;  // 4 waves
  const int quad = lane >> 4, ln = lane & 15;

  if (tid < 128){
    int j = tid >> 4, q = (tid & 15)*8;
    *(uint4*)&es16[j*136 + q] = *(const uint4*)((const ushort*)Xe + (size_t)(m0+j)*D_ + q);
    cbw[tid] = chb[tid]; cww[tid] = cow[tid];
  }
  __syncthreads();

  // acat MFMA: wave w covers cols w*64..w*64+63 (4 n-tiles)
  f32x4 acc[4];
  #pragma unroll
  for (int nt=0;nt<4;nt++)
    #pragma unroll
    for (int r=0;r<4;r++) acc[nt][r] = 0.f;
  #pragma unroll
  for (int ks=0; ks<4; ks++){
    bf16x8 af = *(const bf16x8*)&es16[(ln & 7)*136 + ks*32 + quad*8];
    #pragma unroll
    for (int nt=0;nt<4;nt++){
      int n = wave*64 + nt*16 + ln;
      bf16x8 bfv = *(const bf16x8*)&bcatT[(size_t)n*128 + ks*32 + quad*8];
      acc[nt] = __builtin_amdgcn_mfma_f32_16x16x32_bf16(af, bfv, acc[nt], 0,0,0);
    }
  }
  if (quad < 2){        // rows 0..7 live in quads 0,1
    #pragma unroll
    for (int nt=0;nt<4;nt++){
      int col = wave*64 + nt*16 + ln;
      #pragma unroll
      for (int r=0;r<4;r++){
        int row = quad*4 + r;
        float v = acc[nt][r];
        if (col < 128) ai[row][col] = v; else aj[row][col-128] = v;
      }
    }
  }
  __syncthreads();

  {
    int p = tid >> 2, q = tid & 3;
    int i = p >> 3, j = p & 7;
    float s = 0.f;
    #pragma unroll
    for (int h4 = 0; h4 < 8; h4++){
      int hh = q*32 + h4*4;
      float4 a4 = *(const float4*)&ai[i][hh];
      float4 b4 = *(const float4*)&aj[j][hh];
      float4 c4 = *(const float4*)&cbw[hh];
      float4 w4 = *(const float4*)&cww[hh];
      s += fmaxf(a4.x + b4.x + c4.x, 0.f) * w4.x;
      s += fmaxf(a4.y + b4.y + c4.y, 0.f) * w4.y;
      s += fmaxf(a4.z + b4.z + c4.z, 0.f) * w4.z;
      s += fmaxf(a4.w + b4.w + c4.w, 0.f) * w4.w;
    }
    s += __shfl_down(s, 2);
    s += __shfl_down(s, 1);
    if (q == 0) {
      float Cv = sigmoidf_(s + cob[0]);
      Cs[i][j] = (i==j) ? 0.f : Cv;
    }
  }
  __syncthreads();
  {
    int i2 = tid >> 5, d4 = (tid & 31) * 4;
    float a0=0.f, a1=0.f, a2=0.f, a3=0.f;
    #pragma unroll
    for (int j=0;j<NA_;j++){
      float c = Cs[i2][j];
      ushort4 e4 = *(const ushort4*)&es16[j*136 + d4];
      a0 = fmaf(c, bu2f(e4.x), a0);
      a1 = fmaf(c, bu2f(e4.y), a1);
      a2 = fmaf(c, bu2f(e4.z), a2);
      a3 = fmaf(c, bu2f(e4.w), a3);
    }
    ushort4 o; o.x=f2bu(a0); o.y=f2bu(a1); o.z=f2bu(a2); o.w=f2bu(a3);
    *(ushort4*)&((ushort*)ctxb)[(size_t)(m0+i2)*D_ + d4] = o;
  }
}

// ---------------------------------------------------------------------------
// Fused value head: v1 = relu(Xe@v1wT+b1) kept in LDS (bf16), then
// v = relu(v1@v2wT+b2) dot vow, atomicAdd per row. Kills the v1b16 HBM
// round trip (66 MB) and one dispatch. LDS = 136KB, 1 blk/CU.
// ---------------------------------------------------------------------------
__global__ __launch_bounds__(256)
void vheadf_k(const __hip_bfloat16* __restrict__ Xe, const __hip_bfloat16* __restrict__ v1wT,
              const float* __restrict__ v1b, const __hip_bfloat16* __restrict__ v2wT,
              const float* __restrict__ v2b, const float* __restrict__ vow,
              const float* __restrict__ vob, float* __restrict__ values)
{
  __shared__ ushort S1[128*136];      // Xe stage
  __shared__ ushort S2[128*136];      // weight stage
  __shared__ ushort V1[2][128*136];   // v1 halves (bf16)
  const int tid  = threadIdx.x;
  const int lane = tid & 63, wave = tid >> 6;
  const int wm = wave >> 1, wn = wave & 1;
  const int quad = lane >> 4, ln = lane & 15;
  const int m0 = blockIdx.x * 128;

  // stage Xe -> S1
  #pragma unroll
  for (int i=0;i<8;i++){
    int c8 = tid + i*256;
    int m = c8 >> 4, kq = (c8 & 15)*8;
    *(uint4*)&S1[m*136 + kq] = *(const uint4*)((const ushort*)Xe + (size_t)(m0+m)*128 + kq);
  }

  // phase 1: v1 halves
  for (int h=0; h<2; h++){
    #pragma unroll
    for (int i=0;i<8;i++){
      int c8 = tid + i*256;
      int n = c8 >> 4, kq = (c8 & 15)*8;
      *(uint4*)&S2[n*136 + kq] = *(const uint4*)((const ushort*)v1wT + (size_t)(h*128+n)*128 + kq);
    }
    __syncthreads();
    f32x4 acc[4][4];
    #pragma unroll
    for (int i=0;i<4;i++)
      #pragma unroll
      for (int j=0;j<4;j++)
        #pragma unroll
        for (int r=0;r<4;r++) acc[i][j][r] = 0.f;
    #pragma unroll
    for (int ks=0; ks<4; ks++){
      const int kq = ks*32 + quad*8;
      bf16x8 af[4], bfv[4];
      #pragma unroll
      for (int mt=0;mt<4;mt++)
        af[mt] = *(const bf16x8*)&S1[(wm*64 + mt*16 + ln)*136 + kq];
      #pragma unroll
      for (int nt=0;nt<4;nt++)
        bfv[nt] = *(const bf16x8*)&S2[(wn*64 + nt*16 + ln)*136 + kq];
      #pragma unroll
      for (int mt=0;mt<4;mt++)
        #pragma unroll
        for (int nt=0;nt<4;nt++)
          acc[mt][nt] = __builtin_amdgcn_mfma_f32_16x16x32_bf16(af[mt], bfv[nt], acc[mt][nt], 0,0,0);
    }
    __syncthreads();   // S2 free, and orders V1 writes vs next stage
    #pragma unroll
    for (int mt=0;mt<4;mt++)
      #pragma unroll
      for (int r=0;r<4;r++){
        int rl = wm*64 + mt*16 + quad*4 + r;
        #pragma unroll
        for (int nt=0;nt<4;nt++){
          int cl = wn*64 + nt*16 + ln;
          V1[h][rl*136 + cl] = f2bu(fmaxf(acc[mt][nt][r] + v1b[h*128 + cl], 0.f));
        }
      }
  }

  // phase 2: v2 (K=256 from V1) in 2 output chunks x 2 k-halves; dot with vow
  float s[4][4];
  #pragma unroll
  for (int mt=0;mt<4;mt++)
    #pragma unroll
    for (int r=0;r<4;r++) s[mt][r] = 0.f;

  for (int oc=0; oc<2; oc++){
    f32x4 acc[4][4];
    #pragma unroll
    for (int i=0;i<4;i++)
      #pragma unroll
      for (int j=0;j<4;j++)
        #pragma unroll
        for (int r=0;r<4;r++) acc[i][j][r] = 0.f;
    for (int kh=0; kh<2; kh++){
      #pragma unroll
      for (int i=0;i<8;i++){
        int c8 = tid + i*256;
        int n = c8 >> 4, kq = (c8 & 15)*8;
        *(uint4*)&S2[n*136 + kq] = *(const uint4*)((const ushort*)v2wT + (size_t)(oc*128+n)*256 + kh*128 + kq);
      }
      __syncthreads();   // orders V1 writes (first iter) + stage before MFMA
      #pragma unroll
      for (int ks=0; ks<4; ks++){
        const int kq = ks*32 + quad*8;
        bf16x8 af[4], bfv[4];
        #pragma unroll
        for (int mt=0;mt<4;mt++)
          af[mt] = *(const bf16x8*)&V1[kh][(wm*64 + mt*16 + ln)*136 + kq];
        #pragma unroll
        for (int nt=0;nt<4;nt++)
          bfv[nt] = *(const bf16x8*)&S2[(wn*64 + nt*16 + ln)*136 + kq];
        #pragma unroll
        for (int mt=0;mt<4;mt++)
          #pragma unroll
          for (int nt=0;nt<4;nt++)
            acc[mt][nt] = __builtin_amdgcn_mfma_f32_16x16x32_bf16(af[mt], bfv[nt], acc[mt][nt], 0,0,0);
      }
      __syncthreads();   // S2 reusable
    }
    float v2bv[4], voww[4];
    #pragma unroll
    for (int nt=0;nt<4;nt++){
      int col = oc*128 + wn*64 + nt*16 + ln;
      v2bv[nt] = v2b[col];
      voww[nt] = vow[col];
    }
    #pragma unroll
    for (int mt=0;mt<4;mt++)
      #pragma unroll
      for (int r=0;r<4;r++){
        float p = 0.f;
        #pragma unroll
        for (int nt=0;nt<4;nt++)
          p += fmaxf(acc[mt][nt][r] + v2bv[nt], 0.f) * voww[nt];
        s[mt][r] += p;
      }
  }

  #pragma unroll
  for (int off=1; off<16; off<<=1)
    #pragma unroll
    for (int mt=0;mt<4;mt++)
      #pragma unroll
      for (int r=0;r<4;r++)
        s[mt][r] += __shfl_xor(s[mt][r], off);
  if (ln == 0){
    float add = (wn == 0) ? vob[0] : 0.f;
    #pragma unroll
    for (int mt=0;mt<4;mt++)
      #pragma unroll
      for (int r=0;r<4;r++)
        atomicAdd(&values[m0 + wm*64 + mt*16 + quad*4 + r], s[mt][r] + add);
  }
}

// ---------------------------------------------------------------------------
// MFMA GRU v10 (best measured: 84.9us, round 3). Depth-4 gi prefetch, raw
// fp16 registers, LDS-only barrier, x4 unroll static rotation. Parked.
// ---------------------------------------------------------------------------
__global__ __launch_bounds__(512, 1)
void grum8_k(const ushort* __restrict__ gih, const float* __restrict__ hidden0,
             const int* __restrict__ dones, const float* __restrict__ gWh,
             const float* __restrict__ bhn, __hip_bfloat16* __restrict__ eb_out,
             float* __restrict__ hout)
{
  __shared__ ushort wstg[32*392];
  __shared__ ushort hb[2][16*136];
  __shared__ float  dnS[T_*4];
  const int tid  = threadIdx.x;
  const int lane = tid & 63, wave = tid >> 6;
  const int quad = lane >> 4, ln = lane & 15;
  const int r0   = blockIdx.x * 4;
  const int col  = wave*16 + ln;
  const int lnb  = ln & 12;

  dnS[tid] = (dones[(size_t)(tid>>2)*B_ + r0 + (tid&3)] != 0) ? 1.f : 0.f;
  const float bhnr = bhn[col];

  for (int i=tid; i<16*136; i+=512){ hb[0][i]=0; hb[1][i]=0; }

  f16x8 bf[3][4];
  #pragma unroll
  for (int kc=0; kc<4; kc++){
    for (int i=tid; i<32*384; i+=512){
      int kk = i/384, c = i - kk*384;
      wstg[kk*392 + c] = f2hu(gWh[(size_t)(kc*32+kk)*384 + c]);
    }
    __syncthreads();
    #pragma unroll
    for (int g=0; g<3; g++){
      int c = g*128 + col;
      ushort tmp[8];
      #pragma unroll
      for (int j=0;j<8;j++) tmp[j] = wstg[(quad*8+j)*392 + c];
      bf[g][kc] = *(const f16x8*)tmp;
    }
    __syncthreads();
  }

  float hc = hidden0[(size_t)(r0+quad)*D_ + col];
  if (dnS[quad] > 0.5f) hc = 0.f;
  hb[0][(quad*4)*136 + col] = f2hu(hc);
  __syncthreads();

  const ushort* gbase = gih + ((size_t)(r0+quad))*384;
  const size_t  gstep = (size_t)B_*384;

  // current-step gates (float) + depth-3 raw fp16 prefetch buffers
  float c_r, c_z, c_n;
  c_r = hu2f(gbase[col]); c_z = hu2f(gbase[col+128]); c_n = hu2f(gbase[col+256]);
  ushort aR,aZ,aN, bR,bZ,bN, cR,cZ,cN, dR,dZ,dN;
  { const ushort* gp = gbase + 1*gstep; aR = gp[col]; aZ = gp[col+128]; aN = gp[col+256]; }
  { const ushort* gp = gbase + 2*gstep; bR = gp[col]; bZ = gp[col+128]; bN = gp[col+256]; }
  { const ushort* gp = gbase + 3*gstep; cR = gp[col]; cZ = gp[col+128]; cN = gp[col+256]; }
  dR=0; dZ=0; dN=0;

  ushort pend_eu = 0;

#define GSTEP(t, IR,IZ,IN, OR,OZ,ON)                                          \
  {                                                                           \
    if ((t) > 0)                                                              \
      ((ushort*)eb_out)[((size_t)((t)-1)*B_ + r0+quad)*D_ + col] = pend_eu;   \
    { int tl = (t)+4; if (tl > T_-1) tl = T_-1;                               \
      const ushort* gp = gbase + (size_t)tl*gstep;                            \
      OR = gp[col]; OZ = gp[col+128]; ON = gp[col+256]; }                     \
    const ushort* hbuf = hb[(t)&1];                                           \
    f32x4 accA[3], accB[3];                                                   \
    _Pragma("unroll")                                                         \
    for (int g=0;g<3;g++){                                                    \
      _Pragma("unroll")                                                       \
      for (int r=0;r<4;r++){ accA[g][r]=0.f; accB[g][r]=0.f; }                \
    }                                                                         \
    _Pragma("unroll")                                                         \
    for (int ks=0; ks<2; ks++){                                               \
      f16x8 ahA = *(const f16x8*)&hbuf[lnb*136 + (2*ks  )*32 + quad*8];       \
      f16x8 ahB = *(const f16x8*)&hbuf[lnb*136 + (2*ks+1)*32 + quad*8];       \
      _Pragma("unroll")                                                       \
      for (int g=0;g<3;g++){                                                  \
        accA[g] = __builtin_amdgcn_mfma_f32_16x16x32_f16(ahA, bf[g][2*ks  ], accA[g], 0,0,0); \
        accB[g] = __builtin_amdgcn_mfma_f32_16x16x32_f16(ahB, bf[g][2*ks+1], accB[g], 0,0,0); \
      }                                                                       \
    }                                                                         \
    const float dnow  = dnS[(t)*4 + quad];                                    \
    const float dnext = ((t)+1 < T_) ? dnS[((t)+1)*4 + quad] : 0.f;           \
    float rg = sigmoidf_(c_r + accA[0][0] + accB[0][0]);                      \
    float zg = sigmoidf_(c_z + accA[1][0] + accB[1][0]);                      \
    float x  = c_n + rg*(accA[2][0] + accB[2][0] + bhnr);                     \
    float ng = 2.f/(1.f+__expf(-2.f*x)) - 1.f;                                \
    float hnew = (1.f - zg)*ng + zg*hc;                                       \
    pend_eu = f2bu(hnew*(1.f-dnow));                                          \
    float hv = (dnext > 0.5f) ? 0.f : hnew;                                   \
    hc = hv;                                                                  \
    hb[((t)+1)&1][(quad*4)*136 + col] = f2hu(hv);                             \
    asm volatile("s_waitcnt lgkmcnt(0)\n\ts_barrier" ::: "memory");           \
    c_r = hu2f(IR); c_z = hu2f(IZ); c_n = hu2f(IN);                           \
  }

  for (int t=0; t<T_; t+=4){
    GSTEP(t+0, aR,aZ,aN, dR,dZ,dN);
    GSTEP(t+1, bR,bZ,bN, aR,aZ,aN);
    GSTEP(t+2, cR,cZ,cN, bR,bZ,bN);
    GSTEP(t+3, dR,dZ,dN, cR,cZ,cN);
  }
#undef GSTEP

  ((ushort*)eb_out)[((size_t)(T_-1)*B_ + r0+quad)*D_ + col] = pend_eu;
  hout[(size_t)(r0+quad)*D_ + col] = hc;
}

// ---------------------------------------------------------------------------
// Weight-prep preamble.
// ---------------------------------------------------------------------------
__global__ __launch_bounds__(256)
void packall_k(const float* __restrict__ e1w, ushort* __restrict__ e1T,
               const float* __restrict__ e2w, ushort* __restrict__ e2T,
               const float* __restrict__ gWi, ushort* __restrict__ giT,
               const float* __restrict__ chw, __hip_bfloat16* __restrict__ bcatT,
               const float* __restrict__ uhw, __hip_bfloat16* __restrict__ uhwT,
               const float* __restrict__ uow, __hip_bfloat16* __restrict__ uowT,
               const float* __restrict__ v1w, __hip_bfloat16* __restrict__ v1wT,
               const float* __restrict__ v2w, __hip_bfloat16* __restrict__ v2wT)
{
  const int b = blockIdx.x, tid = threadIdx.x;
  if (b < 32){
    int idx = b*256 + tid;
    int n = idx >> 6, k = idx & 63;
    e1T[idx] = f2hu(e1w[k*128 + n]);
  } else if (b < 96){
    int idx = (b-32)*256 + tid;
    int n = idx >> 7, k = idx & 127;
    e2T[idx] = f2hu(e2w[k*128 + n]);
  } else if (b < 288){
    int idx = (b-96)*256 + tid;
    int n = idx >> 7, k = idx & 127;
    giT[idx] = f2hu(gWi[k*384 + n]);
  } else if (b < 416){
    int idx = (b-288)*256 + tid;
    int n = idx >> 7, k = idx & 127;
    float v = (n < 128) ? chw[k*128 + n] : chw[(128+k)*128 + (n-128)];
    bcatT[idx] = __float2bfloat16(v);
  } else if (b < 544){
    int idx = (b-416)*256 + tid;
    int r = idx >> 7, c = idx & 127;
    uhwT[c*256 + r] = __float2bfloat16(uhw[idx]);
  } else if (b < 608){
    int idx = (b-544)*256 + tid;
    int r = idx >> 7, c = idx & 127;
    uowT[c*128 + r] = __float2bfloat16(uow[idx]);
  } else if (b < 736){
    int idx = (b-608)*256 + tid;
    int r = idx >> 8, c = idx & 255;
    v1wT[c*128 + r] = __float2bfloat16(v1w[idx]);
  } else {
    int idx = (b-736)*256 + tid;
    int r = idx >> 8, c = idx & 255;
    v2wT[c*256 + r] = __float2bfloat16(v2w[idx]);
  }
}

extern "C" void kernel_launch(void* const* d_in, const int* in_sizes, int n_in,
                              void* d_out, int out_size, void* d_ws, size_t ws_size,
                              hipStream_t stream) {
  const float* hidden = (const float*)d_in[0];
  const float* obs    = (const float*)d_in[1];
  const int*   dones  = (const int*)  d_in[2];
  const float* e1w = (const float*)d_in[3];
  const float* e1b = (const float*)d_in[4];
  const float* e2w = (const float*)d_in[5];
  const float* e2b = (const float*)d_in[6];
  const float* gWi = (const float*)d_in[7];
  const float* gbi = (const float*)d_in[8];
  const float* gWh = (const float*)d_in[9];
  const float* gbhn= (const float*)d_in[10];
  const float* chw = (const float*)d_in[11];
  const float* chb = (const float*)d_in[12];
  const float* cow = (const float*)d_in[13];
  const float* cob = (const float*)d_in[14];
  const float* uhw = (const float*)d_in[15];
  const float* uhb = (const float*)d_in[16];
  const float* uow = (const float*)d_in[17];
  const float* uob = (const float*)d_in[18];
  const float* v1w = (const float*)d_in[19];
  const float* v1b = (const float*)d_in[20];
  const float* v2w = (const float*)d_in[21];
  const float* v2b = (const float*)d_in[22];
  const float* vow = (const float*)d_in[23];
  const float* vob = (const float*)d_in[24];
  (void)in_sizes; (void)n_in; (void)out_size;

  float* out_hidden = (float*)d_out;
  float* out_values = (float*)d_out + (size_t)B_*D_;

  // Arena (float-slot offsets).
  float* ws = (float*)d_ws;
  ushort* giH   = (ushort*)(ws + 10485760);           // [10.49M, 23.07M)
  __hip_bfloat16* Xe = (__hip_bfloat16*)(ws + 23068672); // [23.07M, 27.26M)
  ushort* wb    = (ushort*)(ws + 27262976);           // weights
  // post-GRU overlays (pre-GRU regions dead after grum):
  __hip_bfloat16* Xc    = (__hip_bfloat16*)(ws);              // [0, 4.19M)
  if (ws_size < (size_t)27500000 * sizeof(float)) return;

  __hip_bfloat16* bcatT = (__hip_bfloat16*)wb;           // [256][128]
  __hip_bfloat16* uhwT  = (__hip_bfloat16*)wb + 32768;   // [128][256]
  __hip_bfloat16* uowT  = (__hip_bfloat16*)wb + 65536;   // [128][128]
  __hip_bfloat16* v1wT  = (__hip_bfloat16*)wb + 81920;   // [256][128]
  __hip_bfloat16* v2wT  = (__hip_bfloat16*)wb + 114688;  // [256][256]
  ushort* e1wT = wb + 180224;   // [128][64]  fp16
  ushort* e2wT = wb + 188416;   // [128][128] fp16
  ushort* gWiT = wb + 204800;   // [384][128] fp16

  dim3 blk(256);
  hipMemsetAsync(out_values, 0, (size_t)M_*sizeof(float), stream);
  packall_k<<<dim3(992), blk, 0, stream>>>(
    e1w, e1wT, e2w, e2wT, gWi, gWiT,
    chw, bcatT, uhw, uhwT, uow, uowT, v1w, v1wT, v2w, v2wT);

  // fused obs -> emb1 -> emb2 -> gi
  embgi_k<<<dim3(512), blk, 0, stream>>>(obs, e1wT, e1b, e2wT, e2b, gWiT, gbi, giH);

  // MFMA GRU (best measured config)
  grum8_k<<<dim3(128), dim3(512), 0, stream>>>(giH, hidden, dones, gWh, gbhn, Xe, out_hidden);

  for (int it=0; it<2; it++){
    couple2_k<<<dim3(T_*NE_), blk, 0, stream>>>(Xe, (const ushort*)bcatT, chb, cow, cob, Xc);
    updf_k<<<dim3(512), blk, 0, stream>>>(Xe, Xc, uhwT, uhb, uowT, uob, dones, Xe);
  }
  // fused value head (v1 + v2 + dot)
  vheadf_k<<<dim3(512), blk, 0, stream>>>(Xe, v1wT, v1b, v2wT, v2b, vow, vob, out_values);
}

// Round 8
// 359.939 us; speedup vs baseline: 1.2105x; 1.0800x over previous
//
#include <hip/hip_runtime.h>
#include <hip/hip_bf16.h>
#include <math.h>

#define T_ 128
#define NE_ 64
#define NA_ 8
#define B_ 512
#define OBS_ 64
#define D_ 128
#define CH_ 128
#define VH_ 256
#define M_ (T_*B_)   // 65536

typedef __attribute__((ext_vector_type(8))) short bf16x8;
typedef __attribute__((ext_vector_type(8))) _Float16 f16x8;
typedef __attribute__((ext_vector_type(4))) float f32x4;

__device__ __forceinline__ float sigmoidf_(float x){ return 1.f/(1.f+__expf(-x)); }
__device__ __forceinline__ unsigned short f2bu(float v){
  __hip_bfloat16 b = __float2bfloat16(v);
  return __builtin_bit_cast(unsigned short, b);
}
__device__ __forceinline__ float bu2f(unsigned short u){
  return __builtin_bit_cast(float, (unsigned int)u << 16);
}
__device__ __forceinline__ unsigned short f2hu(float v){
  _Float16 h = (_Float16)v;
  return __builtin_bit_cast(unsigned short, h);
}
__device__ __forceinline__ float hu2f(unsigned short u){
  return (float)__builtin_bit_cast(_Float16, u);
}

// ---------------------------------------------------------------------------
// Fused preamble GEMM chain: obs(f32) -> emb1 -> emb2 -> gi, one kernel.
// ---------------------------------------------------------------------------
__global__ __launch_bounds__(256)
void embgi_k(const float* __restrict__ obs,
             const ushort* __restrict__ e1wT, const float* __restrict__ e1b,
             const ushort* __restrict__ e2wT, const float* __restrict__ e2b,
             const ushort* __restrict__ gWiT, const float* __restrict__ gbi,
             ushort* __restrict__ giH)
{
  __shared__ ushort S1[128*136];
  __shared__ ushort S2[128*136];
  const int tid  = threadIdx.x;
  const int lane = tid & 63, wave = tid >> 6;
  const int wm = wave >> 1, wn = wave & 1;
  const int quad = lane >> 4, ln = lane & 15;
  const int m0 = blockIdx.x * 128;

  f32x4 acc[4][4];

  // stage obs (f32 -> f16) into S1, e1wT into S2
  #pragma unroll
  for (int i=0;i<8;i++){
    int c4 = tid + i*256;                 // 2048 float4 groups
    int m = c4 >> 4, kf = (c4 & 15) * 4;
    float4 v = *(const float4*)&obs[(size_t)(m0+m)*OBS_ + kf];
    ushort4 h; h.x=f2hu(v.x); h.y=f2hu(v.y); h.z=f2hu(v.z); h.w=f2hu(v.w);
    *(ushort4*)&S1[m*136 + kf] = h;
  }
  #pragma unroll
  for (int i=0;i<4;i++){
    int c8 = tid + i*256;                 // 1024 ushort8
    int n = c8 >> 3, kq = (c8 & 7)*8;
    *(uint4*)&S2[n*136 + kq] = *(const uint4*)&e1wT[(size_t)n*64 + kq];
  }
  __syncthreads();

  // GEMM1: emb1 = relu(obs @ e1w + e1b), K=64
  #pragma unroll
  for (int i=0;i<4;i++)
    #pragma unroll
    for (int j=0;j<4;j++)
      #pragma unroll
      for (int r=0;r<4;r++) acc[i][j][r] = 0.f;
  #pragma unroll
  for (int ks=0; ks<2; ks++){
    const int kq = ks*32 + quad*8;
    f16x8 af[4], bfv[4];
    #pragma unroll
    for (int mt=0;mt<4;mt++)
      af[mt] = *(const f16x8*)&S1[(wm*64 + mt*16 + ln)*136 + kq];
    #pragma unroll
    for (int nt=0;nt<4;nt++)
      bfv[nt] = *(const f16x8*)&S2[(wn*64 + nt*16 + ln)*136 + kq];
    #pragma unroll
    for (int mt=0;mt<4;mt++)
      #pragma unroll
      for (int nt=0;nt<4;nt++)
        acc[mt][nt] = __builtin_amdgcn_mfma_f32_16x16x32_f16(af[mt], bfv[nt], acc[mt][nt], 0,0,0);
  }
  __syncthreads();   // everyone done reading S1/S2

  // emb1 -> S1; stage e2wT -> S2
  #pragma unroll
  for (int mt=0;mt<4;mt++)
    #pragma unroll
    for (int r=0;r<4;r++){
      int rl = wm*64 + mt*16 + quad*4 + r;
      #pragma unroll
      for (int nt=0;nt<4;nt++){
        int cl = wn*64 + nt*16 + ln;
        S1[rl*136 + cl] = f2hu(fmaxf(acc[mt][nt][r] + e1b[cl], 0.f));
      }
    }
  #pragma unroll
  for (int i=0;i<8;i++){
    int c8 = tid + i*256;
    int n = c8 >> 4, kq = (c8 & 15)*8;
    *(uint4*)&S2[n*136 + kq] = *(const uint4*)&e2wT[(size_t)n*128 + kq];
  }
  __syncthreads();

  // GEMM2: emb2 = relu(emb1 @ e2w + e2b), K=128
  #pragma unroll
  for (int i=0;i<4;i++)
    #pragma unroll
    for (int j=0;j<4;j++)
      #pragma unroll
      for (int r=0;r<4;r++) acc[i][j][r] = 0.f;
  #pragma unroll
  for (int ks=0; ks<4; ks++){
    const int kq = ks*32 + quad*8;
    f16x8 af[4], bfv[4];
    #pragma unroll
    for (int mt=0;mt<4;mt++)
      af[mt] = *(const f16x8*)&S1[(wm*64 + mt*16 + ln)*136 + kq];
    #pragma unroll
    for (int nt=0;nt<4;nt++)
      bfv[nt] = *(const f16x8*)&S2[(wn*64 + nt*16 + ln)*136 + kq];
    #pragma unroll
    for (int mt=0;mt<4;mt++)
      #pragma unroll
      for (int nt=0;nt<4;nt++)
        acc[mt][nt] = __builtin_amdgcn_mfma_f32_16x16x32_f16(af[mt], bfv[nt], acc[mt][nt], 0,0,0);
  }
  __syncthreads();   // done reading emb1(S1) / e2w(S2)

  // emb2 -> S1
  #pragma unroll
  for (int mt=0;mt<4;mt++)
    #pragma unroll
    for (int r=0;r<4;r++){
      int rl = wm*64 + mt*16 + quad*4 + r;
      #pragma unroll
      for (int nt=0;nt<4;nt++){
        int cl = wn*64 + nt*16 + ln;
        S1[rl*136 + cl] = f2hu(fmaxf(acc[mt][nt][r] + e2b[cl], 0.f));
      }
    }

  // gi chunks: gi[:, c*128 .. c*128+127] = emb2 @ gWi_chunk + gbi  (no act)
  for (int c=0; c<3; c++){
    #pragma unroll
    for (int i=0;i<8;i++){
      int c8 = tid + i*256;
      int n = c8 >> 4, kq = (c8 & 15)*8;
      *(uint4*)&S2[n*136 + kq] = *(const uint4*)&gWiT[(size_t)(c*128+n)*128 + kq];
    }
    __syncthreads();
    #pragma unroll
    for (int i=0;i<4;i++)
      #pragma unroll
      for (int j=0;j<4;j++)
        #pragma unroll
        for (int r=0;r<4;r++) acc[i][j][r] = 0.f;
    #pragma unroll
    for (int ks=0; ks<4; ks++){
      const int kq = ks*32 + quad*8;
      f16x8 af[4], bfv[4];
      #pragma unroll
      for (int mt=0;mt<4;mt++)
        af[mt] = *(const f16x8*)&S1[(wm*64 + mt*16 + ln)*136 + kq];
      #pragma unroll
      for (int nt=0;nt<4;nt++)
        bfv[nt] = *(const f16x8*)&S2[(wn*64 + nt*16 + ln)*136 + kq];
      #pragma unroll
      for (int mt=0;mt<4;mt++)
        #pragma unroll
        for (int nt=0;nt<4;nt++)
          acc[mt][nt] = __builtin_amdgcn_mfma_f32_16x16x32_f16(af[mt], bfv[nt], acc[mt][nt], 0,0,0);
    }
    __syncthreads();   // done reading S2 before next chunk restage
    #pragma unroll
    for (int mt=0;mt<4;mt++)
      #pragma unroll
      for (int r=0;r<4;r++){
        int row = m0 + wm*64 + mt*16 + quad*4 + r;
        #pragma unroll
        for (int nt=0;nt<4;nt++){
          int cl = wn*64 + nt*16 + ln;
          giH[(size_t)row*384 + c*128 + cl] = f2hu(acc[mt][nt][r] + gbi[c*128 + cl]);
        }
      }
  }
}

// ---------------------------------------------------------------------------
// R8: fully fused coupling+update iteration (replaces couple2_k + updf_k).
// Per 128-row block (= 16 whole envs, 8 agent rows each):
//   A. stage Xe tile -> S1 (LDS, pristine all kernel).
//   B. per 4-env group g: ai = e@W1, aj = e@W2 (MFMA, f32 LDS), then
//      C_ij = sigmoid(sum_h relu(ai+aj+cb)*cw), ctx = C@e -> XcS (bf16 LDS).
//   C. dpre = relu([Xe|ctx]@uhwT + uhb): K=256 with A from S1 (kc=0) and
//      XcS (kc=1); dpre -> XcS (overwrite, ctx consumed).
//   D. Xe = (Xe + relu(dpre@uowT + uob)) * alive, Xe add from S1.
// Kills Xc HBM round trip (34 MB/iter), ~0.5 GB/iter L2 bcatT re-reads
// (8192 tiny blocks -> 512, bcat staged per group), 1 dispatch tail/iter,
// duplicate Xe reads. In-place Xe safe: all deps intra-env -> intra-block.
// LDS = 137 KB -> 1 blk/CU (occupancy is the watch-item).
// ---------------------------------------------------------------------------
__global__ __launch_bounds__(256, 1)
void upd3_k(const __hip_bfloat16* __restrict__ Xe, const __hip_bfloat16* __restrict__ bcatT,
            const float* __restrict__ chb, const float* __restrict__ cow,
            const float* __restrict__ cob,
            const __hip_bfloat16* __restrict__ uhwT, const float* __restrict__ uhb,
            const __hip_bfloat16* __restrict__ uowT, const float* __restrict__ uob,
            const int* __restrict__ dones, __hip_bfloat16* __restrict__ XeOut)
{
  __shared__ ushort S1[128*136];            // Xe tile (pristine)
  __shared__ ushort Bs[128*136];            // weight stage
  __shared__ ushort XcS[128*136];           // ctx, then dpre
  __shared__ alignas(16) float AI[32][132]; // ai for 4-env group
  __shared__ alignas(16) float AJ[32][132]; // aj for 4-env group
  __shared__ alignas(16) float cbw[CH_], cww[CH_];
  __shared__ float Cs[4][NA_][NA_];
  const int tid  = threadIdx.x;
  const int lane = tid & 63, wave = tid >> 6;
  const int wm = wave >> 1, wn = wave & 1;
  const int quad = lane >> 4, ln = lane & 15;
  const int m0 = blockIdx.x * 128;

  // stage Xe -> S1, coupling vectors
  #pragma unroll
  for (int i=0;i<8;i++){
    int c8 = tid + i*256;
    int m = c8 >> 4, kq = (c8 & 15)*8;
    *(uint4*)&S1[m*136 + kq] = *(const uint4*)((const ushort*)Xe + (size_t)(m0+m)*128 + kq);
  }
  if (tid < 128){ cbw[tid] = chb[tid]; cww[tid] = cow[tid]; }
  const float cob0 = cob[0];
  __syncthreads();

  // ---- coupling: 4 groups of 4 envs (32 rows) ----
  for (int g=0; g<4; g++){
    const int r0 = g*32;
    // ai: stage W1 (bcatT rows 0..127) -> Bs
    #pragma unroll
    for (int i=0;i<8;i++){
      int c8 = tid + i*256;
      int n = c8 >> 4, kq = (c8 & 15)*8;
      *(uint4*)&Bs[n*136 + kq] = *(const uint4*)((const ushort*)bcatT + (size_t)n*128 + kq);
    }
    __syncthreads();
    {
      f32x4 acc[2][2];
      #pragma unroll
      for (int mt=0;mt<2;mt++)
        #pragma unroll
        for (int nt=0;nt<2;nt++)
          #pragma unroll
          for (int r=0;r<4;r++) acc[mt][nt][r] = 0.f;
      #pragma unroll
      for (int ks=0; ks<4; ks++){
        const int kq = ks*32 + quad*8;
        bf16x8 af[2], bfv[2];
        #pragma unroll
        for (int mt=0;mt<2;mt++)
          af[mt] = *(const bf16x8*)&S1[(r0 + mt*16 + ln)*136 + kq];
        #pragma unroll
        for (int nt=0;nt<2;nt++)
          bfv[nt] = *(const bf16x8*)&Bs[(wave*32 + nt*16 + ln)*136 + kq];
        #pragma unroll
        for (int mt=0;mt<2;mt++)
          #pragma unroll
          for (int nt=0;nt<2;nt++)
            acc[mt][nt] = __builtin_amdgcn_mfma_f32_16x16x32_bf16(af[mt], bfv[nt], acc[mt][nt], 0,0,0);
      }
      __syncthreads();   // Bs free (restage W2), AI writes below race-free
      #pragma unroll
      for (int mt=0;mt<2;mt++)
        #pragma unroll
        for (int r=0;r<4;r++)
          #pragma unroll
          for (int nt=0;nt<2;nt++)
            AI[mt*16 + quad*4 + r][wave*32 + nt*16 + ln] = acc[mt][nt][r];
    }
    // aj: stage W2 (bcatT rows 128..255) -> Bs
    #pragma unroll
    for (int i=0;i<8;i++){
      int c8 = tid + i*256;
      int n = c8 >> 4, kq = (c8 & 15)*8;
      *(uint4*)&Bs[n*136 + kq] = *(const uint4*)((const ushort*)bcatT + (size_t)(128+n)*128 + kq);
    }
    __syncthreads();
    {
      f32x4 acc[2][2];
      #pragma unroll
      for (int mt=0;mt<2;mt++)
        #pragma unroll
        for (int nt=0;nt<2;nt++)
          #pragma unroll
          for (int r=0;r<4;r++) acc[mt][nt][r] = 0.f;
      #pragma unroll
      for (int ks=0; ks<4; ks++){
        const int kq = ks*32 + quad*8;
        bf16x8 af[2], bfv[2];
        #pragma unroll
        for (int mt=0;mt<2;mt++)
          af[mt] = *(const bf16x8*)&S1[(r0 + mt*16 + ln)*136 + kq];
        #pragma unroll
        for (int nt=0;nt<2;nt++)
          bfv[nt] = *(const bf16x8*)&Bs[(wave*32 + nt*16 + ln)*136 + kq];
        #pragma unroll
        for (int mt=0;mt<2;mt++)
          #pragma unroll
          for (int nt=0;nt<2;nt++)
            acc[mt][nt] = __builtin_amdgcn_mfma_f32_16x16x32_bf16(af[mt], bfv[nt], acc[mt][nt], 0,0,0);
      }
      #pragma unroll
      for (int mt=0;mt<2;mt++)
        #pragma unroll
        for (int r=0;r<4;r++)
          #pragma unroll
          for (int nt=0;nt<2;nt++)
            AJ[mt*16 + quad*4 + r][wave*32 + nt*16 + ln] = acc[mt][nt][r];
    }
    __syncthreads();   // AI/AJ visible

    // Ch + C: one thread per (env,i,j) pair; full h reduction in-thread
    {
      const int env = tid >> 6;            // 0..3 (== wave)
      const int p = tid & 63, i = p >> 3, j = p & 7;
      const float* aiR = &AI[env*8 + i][0];
      const float* ajR = &AJ[env*8 + j][0];
      float s = 0.f;
      #pragma unroll
      for (int h4=0; h4<32; h4++){
        float4 a4 = *(const float4*)&aiR[h4*4];
        float4 b4 = *(const float4*)&ajR[h4*4];
        float4 c4 = *(const float4*)&cbw[h4*4];
        float4 w4 = *(const float4*)&cww[h4*4];
        s += fmaxf(a4.x + b4.x + c4.x, 0.f) * w4.x;
        s += fmaxf(a4.y + b4.y + c4.y, 0.f) * w4.y;
        s += fmaxf(a4.z + b4.z + c4.z, 0.f) * w4.z;
        s += fmaxf(a4.w + b4.w + c4.w, 0.f) * w4.w;
      }
      float Cv = sigmoidf_(s + cob0);
      Cs[env][i][j] = (i==j) ? 0.f : Cv;
    }
    __syncthreads();   // Cs visible

    // ctx = C @ e  -> XcS rows r0..r0+31 (bf16)
    {
      const int lr = tid >> 3;             // 0..31
      const int env = lr >> 3, i = lr & 7;
      const int c0 = (tid & 7) * 16;
      #pragma unroll
      for (int cc=0; cc<4; cc++){
        int d = c0 + cc*4;
        float a0=0.f, a1=0.f, a2=0.f, a3=0.f;
        #pragma unroll
        for (int j=0;j<NA_;j++){
          float c = Cs[env][i][j];
          ushort4 e4 = *(const ushort4*)&S1[(r0 + env*8 + j)*136 + d];
          a0 = fmaf(c, bu2f(e4.x), a0);
          a1 = fmaf(c, bu2f(e4.y), a1);
          a2 = fmaf(c, bu2f(e4.z), a2);
          a3 = fmaf(c, bu2f(e4.w), a3);
        }
        ushort4 o; o.x=f2bu(a0); o.y=f2bu(a1); o.z=f2bu(a2); o.w=f2bu(a3);
        *(ushort4*)&XcS[(r0 + lr)*136 + d] = o;
      }
    }
    __syncthreads();   // XcS group rows done; Bs/AI/AJ reusable next group
  }

  // ---- dpre = relu([Xe|ctx] @ uhwT + uhb), K=256 ----
  f32x4 acc[4][4];
  #pragma unroll
  for (int i=0;i<4;i++)
    #pragma unroll
    for (int j=0;j<4;j++)
      #pragma unroll
      for (int r=0;r<4;r++) acc[i][j][r] = 0.f;

  #pragma unroll
  for (int kc=0; kc<2; kc++){
    #pragma unroll
    for (int i=0;i<8;i++){
      int c8 = tid + i*256;
      int n = c8 >> 4, kq = (c8 & 15)*8;
      *(uint4*)&Bs[n*136 + kq] = *(const uint4*)((const ushort*)uhwT + (size_t)n*256 + kc*128 + kq);
    }
    __syncthreads();
    const ushort* Ab = kc ? XcS : S1;
    #pragma unroll
    for (int ks=0; ks<4; ks++){
      const int kq = ks*32 + quad*8;
      bf16x8 af[4], bfv[4];
      #pragma unroll
      for (int mt=0;mt<4;mt++)
        af[mt] = *(const bf16x8*)&Ab[(wm*64 + mt*16 + ln)*136 + kq];
      #pragma unroll
      for (int nt=0;nt<4;nt++)
        bfv[nt] = *(const bf16x8*)&Bs[(wn*64 + nt*16 + ln)*136 + kq];
      #pragma unroll
      for (int mt=0;mt<4;mt++)
        #pragma unroll
        for (int nt=0;nt<4;nt++)
          acc[mt][nt] = __builtin_amdgcn_mfma_f32_16x16x32_bf16(af[mt], bfv[nt], acc[mt][nt], 0,0,0);
    }
    __syncthreads();
  }

  // dpre epilogue -> XcS (ctx consumed); stage uowT -> Bs
  #pragma unroll
  for (int i=0;i<8;i++){
    int c8 = tid + i*256;
    int n = c8 >> 4, kq = (c8 & 15)*8;
    *(uint4*)&Bs[n*136 + kq] = *(const uint4*)((const ushort*)uowT + (size_t)n*128 + kq);
  }
  #pragma unroll
  for (int mt=0;mt<4;mt++)
    #pragma unroll
    for (int r=0;r<4;r++){
      int rl = wm*64 + mt*16 + quad*4 + r;
      #pragma unroll
      for (int nt=0;nt<4;nt++){
        int cl = wn*64 + nt*16 + ln;
        XcS[rl*136 + cl] = f2bu(fmaxf(acc[mt][nt][r] + uhb[cl], 0.f));
      }
    }
  __syncthreads();

  // ---- update: Xe = (Xe + relu(dpre @ uowT + uob)) * alive ----
  f32x4 acc2[4][4];
  #pragma unroll
  for (int i=0;i<4;i++)
    #pragma unroll
    for (int j=0;j<4;j++)
      #pragma unroll
      for (int r=0;r<4;r++) acc2[i][j][r] = 0.f;
  #pragma unroll
  for (int ks=0; ks<4; ks++){
    const int kq = ks*32 + quad*8;
    bf16x8 af[4], bfv[4];
    #pragma unroll
    for (int mt=0;mt<4;mt++)
      af[mt] = *(const bf16x8*)&XcS[(wm*64 + mt*16 + ln)*136 + kq];
    #pragma unroll
    for (int nt=0;nt<4;nt++)
      bfv[nt] = *(const bf16x8*)&Bs[(wn*64 + nt*16 + ln)*136 + kq];
    #pragma unroll
    for (int mt=0;mt<4;mt++)
      #pragma unroll
      for (int nt=0;nt<4;nt++)
        acc2[mt][nt] = __builtin_amdgcn_mfma_f32_16x16x32_bf16(af[mt], bfv[nt], acc2[mt][nt], 0,0,0);
  }
  #pragma unroll
  for (int mt=0;mt<4;mt++){
    #pragma unroll
    for (int r=0;r<4;r++){
      int rl = wm*64 + mt*16 + quad*4 + r;
      int row = m0 + rl;
      float al = (dones[row]!=0) ? 0.f : 1.f;
      #pragma unroll
      for (int nt=0;nt<4;nt++){
        int cl = wn*64 + nt*16 + ln;
        float v = fmaxf(acc2[mt][nt][r] + uob[cl], 0.f);
        v += bu2f(S1[rl*136 + cl]);
        v *= al;
        XeOut[(size_t)row*128 + cl] = __float2bfloat16(v);
      }
    }
  }
}

// ---------------------------------------------------------------------------
// Fused value head: v1 = relu(Xe@v1wT+b1) kept in LDS (bf16), then
// v = relu(v1@v2wT+b2) dot vow, atomicAdd per row. LDS = 136KB, 1 blk/CU.
// ---------------------------------------------------------------------------
__global__ __launch_bounds__(256)
void vheadf_k(const __hip_bfloat16* __restrict__ Xe, const __hip_bfloat16* __restrict__ v1wT,
              const float* __restrict__ v1b, const __hip_bfloat16* __restrict__ v2wT,
              const float* __restrict__ v2b, const float* __restrict__ vow,
              const float* __restrict__ vob, float* __restrict__ values)
{
  __shared__ ushort S1[128*136];      // Xe stage
  __shared__ ushort S2[128*136];      // weight stage
  __shared__ ushort V1[2][128*136];   // v1 halves (bf16)
  const int tid  = threadIdx.x;
  const int lane = tid & 63, wave = tid >> 6;
  const int wm = wave >> 1, wn = wave & 1;
  const int quad = lane >> 4, ln = lane & 15;
  const int m0 = blockIdx.x * 128;

  // stage Xe -> S1
  #pragma unroll
  for (int i=0;i<8;i++){
    int c8 = tid + i*256;
    int m = c8 >> 4, kq = (c8 & 15)*8;
    *(uint4*)&S1[m*136 + kq] = *(const uint4*)((const ushort*)Xe + (size_t)(m0+m)*128 + kq);
  }

  // phase 1: v1 halves
  for (int h=0; h<2; h++){
    #pragma unroll
    for (int i=0;i<8;i++){
      int c8 = tid + i*256;
      int n = c8 >> 4, kq = (c8 & 15)*8;
      *(uint4*)&S2[n*136 + kq] = *(const uint4*)((const ushort*)v1wT + (size_t)(h*128+n)*128 + kq);
    }
    __syncthreads();
    f32x4 acc[4][4];
    #pragma unroll
    for (int i=0;i<4;i++)
      #pragma unroll
      for (int j=0;j<4;j++)
        #pragma unroll
        for (int r=0;r<4;r++) acc[i][j][r] = 0.f;
    #pragma unroll
    for (int ks=0; ks<4; ks++){
      const int kq = ks*32 + quad*8;
      bf16x8 af[4], bfv[4];
      #pragma unroll
      for (int mt=0;mt<4;mt++)
        af[mt] = *(const bf16x8*)&S1[(wm*64 + mt*16 + ln)*136 + kq];
      #pragma unroll
      for (int nt=0;nt<4;nt++)
        bfv[nt] = *(const bf16x8*)&S2[(wn*64 + nt*16 + ln)*136 + kq];
      #pragma unroll
      for (int mt=0;mt<4;mt++)
        #pragma unroll
        for (int nt=0;nt<4;nt++)
          acc[mt][nt] = __builtin_amdgcn_mfma_f32_16x16x32_bf16(af[mt], bfv[nt], acc[mt][nt], 0,0,0);
    }
    __syncthreads();   // S2 free, and orders V1 writes vs next stage
    #pragma unroll
    for (int mt=0;mt<4;mt++)
      #pragma unroll
      for (int r=0;r<4;r++){
        int rl = wm*64 + mt*16 + quad*4 + r;
        #pragma unroll
        for (int nt=0;nt<4;nt++){
          int cl = wn*64 + nt*16 + ln;
          V1[h][rl*136 + cl] = f2bu(fmaxf(acc[mt][nt][r] + v1b[h*128 + cl], 0.f));
        }
      }
  }

  // phase 2: v2 (K=256 from V1) in 2 output chunks x 2 k-halves; dot with vow
  float s[4][4];
  #pragma unroll
  for (int mt=0;mt<4;mt++)
    #pragma unroll
    for (int r=0;r<4;r++) s[mt][r] = 0.f;

  for (int oc=0; oc<2; oc++){
    f32x4 acc[4][4];
    #pragma unroll
    for (int i=0;i<4;i++)
      #pragma unroll
      for (int j=0;j<4;j++)
        #pragma unroll
        for (int r=0;r<4;r++) acc[i][j][r] = 0.f;
    for (int kh=0; kh<2; kh++){
      #pragma unroll
      for (int i=0;i<8;i++){
        int c8 = tid + i*256;
        int n = c8 >> 4, kq = (c8 & 15)*8;
        *(uint4*)&S2[n*136 + kq] = *(const uint4*)((const ushort*)v2wT + (size_t)(oc*128+n)*256 + kh*128 + kq);
      }
      __syncthreads();   // orders V1 writes (first iter) + stage before MFMA
      #pragma unroll
      for (int ks=0; ks<4; ks++){
        const int kq = ks*32 + quad*8;
        bf16x8 af[4], bfv[4];
        #pragma unroll
        for (int mt=0;mt<4;mt++)
          af[mt] = *(const bf16x8*)&V1[kh][(wm*64 + mt*16 + ln)*136 + kq];
        #pragma unroll
        for (int nt=0;nt<4;nt++)
          bfv[nt] = *(const bf16x8*)&S2[(wn*64 + nt*16 + ln)*136 + kq];
        #pragma unroll
        for (int mt=0;mt<4;mt++)
          #pragma unroll
          for (int nt=0;nt<4;nt++)
            acc[mt][nt] = __builtin_amdgcn_mfma_f32_16x16x32_bf16(af[mt], bfv[nt], acc[mt][nt], 0,0,0);
      }
      __syncthreads();   // S2 reusable
    }
    float v2bv[4], voww[4];
    #pragma unroll
    for (int nt=0;nt<4;nt++){
      int col = oc*128 + wn*64 + nt*16 + ln;
      v2bv[nt] = v2b[col];
      voww[nt] = vow[col];
    }
    #pragma unroll
    for (int mt=0;mt<4;mt++)
      #pragma unroll
      for (int r=0;r<4;r++){
        float p = 0.f;
        #pragma unroll
        for (int nt=0;nt<4;nt++)
          p += fmaxf(acc[mt][nt][r] + v2bv[nt], 0.f) * voww[nt];
        s[mt][r] += p;
      }
  }

  #pragma unroll
  for (int off=1; off<16; off<<=1)
    #pragma unroll
    for (int mt=0;mt<4;mt++)
      #pragma unroll
      for (int r=0;r<4;r++)
        s[mt][r] += __shfl_xor(s[mt][r], off);
  if (ln == 0){
    float add = (wn == 0) ? vob[0] : 0.f;
    #pragma unroll
    for (int mt=0;mt<4;mt++)
      #pragma unroll
      for (int r=0;r<4;r++)
        atomicAdd(&values[m0 + wm*64 + mt*16 + quad*4 + r], s[mt][r] + add);
  }
}

// ---------------------------------------------------------------------------
// MFMA GRU v10 (best measured: 84.9us, round 3). Parked.
// ---------------------------------------------------------------------------
__global__ __launch_bounds__(512, 1)
void grum8_k(const ushort* __restrict__ gih, const float* __restrict__ hidden0,
             const int* __restrict__ dones, const float* __restrict__ gWh,
             const float* __restrict__ bhn, __hip_bfloat16* __restrict__ eb_out,
             float* __restrict__ hout)
{
  __shared__ ushort wstg[32*392];
  __shared__ ushort hb[2][16*136];
  __shared__ float  dnS[T_*4];
  const int tid  = threadIdx.x;
  const int lane = tid & 63, wave = tid >> 6;
  const int quad = lane >> 4, ln = lane & 15;
  const int r0   = blockIdx.x * 4;
  const int col  = wave*16 + ln;
  const int lnb  = ln & 12;

  dnS[tid] = (dones[(size_t)(tid>>2)*B_ + r0 + (tid&3)] != 0) ? 1.f : 0.f;
  const float bhnr = bhn[col];

  for (int i=tid; i<16*136; i+=512){ hb[0][i]=0; hb[1][i]=0; }

  f16x8 bf[3][4];
  #pragma unroll
  for (int kc=0; kc<4; kc++){
    for (int i=tid; i<32*384; i+=512){
      int kk = i/384, c = i - kk*384;
      wstg[kk*392 + c] = f2hu(gWh[(size_t)(kc*32+kk)*384 + c]);
    }
    __syncthreads();
    #pragma unroll
    for (int g=0; g<3; g++){
      int c = g*128 + col;
      ushort tmp[8];
      #pragma unroll
      for (int j=0;j<8;j++) tmp[j] = wstg[(quad*8+j)*392 + c];
      bf[g][kc] = *(const f16x8*)tmp;
    }
    __syncthreads();
  }

  float hc = hidden0[(size_t)(r0+quad)*D_ + col];
  if (dnS[quad] > 0.5f) hc = 0.f;
  hb[0][(quad*4)*136 + col] = f2hu(hc);
  __syncthreads();

  const ushort* gbase = gih + ((size_t)(r0+quad))*384;
  const size_t  gstep = (size_t)B_*384;

  float c_r, c_z, c_n;
  c_r = hu2f(gbase[col]); c_z = hu2f(gbase[col+128]); c_n = hu2f(gbase[col+256]);
  ushort aR,aZ,aN, bR,bZ,bN, cR,cZ,cN, dR,dZ,dN;
  { const ushort* gp = gbase + 1*gstep; aR = gp[col]; aZ = gp[col+128]; aN = gp[col+256]; }
  { const ushort* gp = gbase + 2*gstep; bR = gp[col]; bZ = gp[col+128]; bN = gp[col+256]; }
  { const ushort* gp = gbase + 3*gstep; cR = gp[col]; cZ = gp[col+128]; cN = gp[col+256]; }
  dR=0; dZ=0; dN=0;

  ushort pend_eu = 0;

#define GSTEP(t, IR,IZ,IN, OR,OZ,ON)                                          \
  {                                                                           \
    if ((t) > 0)                                                              \
      ((ushort*)eb_out)[((size_t)((t)-1)*B_ + r0+quad)*D_ + col] = pend_eu;   \
    { int tl = (t)+4; if (tl > T_-1) tl = T_-1;                               \
      const ushort* gp = gbase + (size_t)tl*gstep;                            \
      OR = gp[col]; OZ = gp[col+128]; ON = gp[col+256]; }                     \
    const ushort* hbuf = hb[(t)&1];                                           \
    f32x4 accA[3], accB[3];                                                   \
    _Pragma("unroll")                                                         \
    for (int g=0;g<3;g++){                                                    \
      _Pragma("unroll")                                                       \
      for (int r=0;r<4;r++){ accA[g][r]=0.f; accB[g][r]=0.f; }                \
    }                                                                         \
    _Pragma("unroll")                                                         \
    for (int ks=0; ks<2; ks++){                                               \
      f16x8 ahA = *(const f16x8*)&hbuf[lnb*136 + (2*ks  )*32 + quad*8];       \
      f16x8 ahB = *(const f16x8*)&hbuf[lnb*136 + (2*ks+1)*32 + quad*8];       \
      _Pragma("unroll")                                                       \
      for (int g=0;g<3;g++){                                                  \
        accA[g] = __builtin_amdgcn_mfma_f32_16x16x32_f16(ahA, bf[g][2*ks  ], accA[g], 0,0,0); \
        accB[g] = __builtin_amdgcn_mfma_f32_16x16x32_f16(ahB, bf[g][2*ks+1], accB[g], 0,0,0); \
      }                                                                       \
    }                                                                         \
    const float dnow  = dnS[(t)*4 + quad];                                    \
    const float dnext = ((t)+1 < T_) ? dnS[((t)+1)*4 + quad] : 0.f;           \
    float rg = sigmoidf_(c_r + accA[0][0] + accB[0][0]);                      \
    float zg = sigmoidf_(c_z + accA[1][0] + accB[1][0]);                      \
    float x  = c_n + rg*(accA[2][0] + accB[2][0] + bhnr);                     \
    float ng = 2.f/(1.f+__expf(-2.f*x)) - 1.f;                                \
    float hnew = (1.f - zg)*ng + zg*hc;                                       \
    pend_eu = f2bu(hnew*(1.f-dnow));                                          \
    float hv = (dnext > 0.5f) ? 0.f : hnew;                                   \
    hc = hv;                                                                  \
    hb[((t)+1)&1][(quad*4)*136 + col] = f2hu(hv);                             \
    asm volatile("s_waitcnt lgkmcnt(0)\n\ts_barrier" ::: "memory");           \
    c_r = hu2f(IR); c_z = hu2f(IZ); c_n = hu2f(IN);                           \
  }

  for (int t=0; t<T_; t+=4){
    GSTEP(t+0, aR,aZ,aN, dR,dZ,dN);
    GSTEP(t+1, bR,bZ,bN, aR,aZ,aN);
    GSTEP(t+2, cR,cZ,cN, bR,bZ,bN);
    GSTEP(t+3, dR,dZ,dN, cR,cZ,cN);
  }
#undef GSTEP

  ((ushort*)eb_out)[((size_t)(T_-1)*B_ + r0+quad)*D_ + col] = pend_eu;
  hout[(size_t)(r0+quad)*D_ + col] = hc;
}

// ---------------------------------------------------------------------------
// Weight-prep preamble.
// ---------------------------------------------------------------------------
__global__ __launch_bounds__(256)
void packall_k(const float* __restrict__ e1w, ushort* __restrict__ e1T,
               const float* __restrict__ e2w, ushort* __restrict__ e2T,
               const float* __restrict__ gWi, ushort* __restrict__ giT,
               const float* __restrict__ chw, __hip_bfloat16* __restrict__ bcatT,
               const float* __restrict__ uhw, __hip_bfloat16* __restrict__ uhwT,
               const float* __restrict__ uow, __hip_bfloat16* __restrict__ uowT,
               const float* __restrict__ v1w, __hip_bfloat16* __restrict__ v1wT,
               const float* __restrict__ v2w, __hip_bfloat16* __restrict__ v2wT)
{
  const int b = blockIdx.x, tid = threadIdx.x;
  if (b < 32){
    int idx = b*256 + tid;
    int n = idx >> 6, k = idx & 63;
    e1T[idx] = f2hu(e1w[k*128 + n]);
  } else if (b < 96){
    int idx = (b-32)*256 + tid;
    int n = idx >> 7, k = idx & 127;
    e2T[idx] = f2hu(e2w[k*128 + n]);
  } else if (b < 288){
    int idx = (b-96)*256 + tid;
    int n = idx >> 7, k = idx & 127;
    giT[idx] = f2hu(gWi[k*384 + n]);
  } else if (b < 416){
    int idx = (b-288)*256 + tid;
    int n = idx >> 7, k = idx & 127;
    float v = (n < 128) ? chw[k*128 + n] : chw[(128+k)*128 + (n-128)];
    bcatT[idx] = __float2bfloat16(v);
  } else if (b < 544){
    int idx = (b-416)*256 + tid;
    int r = idx >> 7, c = idx & 127;
    uhwT[c*256 + r] = __float2bfloat16(uhw[idx]);
  } else if (b < 608){
    int idx = (b-544)*256 + tid;
    int r = idx >> 7, c = idx & 127;
    uowT[c*128 + r] = __float2bfloat16(uow[idx]);
  } else if (b < 736){
    int idx = (b-608)*256 + tid;
    int r = idx >> 8, c = idx & 255;
    v1wT[c*128 + r] = __float2bfloat16(v1w[idx]);
  } else {
    int idx = (b-736)*256 + tid;
    int r = idx >> 8, c = idx & 255;
    v2wT[c*256 + r] = __float2bfloat16(v2w[idx]);
  }
}

extern "C" void kernel_launch(void* const* d_in, const int* in_sizes, int n_in,
                              void* d_out, int out_size, void* d_ws, size_t ws_size,
                              hipStream_t stream) {
  const float* hidden = (const float*)d_in[0];
  const float* obs    = (const float*)d_in[1];
  const int*   dones  = (const int*)  d_in[2];
  const float* e1w = (const float*)d_in[3];
  const float* e1b = (const float*)d_in[4];
  const float* e2w = (const float*)d_in[5];
  const float* e2b = (const float*)d_in[6];
  const float* gWi = (const float*)d_in[7];
  const float* gbi = (const float*)d_in[8];
  const float* gWh = (const float*)d_in[9];
  const float* gbhn= (const float*)d_in[10];
  const float* chw = (const float*)d_in[11];
  const float* chb = (const float*)d_in[12];
  const float* cow = (const float*)d_in[13];
  const float* cob = (const float*)d_in[14];
  const float* uhw = (const float*)d_in[15];
  const float* uhb = (const float*)d_in[16];
  const float* uow = (const float*)d_in[17];
  const float* uob = (const float*)d_in[18];
  const float* v1w = (const float*)d_in[19];
  const float* v1b = (const float*)d_in[20];
  const float* v2w = (const float*)d_in[21];
  const float* v2b = (const float*)d_in[22];
  const float* vow = (const float*)d_in[23];
  const float* vob = (const float*)d_in[24];
  (void)in_sizes; (void)n_in; (void)out_size;

  float* out_hidden = (float*)d_out;
  float* out_values = (float*)d_out + (size_t)B_*D_;

  // Arena (float-slot offsets).
  float* ws = (float*)d_ws;
  ushort* giH   = (ushort*)(ws + 10485760);           // [10.49M, 23.07M)
  __hip_bfloat16* Xe = (__hip_bfloat16*)(ws + 23068672); // [23.07M, 27.26M)
  ushort* wb    = (ushort*)(ws + 27262976);           // weights
  if (ws_size < (size_t)27500000 * sizeof(float)) return;

  __hip_bfloat16* bcatT = (__hip_bfloat16*)wb;           // [256][128]
  __hip_bfloat16* uhwT  = (__hip_bfloat16*)wb + 32768;   // [128][256]
  __hip_bfloat16* uowT  = (__hip_bfloat16*)wb + 65536;   // [128][128]
  __hip_bfloat16* v1wT  = (__hip_bfloat16*)wb + 81920;   // [256][128]
  __hip_bfloat16* v2wT  = (__hip_bfloat16*)wb + 114688;  // [256][256]
  ushort* e1wT = wb + 180224;   // [128][64]  fp16
  ushort* e2wT = wb + 188416;   // [128][128] fp16
  ushort* gWiT = wb + 204800;   // [384][128] fp16

  dim3 blk(256);
  hipMemsetAsync(out_values, 0, (size_t)M_*sizeof(float), stream);
  packall_k<<<dim3(992), blk, 0, stream>>>(
    e1w, e1wT, e2w, e2wT, gWi, gWiT,
    chw, bcatT, uhw, uhwT, uow, uowT, v1w, v1wT, v2w, v2wT);

  // fused obs -> emb1 -> emb2 -> gi
  embgi_k<<<dim3(512), blk, 0, stream>>>(obs, e1wT, e1b, e2wT, e2b, gWiT, gbi, giH);

  // MFMA GRU (best measured config)
  grum8_k<<<dim3(128), dim3(512), 0, stream>>>(giH, hidden, dones, gWh, gbhn, Xe, out_hidden);

  // fused coupling+update, one dispatch per iteration (Xc round trip gone)
  for (int it=0; it<2; it++){
    upd3_k<<<dim3(512), blk, 0, stream>>>(Xe, bcatT, chb, cow, cob,
                                          uhwT, uhb, uowT, uob, dones, Xe);
  }
  // fused value head (v1 + v2 + dot)
  vheadf_k<<<dim3(512), blk, 0, stream>>>(Xe, v1wT, v1b, v2wT, v2b, vow, vob, out_values);
}